// Round 1
// baseline (231.719 us; speedup 1.0000x reference)
//
#include <hip/hip_runtime.h>
#include <cstdint>

typedef __attribute__((ext_vector_type(4))) float f32x4;
typedef __attribute__((ext_vector_type(8))) short bf16x8;
using u16 = unsigned short;

// ---------- helpers ----------

static __device__ __forceinline__ u16 f2bf(float f) {
  uint32_t u = __float_as_uint(f);
  u += 0x7fffu + ((u >> 16) & 1u);
  return (u16)(u >> 16);
}

// round f32 to float8_e4m3fn (RNE), return dequantized f32.
// Inputs here are |x| <~ 6, far from 448 max, so no overflow handling.
static __device__ __forceinline__ float quant_e4m3(float x) {
  uint32_t u = __float_as_uint(x);
  uint32_t absu = u & 0x7fffffffu;
  if (absu >= 0x3c800000u) {  // |x| >= 2^-6 : e4m3 normal, keep 3 mantissa bits RNE
    uint32_t lsb = (absu >> 20) & 1u;
    uint32_t r = (absu + 0x7ffffu + lsb) & ~0xfffffu;
    return __uint_as_float((u & 0x80000000u) | r);
  }
  // subnormal range: quantum 2^-9, RNE
  return rintf(x * 512.0f) * 0.001953125f;
}

static __device__ __forceinline__ void async16(const void* g, void* l) {
  __builtin_amdgcn_global_load_lds(
      (const __attribute__((address_space(1))) void*)g,
      (__attribute__((address_space(3))) void*)l, 16, 0, 0);
}

#define MFMA(a, b, c) __builtin_amdgcn_mfma_f32_16x16x32_bf16(a, b, c, 0, 0, 0)

// ---------- kernel 1: quantize activations fp32 -> e4m3 -> bf16 ----------

__global__ __launch_bounds__(256)
void quant_inputs_kernel(const float* __restrict__ x0, const float* __restrict__ x1,
                         const float* __restrict__ x2,
                         u16* __restrict__ y0, u16* __restrict__ y1, u16* __restrict__ y2) {
  const float* x = blockIdx.y == 0 ? x0 : (blockIdx.y == 1 ? x1 : x2);
  u16* y = blockIdx.y == 0 ? y0 : (blockIdx.y == 1 ? y1 : y2);
  int i = (blockIdx.x * 256 + threadIdx.x) * 8;
  f32x4 a = *(const f32x4*)(x + i);
  f32x4 b = *(const f32x4*)(x + i + 4);
  union { bf16x8 v; u16 s[8]; } r;
#pragma unroll
  for (int j = 0; j < 4; ++j) r.s[j] = f2bf(quant_e4m3(a[j]));
#pragma unroll
  for (int j = 0; j < 4; ++j) r.s[4 + j] = f2bf(quant_e4m3(b[j]));
  *(bf16x8*)(y + i) = r.v;
}

// ---------- kernel 2: W_{Q,K,V} [H,M,D] fp32 -> quant -> bf16, layout Bt[n=h*64+d][k=m] ----------

__global__ __launch_bounds__(256)
void wqkv_transpose_kernel(const float* __restrict__ w0, const float* __restrict__ w1,
                           const float* __restrict__ w2,
                           u16* __restrict__ t0, u16* __restrict__ t1, u16* __restrict__ t2) {
  const float* w = blockIdx.z == 0 ? w0 : (blockIdx.z == 1 ? w1 : w2);
  u16* wt = blockIdx.z == 0 ? t0 : (blockIdx.z == 1 ? t1 : t2);
  int h = blockIdx.x;        // 0..15
  int k0 = blockIdx.y * 64;  // m tile
  __shared__ u16 T[64][72];  // T[m_local][d]
  int t = threadIdx.x;
  int ml = t >> 2, d0 = (t & 3) * 16;
  const float* src = w + ((size_t)h * 1024 + (k0 + ml)) * 64 + d0;
  u16 q16[16];
#pragma unroll
  for (int j = 0; j < 16; j += 4) {
    f32x4 f = *(const f32x4*)(src + j);
#pragma unroll
    for (int c = 0; c < 4; ++c) q16[j + c] = f2bf(quant_e4m3(f[c]));
  }
#pragma unroll
  for (int j = 0; j < 16; ++j) T[ml][d0 + j] = q16[j];
  __syncthreads();
  int d = t >> 2, cb = t & 3;
  union { bf16x8 v; u16 s[8]; } o0, o1;
#pragma unroll
  for (int j = 0; j < 8; ++j) { o0.s[j] = T[cb * 16 + j][d]; o1.s[j] = T[cb * 16 + 8 + j][d]; }
  u16* dst = wt + (size_t)(h * 64 + d) * 1024 + k0 + cb * 16;
  *(bf16x8*)(dst) = o0.v;
  *(bf16x8*)(dst + 8) = o1.v;
}

// ---------- kernel 3: W_O [H,D,M] fp32 -> bf16 (no quant), layout Bt[n=m][k=h*64+d] ----------

__global__ __launch_bounds__(256)
void wo_transpose_kernel(const float* __restrict__ w, u16* __restrict__ wt) {
  int r0 = blockIdx.x * 64;  // hd tile
  int c0 = blockIdx.y * 64;  // m tile
  __shared__ u16 T[64][72];  // T[hd_local][m_local]
  int t = threadIdx.x;
  int rl = t >> 2, cl0 = (t & 3) * 16;
  const float* src = w + (size_t)(r0 + rl) * 1024 + c0 + cl0;
  u16 q16[16];
#pragma unroll
  for (int j = 0; j < 16; j += 4) {
    f32x4 f = *(const f32x4*)(src + j);
#pragma unroll
    for (int c = 0; c < 4; ++c) q16[j + c] = f2bf(f[c]);
  }
#pragma unroll
  for (int j = 0; j < 16; ++j) T[rl][cl0 + j] = q16[j];
  __syncthreads();
  int ml = t >> 2, cb = t & 3;
  union { bf16x8 v; u16 s[8]; } o0, o1;
#pragma unroll
  for (int j = 0; j < 8; ++j) { o0.s[j] = T[cb * 16 + j][ml]; o1.s[j] = T[cb * 16 + 8 + j][ml]; }
  u16* dst = wt + (size_t)(c0 + ml) * 1024 + r0 + cb * 16;
  *(bf16x8*)(dst) = o0.v;
  *(bf16x8*)(dst + 8) = o1.v;
}

// ---------- kernel 4: QKV GEMM: [4096,1024]x[1024,1024] bf16 -> [B,H,S,D] bf16 + bias ----------

__global__ __launch_bounds__(256)
void gemm_qkv_kernel(const u16* __restrict__ A0, const u16* __restrict__ A1, const u16* __restrict__ A2,
                     const u16* __restrict__ B0, const u16* __restrict__ B1, const u16* __restrict__ B2,
                     const float* __restrict__ bias0, const float* __restrict__ bias1,
                     const float* __restrict__ bias2,
                     u16* __restrict__ O0, u16* __restrict__ O1, u16* __restrict__ O2) {
  const int bz = blockIdx.z;
  const u16* A = bz == 0 ? A0 : (bz == 1 ? A1 : A2);
  const u16* Bt = bz == 0 ? B0 : (bz == 1 ? B1 : B2);
  const float* bias = bz == 0 ? bias0 : (bz == 1 ? bias1 : bias2);
  u16* O = bz == 0 ? O0 : (bz == 1 ? O1 : O2);

  __shared__ u16 As[128 * 64];
  __shared__ u16 Bs[128 * 64];
  const int m0 = blockIdx.x * 128;
  const int n0 = blockIdx.y * 128;
  const int tid = threadIdx.x;
  const int wave = tid >> 6, lane = tid & 63;
  const int wr = wave >> 1, wc = wave & 1;
  const int lrow = lane >> 3;
  const int lcol = (lane & 7) * 8;

  f32x4 acc[4][4] = {};

  for (int kt = 0; kt < 1024; kt += 64) {
    __syncthreads();
#pragma unroll
    for (int j = 0; j < 4; ++j) {
      int c = wave * 4 + j;
      int row = c * 8 + lrow;
      async16(A + (size_t)(m0 + row) * 1024 + kt + lcol, As + c * 512);
      async16(Bt + (size_t)(n0 + row) * 1024 + kt + lcol, Bs + c * 512);
    }
    asm volatile("s_waitcnt vmcnt(0)" ::: "memory");
    __syncthreads();
#pragma unroll
    for (int kk = 0; kk < 64; kk += 32) {
      bf16x8 af[4], bfv[4];
#pragma unroll
      for (int i = 0; i < 4; ++i) {
        af[i] = *(const bf16x8*)(As + (wr * 64 + i * 16 + (lane & 15)) * 64 + kk + 8 * (lane >> 4));
        bfv[i] = *(const bf16x8*)(Bs + (wc * 64 + i * 16 + (lane & 15)) * 64 + kk + 8 * (lane >> 4));
      }
#pragma unroll
      for (int i = 0; i < 4; ++i)
#pragma unroll
        for (int j = 0; j < 4; ++j)
          acc[i][j] = MFMA(af[i], bfv[j], acc[i][j]);
    }
  }
#pragma unroll
  for (int fm = 0; fm < 4; ++fm) {
#pragma unroll
    for (int fn = 0; fn < 4; ++fn) {
      int n = n0 + wc * 64 + fn * 16 + (lane & 15);
      int h = n >> 6, d = n & 63;
      float bv = bias[n];
#pragma unroll
      for (int i = 0; i < 4; ++i) {
        int m = m0 + wr * 64 + fm * 16 + (lane >> 4) * 4 + i;
        int b = m >> 11, s = m & 2047;
        O[(((size_t)b * 16 + h) * 2048 + s) * 64 + d] = f2bf(acc[fm][fn][i] + bv);
      }
    }
  }
}

// ---------- kernel 5: causal flash attention, bf16 MFMA ----------
// grid (S/64, B*H), 256 thr. q,k,v,z layouts: q/k/v [B,H,S,D] bf16; z [B,S,H,D] bf16.

__global__ __launch_bounds__(256)
void attn_kernel(const u16* __restrict__ q, const u16* __restrict__ k,
                 const u16* __restrict__ v, u16* __restrict__ z) {
  const int qb = blockIdx.x;
  const int bh = blockIdx.y;
  const int tid = threadIdx.x;
  const int wave = tid >> 6, lane = tid & 63;
  const size_t base = (size_t)bh * (2048 * 64);

  __shared__ u16 Ks[64 * 72];
  __shared__ u16 Vt[64 * 72];
  __shared__ u16 Ps[4][16 * 72];

  const int g = lane >> 4;   // 0..3
  const int lr = lane & 15;

  bf16x8 qf[2];
  {
    int qrow = qb * 64 + wave * 16 + lr;
    const u16* qp = q + base + (size_t)qrow * 64 + 8 * g;
    qf[0] = *(const bf16x8*)(qp);
    qf[1] = *(const bf16x8*)(qp + 32);
  }

  f32x4 o[4] = {};
  float mrow[4], lsum[4];
#pragma unroll
  for (int i = 0; i < 4; ++i) { mrow[i] = -INFINITY; lsum[i] = 0.f; }

  const int svr = tid >> 2;          // staging row 0..63
  const int sd0 = (tid & 3) * 16;

  for (int kvb = 0; kvb <= qb; ++kvb) {
    __syncthreads();
    {
      const u16* kg = k + base + (size_t)(kvb * 64 + svr) * 64 + sd0;
      bf16x8 k0 = *(const bf16x8*)(kg);
      bf16x8 k1 = *(const bf16x8*)(kg + 8);
      *(bf16x8*)(&Ks[svr * 72 + sd0]) = k0;
      *(bf16x8*)(&Ks[svr * 72 + sd0 + 8]) = k1;
      const u16* vg = v + base + (size_t)(kvb * 64 + svr) * 64 + sd0;
      bf16x8 v0 = *(const bf16x8*)(vg);
      bf16x8 v1 = *(const bf16x8*)(vg + 8);
#pragma unroll
      for (int i = 0; i < 8; ++i) {
        Vt[(sd0 + i) * 72 + svr] = (u16)v0[i];
        Vt[(sd0 + 8 + i) * 72 + svr] = (u16)v1[i];
      }
    }
    __syncthreads();

    // S = Q K^T  (per wave: 16 q rows x 64 kv)
    f32x4 sf[4] = {};
#pragma unroll
    for (int kk = 0; kk < 2; ++kk) {
#pragma unroll
      for (int f = 0; f < 4; ++f) {
        bf16x8 bv = *(const bf16x8*)(&Ks[(f * 16 + lr) * 72 + kk * 32 + 8 * g]);
        sf[f] = MFMA(qf[kk], bv, sf[f]);
      }
    }

    const int rowg = qb * 64 + wave * 16 + 4 * g;
    float sc[4][4], pmax[4];
#pragma unroll
    for (int i = 0; i < 4; ++i) pmax[i] = -INFINITY;
#pragma unroll
    for (int f = 0; f < 4; ++f) {
      int col = kvb * 64 + f * 16 + lr;
#pragma unroll
      for (int i = 0; i < 4; ++i) {
        float x = sf[f][i] * 0.125f;
        if (col > rowg + i) x = -INFINITY;
        sc[f][i] = x;
        pmax[i] = fmaxf(pmax[i], x);
      }
    }
#pragma unroll
    for (int off = 1; off < 16; off <<= 1)
#pragma unroll
      for (int i = 0; i < 4; ++i)
        pmax[i] = fmaxf(pmax[i], __shfl_xor(pmax[i], off));

    float alpha[4], rsum[4];
#pragma unroll
    for (int i = 0; i < 4; ++i) {
      float mnew = fmaxf(mrow[i], pmax[i]);
      alpha[i] = __expf(mrow[i] - mnew);
      mrow[i] = mnew;
      rsum[i] = 0.f;
    }
#pragma unroll
    for (int f = 0; f < 4; ++f) {
#pragma unroll
      for (int i = 0; i < 4; ++i) {
        float p = __expf(sc[f][i] - mrow[i]);
        rsum[i] += p;
        Ps[wave][(4 * g + i) * 72 + f * 16 + lr] = f2bf(p);
      }
    }
#pragma unroll
    for (int off = 1; off < 16; off <<= 1)
#pragma unroll
      for (int i = 0; i < 4; ++i)
        rsum[i] += __shfl_xor(rsum[i], off);
#pragma unroll
    for (int i = 0; i < 4; ++i) lsum[i] = lsum[i] * alpha[i] + rsum[i];
#pragma unroll
    for (int fd = 0; fd < 4; ++fd)
#pragma unroll
      for (int i = 0; i < 4; ++i)
        o[fd][i] *= alpha[i];

    // O += P V
#pragma unroll
    for (int kk = 0; kk < 2; ++kk) {
      bf16x8 pa = *(const bf16x8*)(&Ps[wave][lr * 72 + kk * 32 + 8 * g]);
#pragma unroll
      for (int fd = 0; fd < 4; ++fd) {
        bf16x8 vb = *(const bf16x8*)(&Vt[(fd * 16 + lr) * 72 + kk * 32 + 8 * g]);
        o[fd] = MFMA(pa, vb, o[fd]);
      }
    }
  }

  const int b = bh >> 4, h = bh & 15;
#pragma unroll
  for (int fd = 0; fd < 4; ++fd) {
    int d = fd * 16 + lr;
#pragma unroll
    for (int i = 0; i < 4; ++i) {
      int s = qb * 64 + wave * 16 + 4 * g + i;
      float zv = o[fd][i] / lsum[i];
      z[(((size_t)b * 2048 + s) * 16 + h) * 64 + d] = f2bf(zv);
    }
  }
}

// ---------- kernel 6: output projection GEMM: z[4096,1024] x WoT -> fp32 out + b_O ----------

__global__ __launch_bounds__(256)
void gemm_out_kernel(const u16* __restrict__ A, const u16* __restrict__ Bt,
                     const float* __restrict__ bias, float* __restrict__ Out) {
  __shared__ u16 As[128 * 64];
  __shared__ u16 Bs[128 * 64];
  const int m0 = blockIdx.x * 128;
  const int n0 = blockIdx.y * 128;
  const int tid = threadIdx.x;
  const int wave = tid >> 6, lane = tid & 63;
  const int wr = wave >> 1, wc = wave & 1;
  const int lrow = lane >> 3;
  const int lcol = (lane & 7) * 8;

  f32x4 acc[4][4] = {};

  for (int kt = 0; kt < 1024; kt += 64) {
    __syncthreads();
#pragma unroll
    for (int j = 0; j < 4; ++j) {
      int c = wave * 4 + j;
      int row = c * 8 + lrow;
      async16(A + (size_t)(m0 + row) * 1024 + kt + lcol, As + c * 512);
      async16(Bt + (size_t)(n0 + row) * 1024 + kt + lcol, Bs + c * 512);
    }
    asm volatile("s_waitcnt vmcnt(0)" ::: "memory");
    __syncthreads();
#pragma unroll
    for (int kk = 0; kk < 64; kk += 32) {
      bf16x8 af[4], bfv[4];
#pragma unroll
      for (int i = 0; i < 4; ++i) {
        af[i] = *(const bf16x8*)(As + (wr * 64 + i * 16 + (lane & 15)) * 64 + kk + 8 * (lane >> 4));
        bfv[i] = *(const bf16x8*)(Bs + (wc * 64 + i * 16 + (lane & 15)) * 64 + kk + 8 * (lane >> 4));
      }
#pragma unroll
      for (int i = 0; i < 4; ++i)
#pragma unroll
        for (int j = 0; j < 4; ++j)
          acc[i][j] = MFMA(af[i], bfv[j], acc[i][j]);
    }
  }
#pragma unroll
  for (int fm = 0; fm < 4; ++fm) {
#pragma unroll
    for (int fn = 0; fn < 4; ++fn) {
      int n = n0 + wc * 64 + fn * 16 + (lane & 15);
      float bv = bias[n];
#pragma unroll
      for (int i = 0; i < 4; ++i) {
        int m = m0 + wr * 64 + fm * 16 + (lane >> 4) * 4 + i;
        Out[(size_t)m * 1024 + n] = acc[fm][fn][i] + bv;
      }
    }
  }
}

// ---------- launcher ----------

extern "C" void kernel_launch(void* const* d_in, const int* in_sizes, int n_in,
                              void* d_out, int out_size, void* d_ws, size_t ws_size,
                              hipStream_t stream) {
  const float* xq = (const float*)d_in[0];
  const float* xk = (const float*)d_in[1];
  const float* xv = (const float*)d_in[2];
  const float* WQ = (const float*)d_in[3];
  const float* WK = (const float*)d_in[4];
  const float* WV = (const float*)d_in[5];
  const float* WO = (const float*)d_in[6];
  const float* bQ = (const float*)d_in[7];
  const float* bK = (const float*)d_in[8];
  const float* bV = (const float*)d_in[9];
  const float* bO = (const float*)d_in[10];
  float* out = (float*)d_out;

  char* ws = (char*)d_ws;
  const size_t MB = 1024 * 1024;
  u16* Xq = (u16*)(ws);             // 8MB each (4096x1024 bf16)
  u16* Xk = (u16*)(ws + 8 * MB);
  u16* Xv = (u16*)(ws + 16 * MB);
  u16* WqT = (u16*)(ws + 24 * MB);  // 2MB each (1024x1024 bf16)
  u16* WkT = (u16*)(ws + 26 * MB);
  u16* WvT = (u16*)(ws + 28 * MB);
  u16* WoT = (u16*)(ws + 30 * MB);
  u16* Q = (u16*)(ws + 32 * MB);    // 8MB each [B,H,S,D] bf16
  u16* K = (u16*)(ws + 40 * MB);
  u16* V = (u16*)(ws + 48 * MB);
  u16* Z = (u16*)(ws + 56 * MB);    // 8MB [B,S,H,D] bf16

  quant_inputs_kernel<<<dim3(2048, 3), 256, 0, stream>>>(xq, xk, xv, Xq, Xk, Xv);
  wqkv_transpose_kernel<<<dim3(16, 16, 3), 256, 0, stream>>>(WQ, WK, WV, WqT, WkT, WvT);
  wo_transpose_kernel<<<dim3(16, 16), 256, 0, stream>>>(WO, WoT);
  gemm_qkv_kernel<<<dim3(32, 8, 3), 256, 0, stream>>>(Xq, Xk, Xv, WqT, WkT, WvT, bQ, bK, bV, Q, K, V);
  attn_kernel<<<dim3(32, 32), 256, 0, stream>>>(Q, K, V, Z);
  gemm_out_kernel<<<dim3(32, 8), 256, 0, stream>>>(Z, WoT, bO, out);
}

// Round 2
// 175.527 us; speedup vs baseline: 1.3201x; 1.3201x over previous
//
#include <hip/hip_runtime.h>
#include <cstdint>
#include <cmath>

typedef __attribute__((ext_vector_type(4))) float f32x4;
typedef __attribute__((ext_vector_type(16))) float f32x16;
typedef __attribute__((ext_vector_type(8))) short bf16x8;
using u16 = unsigned short;
using u32 = uint32_t;

// ---------- helpers ----------

static __device__ __forceinline__ u16 f2bf(float f) {
  uint32_t u = __float_as_uint(f);
  u += 0x7fffu + ((u >> 16) & 1u);
  return (u16)(u >> 16);
}

// round f32 to float8_e4m3fn (RNE), return dequantized f32.
static __device__ __forceinline__ float quant_e4m3(float x) {
  uint32_t u = __float_as_uint(x);
  uint32_t absu = u & 0x7fffffffu;
  if (absu >= 0x3c800000u) {  // |x| >= 2^-6 : e4m3 normal, keep 3 mantissa bits RNE
    uint32_t lsb = (absu >> 20) & 1u;
    uint32_t r = (absu + 0x7ffffu + lsb) & ~0xfffffu;
    return __uint_as_float((u & 0x80000000u) | r);
  }
  return rintf(x * 512.0f) * 0.001953125f;
}

static __device__ __forceinline__ void async16(const void* g, void* l) {
  __builtin_amdgcn_global_load_lds(
      (const __attribute__((address_space(1))) void*)g,
      (__attribute__((address_space(3))) void*)l, 16, 0, 0);
}

static __device__ __forceinline__ u32 cvtpk(float a, float b) {
  u32 r;
  asm("v_cvt_pk_bf16_f32 %0, %1, %2" : "=v"(r) : "v"(a), "v"(b));
  return r;
}

#define MFMA(a, b, c) __builtin_amdgcn_mfma_f32_16x16x32_bf16(a, b, c, 0, 0, 0)
#define MFMA32(a, b, c) __builtin_amdgcn_mfma_f32_32x32x16_bf16(a, b, c, 0, 0, 0)

// ---------- kernel 1: quantize activations fp32 -> e4m3 -> bf16 ----------

__global__ __launch_bounds__(256)
void quant_inputs_kernel(const float* __restrict__ x0, const float* __restrict__ x1,
                         const float* __restrict__ x2,
                         u16* __restrict__ y0, u16* __restrict__ y1, u16* __restrict__ y2) {
  const float* x = blockIdx.y == 0 ? x0 : (blockIdx.y == 1 ? x1 : x2);
  u16* y = blockIdx.y == 0 ? y0 : (blockIdx.y == 1 ? y1 : y2);
  int i = (blockIdx.x * 256 + threadIdx.x) * 8;
  f32x4 a = *(const f32x4*)(x + i);
  f32x4 b = *(const f32x4*)(x + i + 4);
  union { bf16x8 v; u16 s[8]; } r;
#pragma unroll
  for (int j = 0; j < 4; ++j) r.s[j] = f2bf(quant_e4m3(a[j]));
#pragma unroll
  for (int j = 0; j < 4; ++j) r.s[4 + j] = f2bf(quant_e4m3(b[j]));
  *(bf16x8*)(y + i) = r.v;
}

// ---------- kernel 2: W_{Q,K,V} [H,M,D] fp32 -> quant -> bf16, layout Bt[n=h*64+d][k=m] ----------

__global__ __launch_bounds__(256)
void wqkv_transpose_kernel(const float* __restrict__ w0, const float* __restrict__ w1,
                           const float* __restrict__ w2,
                           u16* __restrict__ t0, u16* __restrict__ t1, u16* __restrict__ t2) {
  const float* w = blockIdx.z == 0 ? w0 : (blockIdx.z == 1 ? w1 : w2);
  u16* wt = blockIdx.z == 0 ? t0 : (blockIdx.z == 1 ? t1 : t2);
  int h = blockIdx.x;        // 0..15
  int k0 = blockIdx.y * 64;  // m tile
  __shared__ u16 T[64][72];  // T[m_local][d]
  int t = threadIdx.x;
  int ml = t >> 2, d0 = (t & 3) * 16;
  const float* src = w + ((size_t)h * 1024 + (k0 + ml)) * 64 + d0;
  u16 q16[16];
#pragma unroll
  for (int j = 0; j < 16; j += 4) {
    f32x4 f = *(const f32x4*)(src + j);
#pragma unroll
    for (int c = 0; c < 4; ++c) q16[j + c] = f2bf(quant_e4m3(f[c]));
  }
#pragma unroll
  for (int j = 0; j < 16; ++j) T[ml][d0 + j] = q16[j];
  __syncthreads();
  int d = t >> 2, cb = t & 3;
  union { bf16x8 v; u16 s[8]; } o0, o1;
#pragma unroll
  for (int j = 0; j < 8; ++j) { o0.s[j] = T[cb * 16 + j][d]; o1.s[j] = T[cb * 16 + 8 + j][d]; }
  u16* dst = wt + (size_t)(h * 64 + d) * 1024 + k0 + cb * 16;
  *(bf16x8*)(dst) = o0.v;
  *(bf16x8*)(dst + 8) = o1.v;
}

// ---------- kernel 3: W_O [H,D,M] fp32 -> bf16 (no quant), layout Bt[n=m][k=h*64+d] ----------

__global__ __launch_bounds__(256)
void wo_transpose_kernel(const float* __restrict__ w, u16* __restrict__ wt) {
  int r0 = blockIdx.x * 64;  // hd tile
  int c0 = blockIdx.y * 64;  // m tile
  __shared__ u16 T[64][72];
  int t = threadIdx.x;
  int rl = t >> 2, cl0 = (t & 3) * 16;
  const float* src = w + (size_t)(r0 + rl) * 1024 + c0 + cl0;
  u16 q16[16];
#pragma unroll
  for (int j = 0; j < 16; j += 4) {
    f32x4 f = *(const f32x4*)(src + j);
#pragma unroll
    for (int c = 0; c < 4; ++c) q16[j + c] = f2bf(f[c]);
  }
#pragma unroll
  for (int j = 0; j < 16; ++j) T[rl][cl0 + j] = q16[j];
  __syncthreads();
  int ml = t >> 2, cb = t & 3;
  union { bf16x8 v; u16 s[8]; } o0, o1;
#pragma unroll
  for (int j = 0; j < 8; ++j) { o0.s[j] = T[cb * 16 + j][ml]; o1.s[j] = T[cb * 16 + 8 + j][ml]; }
  u16* dst = wt + (size_t)(c0 + ml) * 1024 + r0 + cb * 16;
  *(bf16x8*)(dst) = o0.v;
  *(bf16x8*)(dst + 8) = o1.v;
}

// ---------- kernel 4: QKV GEMM -> Q,K: [B,H,S,D] bf16 ; V: [B,H,D,S] bf16 (transposed) ----------

__global__ __launch_bounds__(256)
void gemm_qkv_kernel(const u16* __restrict__ A0, const u16* __restrict__ A1, const u16* __restrict__ A2,
                     const u16* __restrict__ B0, const u16* __restrict__ B1, const u16* __restrict__ B2,
                     const float* __restrict__ bias0, const float* __restrict__ bias1,
                     const float* __restrict__ bias2,
                     u16* __restrict__ O0, u16* __restrict__ O1, u16* __restrict__ O2) {
  const int bz = blockIdx.z;
  const u16* A = bz == 0 ? A0 : (bz == 1 ? A1 : A2);
  const u16* Bt = bz == 0 ? B0 : (bz == 1 ? B1 : B2);
  const float* bias = bz == 0 ? bias0 : (bz == 1 ? bias1 : bias2);
  u16* O = bz == 0 ? O0 : (bz == 1 ? O1 : O2);

  __shared__ u16 As[128 * 64];
  __shared__ u16 Bs[128 * 64];
  const int m0 = blockIdx.x * 128;
  const int n0 = blockIdx.y * 128;
  const int tid = threadIdx.x;
  const int wave = tid >> 6, lane = tid & 63;
  const int wr = wave >> 1, wc = wave & 1;
  const int lrow = lane >> 3;
  const int lcol = (lane & 7) * 8;

  f32x4 acc[4][4] = {};

  for (int kt = 0; kt < 1024; kt += 64) {
    __syncthreads();
#pragma unroll
    for (int j = 0; j < 4; ++j) {
      int c = wave * 4 + j;
      int row = c * 8 + lrow;
      async16(A + (size_t)(m0 + row) * 1024 + kt + lcol, As + c * 512);
      async16(Bt + (size_t)(n0 + row) * 1024 + kt + lcol, Bs + c * 512);
    }
    asm volatile("s_waitcnt vmcnt(0)" ::: "memory");
    __syncthreads();
#pragma unroll
    for (int kk = 0; kk < 64; kk += 32) {
      bf16x8 af[4], bfv[4];
#pragma unroll
      for (int i = 0; i < 4; ++i) {
        af[i] = *(const bf16x8*)(As + (wr * 64 + i * 16 + (lane & 15)) * 64 + kk + 8 * (lane >> 4));
        bfv[i] = *(const bf16x8*)(Bs + (wc * 64 + i * 16 + (lane & 15)) * 64 + kk + 8 * (lane >> 4));
      }
#pragma unroll
      for (int i = 0; i < 4; ++i)
#pragma unroll
        for (int j = 0; j < 4; ++j)
          acc[i][j] = MFMA(af[i], bfv[j], acc[i][j]);
    }
  }
  if (bz == 2) {
    // V^T: [B,H,D,S]
#pragma unroll
    for (int fm = 0; fm < 4; ++fm) {
#pragma unroll
      for (int fn = 0; fn < 4; ++fn) {
        int n = n0 + wc * 64 + fn * 16 + (lane & 15);
        int hh = n >> 6, d = n & 63;
        float bv = bias[n];
        int m_base = m0 + wr * 64 + fm * 16 + (lane >> 4) * 4;
        int b = m_base >> 11, s = m_base & 2047;
        union { u16 s4[4]; uint2 u2; } pk;
#pragma unroll
        for (int i = 0; i < 4; ++i) pk.s4[i] = f2bf(acc[fm][fn][i] + bv);
        *(uint2*)(&O[(((size_t)b * 16 + hh) * 64 + d) * 2048 + s]) = pk.u2;
      }
    }
  } else {
#pragma unroll
    for (int fm = 0; fm < 4; ++fm) {
#pragma unroll
      for (int fn = 0; fn < 4; ++fn) {
        int n = n0 + wc * 64 + fn * 16 + (lane & 15);
        int hh = n >> 6, d = n & 63;
        float bv = bias[n];
#pragma unroll
        for (int i = 0; i < 4; ++i) {
          int m = m0 + wr * 64 + fm * 16 + (lane >> 4) * 4 + i;
          int b = m >> 11, s = m & 2047;
          O[(((size_t)b * 16 + hh) * 2048 + s) * 64 + d] = f2bf(acc[fm][fn][i] + bv);
        }
      }
    }
  }
}

// ---------- kernel 5: causal flash attention, 32x32x16 MFMA, swapped operands ----------
// grid (16, 32) = (q-tile-id, b*16+h). 256 thr = 4 waves, 32 q-rows/wave.
// K: [B,H,S,D]; Vt: [B,H,D,S]; z: [B,S,H*D].
// Work pairing: blocks (x,y) and (x,y+16) get complementary qb -> equal per-CU load.

__global__ __launch_bounds__(256)
void attn_kernel(const u16* __restrict__ q, const u16* __restrict__ k,
                 const u16* __restrict__ vt, u16* __restrict__ z) {
  const int bx = blockIdx.x, by = blockIdx.y;
  const int qb = (by < 16) ? bx : (15 - bx);
  const int bh = by;
  const int tid = threadIdx.x;
  const int w = tid >> 6, lane = tid & 63;
  const int l31 = lane & 31, h = lane >> 5;
  const int swz = lane & 7;
  const size_t base = (size_t)bh * (2048 * 64);

  __shared__ u16 Ks[2][64 * 64];
  __shared__ u16 Vs[2][64 * 64];

  const int wq0 = qb * 128 + w * 32;
  const int q_glob = wq0 + l31;

  // Q fragments: B-operand, lane holds Q[q=l31][d = 16*kk + 8*h + j]
  bf16x8 qf[4];
  {
    const u16* qp = q + base + (size_t)q_glob * 64 + 8 * h;
#pragma unroll
    for (int kk = 0; kk < 4; ++kk) qf[kk] = *(const bf16x8*)(qp + 16 * kk);
  }

  // staging geometry: lane writes LDS row chunk*8+(lane>>3), 16B-group lane&7 (linear);
  // source 16B-group pre-swizzled: (lane&7) ^ (lane>>3)  [involution, rule #21]
  const int r8 = lane >> 3;
  const int cg = (lane & 7) ^ r8;
  const int c0 = 2 * w;  // this wave's chunks: c0, c0+1 (8 rows each) for both K and Vt

  f32x16 oa0 = {}, oa1 = {};   // O^T acc: lane holds q=l31, d rows
  float mreg = -1e30f, lsum = 0.f;

  const int ntiles = 2 * qb + 2;

  // prologue: stage tile 0 into buf 0
#pragma unroll
  for (int c = 0; c < 2; ++c) {
    int chunk = c0 + c;
    int row = chunk * 8 + r8;
    async16(k + base + (size_t)row * 64 + cg * 8, &Ks[0][chunk * 512]);
    async16(vt + base + (size_t)row * 2048 + cg * 8, &Vs[0][chunk * 512]);
  }

  int cur = 0;
  for (int t = 0; t < ntiles; ++t) {
    const int kv0 = t * 64;
    if (t + 1 < ntiles) {
      const int kv1 = kv0 + 64;
#pragma unroll
      for (int c = 0; c < 2; ++c) {
        int chunk = c0 + c;
        int row = chunk * 8 + r8;
        async16(k + base + (size_t)(kv1 + row) * 64 + cg * 8, &Ks[cur ^ 1][chunk * 512]);
        async16(vt + base + (size_t)row * 2048 + kv1 + cg * 8, &Vs[cur ^ 1][chunk * 512]);
      }
      asm volatile("s_waitcnt vmcnt(4)" ::: "memory");  // current tile landed; next 4 in flight
    } else {
      asm volatile("s_waitcnt vmcnt(0)" ::: "memory");
    }
    __builtin_amdgcn_s_barrier();

    if (kv0 <= wq0 + 31) {  // skip fully-masked tiles (wave-uniform)
      // S^T = K Q^T : acc lane holds q=l31, kv = 32f + (rg&3)+8*(rg>>2)+4*h
      f32x16 sa[2] = {};
#pragma unroll
      for (int kk = 0; kk < 4; ++kk) {
        const int colo = ((2 * kk + h) ^ swz) * 8;
        bf16x8 k0 = *(const bf16x8*)(&Ks[cur][l31 * 64 + colo]);
        bf16x8 k1 = *(const bf16x8*)(&Ks[cur][(32 + l31) * 64 + colo]);
        sa[0] = MFMA32(k0, qf[kk], sa[0]);
        sa[1] = MFMA32(k1, qf[kk], sa[1]);
      }
      const float SCL = 0.18033688011112042f;  // log2(e)/sqrt(64)
      const bool diag = (kv0 + 63 > wq0);
      float pmax = -1e30f;
#pragma unroll
      for (int f = 0; f < 2; ++f)
#pragma unroll
        for (int rg = 0; rg < 16; ++rg) {
          float x = sa[f][rg] * SCL;
          if (diag) {
            int kvg = kv0 + 32 * f + (rg & 3) + 8 * (rg >> 2) + 4 * h;
            if (kvg > q_glob) x = -1e30f;
          }
          sa[f][rg] = x;
          pmax = fmaxf(pmax, x);
        }
      pmax = fmaxf(pmax, __shfl_xor(pmax, 32));
      const float mnew = fmaxf(mreg, pmax);
      const float alpha = exp2f(mreg - mnew);
      mreg = mnew;
      float rsum = 0.f;
      u32 P32[2][4][2];
#pragma unroll
      for (int f = 0; f < 2; ++f)
#pragma unroll
        for (int tt = 0; tt < 4; ++tt)
#pragma unroll
          for (int cc = 0; cc < 2; ++cc) {
            float p0 = exp2f(sa[f][4 * tt + 2 * cc] - mnew);
            float p1 = exp2f(sa[f][4 * tt + 2 * cc + 1] - mnew);
            rsum += p0 + p1;
            P32[f][tt][cc] = cvtpk(p0, p1);
          }
      rsum += __shfl_xor(rsum, 32);
      lsum = lsum * alpha + rsum;
#pragma unroll
      for (int i = 0; i < 16; ++i) { oa0[i] *= alpha; oa1[i] *= alpha; }

      // exchange P into B-fragment layout (kv = 16*kk + 8*h + j) and do O^T += V^T P^T
#pragma unroll
      for (int kk = 0; kk < 4; ++kk) {
        const int fp = kk >> 1;
        const int ta = 2 * (kk & 1);
        union { u32 u[4]; bf16x8 v; } pb;
#pragma unroll
        for (int cc = 0; cc < 2; ++cc) {
          u32 a = P32[fp][ta][cc], b = P32[fp][ta + 1][cc];
          u32 sb = (u32)__shfl_xor((int)b, 32);
          u32 sa2 = (u32)__shfl_xor((int)a, 32);
          pb.u[cc] = h ? sb : a;
          pb.u[2 + cc] = h ? b : sa2;
        }
        const int colo = ((2 * kk + h) ^ swz) * 8;
        bf16x8 v0 = *(const bf16x8*)(&Vs[cur][l31 * 64 + colo]);
        bf16x8 v1 = *(const bf16x8*)(&Vs[cur][(32 + l31) * 64 + colo]);
        oa0 = MFMA32(v0, pb.v, oa0);
        oa1 = MFMA32(v1, pb.v, oa1);
      }
    }
    asm volatile("s_waitcnt lgkmcnt(0)" ::: "memory");
    __builtin_amdgcn_s_barrier();
    cur ^= 1;
  }

  const float inv = 1.f / lsum;
  const int b_ = bh >> 4, head = bh & 15;
  u16* zp = z + ((size_t)b_ * 2048 + q_glob) * 1024 + head * 64;
#pragma unroll
  for (int fd = 0; fd < 2; ++fd)
#pragma unroll
    for (int tt = 0; tt < 4; ++tt) {
      union { u16 s[4]; uint2 u2; } pk;
#pragma unroll
      for (int i = 0; i < 4; ++i) {
        float ov = (fd ? oa1[4 * tt + i] : oa0[4 * tt + i]) * inv;
        pk.s[i] = f2bf(ov);
      }
      *(uint2*)(zp + fd * 32 + tt * 8 + 4 * h) = pk.u2;
    }
}

// ---------- kernel 6: output projection GEMM: z[4096,1024] x WoT -> fp32 out + b_O ----------

__global__ __launch_bounds__(256)
void gemm_out_kernel(const u16* __restrict__ A, const u16* __restrict__ Bt,
                     const float* __restrict__ bias, float* __restrict__ Out) {
  __shared__ u16 As[128 * 64];
  __shared__ u16 Bs[128 * 64];
  const int m0 = blockIdx.x * 128;
  const int n0 = blockIdx.y * 128;
  const int tid = threadIdx.x;
  const int wave = tid >> 6, lane = tid & 63;
  const int wr = wave >> 1, wc = wave & 1;
  const int lrow = lane >> 3;
  const int lcol = (lane & 7) * 8;

  f32x4 acc[4][4] = {};

  for (int kt = 0; kt < 1024; kt += 64) {
    __syncthreads();
#pragma unroll
    for (int j = 0; j < 4; ++j) {
      int c = wave * 4 + j;
      int row = c * 8 + lrow;
      async16(A + (size_t)(m0 + row) * 1024 + kt + lcol, As + c * 512);
      async16(Bt + (size_t)(n0 + row) * 1024 + kt + lcol, Bs + c * 512);
    }
    asm volatile("s_waitcnt vmcnt(0)" ::: "memory");
    __syncthreads();
#pragma unroll
    for (int kk = 0; kk < 64; kk += 32) {
      bf16x8 af[4], bfv[4];
#pragma unroll
      for (int i = 0; i < 4; ++i) {
        af[i] = *(const bf16x8*)(As + (wr * 64 + i * 16 + (lane & 15)) * 64 + kk + 8 * (lane >> 4));
        bfv[i] = *(const bf16x8*)(Bs + (wc * 64 + i * 16 + (lane & 15)) * 64 + kk + 8 * (lane >> 4));
      }
#pragma unroll
      for (int i = 0; i < 4; ++i)
#pragma unroll
        for (int j = 0; j < 4; ++j)
          acc[i][j] = MFMA(af[i], bfv[j], acc[i][j]);
    }
  }
#pragma unroll
  for (int fm = 0; fm < 4; ++fm) {
#pragma unroll
    for (int fn = 0; fn < 4; ++fn) {
      int n = n0 + wc * 64 + fn * 16 + (lane & 15);
      float bv = bias[n];
#pragma unroll
      for (int i = 0; i < 4; ++i) {
        int m = m0 + wr * 64 + fm * 16 + (lane >> 4) * 4 + i;
        Out[(size_t)m * 1024 + n] = acc[fm][fn][i] + bv;
      }
    }
  }
}

// ---------- launcher ----------

extern "C" void kernel_launch(void* const* d_in, const int* in_sizes, int n_in,
                              void* d_out, int out_size, void* d_ws, size_t ws_size,
                              hipStream_t stream) {
  const float* xq = (const float*)d_in[0];
  const float* xk = (const float*)d_in[1];
  const float* xv = (const float*)d_in[2];
  const float* WQ = (const float*)d_in[3];
  const float* WK = (const float*)d_in[4];
  const float* WV = (const float*)d_in[5];
  const float* WO = (const float*)d_in[6];
  const float* bQ = (const float*)d_in[7];
  const float* bK = (const float*)d_in[8];
  const float* bV = (const float*)d_in[9];
  const float* bO = (const float*)d_in[10];
  float* out = (float*)d_out;

  char* ws = (char*)d_ws;
  const size_t MB = 1024 * 1024;
  u16* Xq = (u16*)(ws);             // 8MB each (4096x1024 bf16)
  u16* Xk = (u16*)(ws + 8 * MB);
  u16* Xv = (u16*)(ws + 16 * MB);
  u16* WqT = (u16*)(ws + 24 * MB);  // 2MB each (1024x1024 bf16)
  u16* WkT = (u16*)(ws + 26 * MB);
  u16* WvT = (u16*)(ws + 28 * MB);
  u16* WoT = (u16*)(ws + 30 * MB);
  u16* Q = (u16*)(ws + 32 * MB);    // 8MB [B,H,S,D]
  u16* K = (u16*)(ws + 40 * MB);    // 8MB [B,H,S,D]
  u16* V = (u16*)(ws + 48 * MB);    // 8MB [B,H,D,S]  (transposed)
  u16* Z = (u16*)(ws + 56 * MB);    // 8MB [B,S,H,D]

  quant_inputs_kernel<<<dim3(2048, 3), 256, 0, stream>>>(xq, xk, xv, Xq, Xk, Xv);
  wqkv_transpose_kernel<<<dim3(16, 16, 3), 256, 0, stream>>>(WQ, WK, WV, WqT, WkT, WvT);
  wo_transpose_kernel<<<dim3(16, 16), 256, 0, stream>>>(WO, WoT);
  gemm_qkv_kernel<<<dim3(32, 8, 3), 256, 0, stream>>>(Xq, Xk, Xv, WqT, WkT, WvT, bQ, bK, bV, Q, K, V);
  attn_kernel<<<dim3(16, 32), 256, 0, stream>>>(Q, K, V, Z);
  gemm_out_kernel<<<dim3(32, 8), 256, 0, stream>>>(Z, WoT, bO, out);
}

// Round 3
// 157.587 us; speedup vs baseline: 1.4704x; 1.1138x over previous
//
#include <hip/hip_runtime.h>
#include <cstdint>
#include <cmath>

typedef __attribute__((ext_vector_type(4))) float f32x4;
typedef __attribute__((ext_vector_type(16))) float f32x16;
typedef __attribute__((ext_vector_type(8))) short bf16x8;
using u16 = unsigned short;
using u32 = uint32_t;

// ---------- helpers ----------

static __device__ __forceinline__ u16 f2bf(float f) {
  uint32_t u = __float_as_uint(f);
  u += 0x7fffu + ((u >> 16) & 1u);
  return (u16)(u >> 16);
}

// round f32 to float8_e4m3fn (RNE), return dequantized f32.
static __device__ __forceinline__ float quant_e4m3(float x) {
  uint32_t u = __float_as_uint(x);
  uint32_t absu = u & 0x7fffffffu;
  if (absu >= 0x3c800000u) {  // |x| >= 2^-6 : e4m3 normal, keep 3 mantissa bits RNE
    uint32_t lsb = (absu >> 20) & 1u;
    uint32_t r = (absu + 0x7ffffu + lsb) & ~0xfffffu;
    return __uint_as_float((u & 0x80000000u) | r);
  }
  return rintf(x * 512.0f) * 0.001953125f;
}

static __device__ __forceinline__ void async16(const void* g, void* l) {
  __builtin_amdgcn_global_load_lds(
      (const __attribute__((address_space(1))) void*)g,
      (__attribute__((address_space(3))) void*)l, 16, 0, 0);
}

static __device__ __forceinline__ u32 cvtpk(float a, float b) {
  u32 r;
  asm("v_cvt_pk_bf16_f32 %0, %1, %2" : "=v"(r) : "v"(a), "v"(b));
  return r;
}

#define MFMA(a, b, c) __builtin_amdgcn_mfma_f32_16x16x32_bf16(a, b, c, 0, 0, 0)
#define MFMA32(a, b, c) __builtin_amdgcn_mfma_f32_32x32x16_bf16(a, b, c, 0, 0, 0)

// log2(e)/sqrt(64): folded into Q at projection time so attn uses exp2 directly.
#define QSCALE 0.18033688011112042f

// ---------- kernel 1: quantize activations fp32 -> e4m3 -> bf16 ----------

__global__ __launch_bounds__(256)
void quant_inputs_kernel(const float* __restrict__ x0, const float* __restrict__ x1,
                         const float* __restrict__ x2,
                         u16* __restrict__ y0, u16* __restrict__ y1, u16* __restrict__ y2) {
  const float* x = blockIdx.y == 0 ? x0 : (blockIdx.y == 1 ? x1 : x2);
  u16* y = blockIdx.y == 0 ? y0 : (blockIdx.y == 1 ? y1 : y2);
  int i = (blockIdx.x * 256 + threadIdx.x) * 8;
  f32x4 a = *(const f32x4*)(x + i);
  f32x4 b = *(const f32x4*)(x + i + 4);
  union { bf16x8 v; u16 s[8]; } r;
#pragma unroll
  for (int j = 0; j < 4; ++j) r.s[j] = f2bf(quant_e4m3(a[j]));
#pragma unroll
  for (int j = 0; j < 4; ++j) r.s[4 + j] = f2bf(quant_e4m3(b[j]));
  *(bf16x8*)(y + i) = r.v;
}

// ---------- kernel 2: W_{Q,K,V} [H,M,D] fp32 -> quant -> bf16, layout Bt[n=h*64+d][k=m] ----------

__global__ __launch_bounds__(256)
void wqkv_transpose_kernel(const float* __restrict__ w0, const float* __restrict__ w1,
                           const float* __restrict__ w2,
                           u16* __restrict__ t0, u16* __restrict__ t1, u16* __restrict__ t2) {
  const float* w = blockIdx.z == 0 ? w0 : (blockIdx.z == 1 ? w1 : w2);
  u16* wt = blockIdx.z == 0 ? t0 : (blockIdx.z == 1 ? t1 : t2);
  int h = blockIdx.x;        // 0..15
  int k0 = blockIdx.y * 64;  // m tile
  __shared__ u16 T[64][72];  // T[m_local][d]
  int t = threadIdx.x;
  int ml = t >> 2, d0 = (t & 3) * 16;
  const float* src = w + ((size_t)h * 1024 + (k0 + ml)) * 64 + d0;
  u16 q16[16];
#pragma unroll
  for (int j = 0; j < 16; j += 4) {
    f32x4 f = *(const f32x4*)(src + j);
#pragma unroll
    for (int c = 0; c < 4; ++c) q16[j + c] = f2bf(quant_e4m3(f[c]));
  }
#pragma unroll
  for (int j = 0; j < 16; ++j) T[ml][d0 + j] = q16[j];
  __syncthreads();
  int d = t >> 2, cb = t & 3;
  union { bf16x8 v; u16 s[8]; } o0, o1;
#pragma unroll
  for (int j = 0; j < 8; ++j) { o0.s[j] = T[cb * 16 + j][d]; o1.s[j] = T[cb * 16 + 8 + j][d]; }
  u16* dst = wt + (size_t)(h * 64 + d) * 1024 + k0 + cb * 16;
  *(bf16x8*)(dst) = o0.v;
  *(bf16x8*)(dst + 8) = o1.v;
}

// ---------- kernel 3: W_O [H,D,M] fp32 -> bf16 (no quant), layout Bt[n=m][k=h*64+d] ----------

__global__ __launch_bounds__(256)
void wo_transpose_kernel(const float* __restrict__ w, u16* __restrict__ wt) {
  int r0 = blockIdx.x * 64;  // hd tile
  int c0 = blockIdx.y * 64;  // m tile
  __shared__ u16 T[64][72];
  int t = threadIdx.x;
  int rl = t >> 2, cl0 = (t & 3) * 16;
  const float* src = w + (size_t)(r0 + rl) * 1024 + c0 + cl0;
  u16 q16[16];
#pragma unroll
  for (int j = 0; j < 16; j += 4) {
    f32x4 f = *(const f32x4*)(src + j);
#pragma unroll
    for (int c = 0; c < 4; ++c) q16[j + c] = f2bf(f[c]);
  }
#pragma unroll
  for (int j = 0; j < 16; ++j) T[rl][cl0 + j] = q16[j];
  __syncthreads();
  int ml = t >> 2, cb = t & 3;
  union { bf16x8 v; u16 s[8]; } o0, o1;
#pragma unroll
  for (int j = 0; j < 8; ++j) { o0.s[j] = T[cb * 16 + j][ml]; o1.s[j] = T[cb * 16 + 8 + j][ml]; }
  u16* dst = wt + (size_t)(c0 + ml) * 1024 + r0 + cb * 16;
  *(bf16x8*)(dst) = o0.v;
  *(bf16x8*)(dst + 8) = o1.v;
}

// ---------- kernel 4: QKV GEMM -> Q (prescaled), K: [B,H,S,D] bf16 ; V: [B,H,D,S] bf16 ----------

__global__ __launch_bounds__(256)
void gemm_qkv_kernel(const u16* __restrict__ A0, const u16* __restrict__ A1, const u16* __restrict__ A2,
                     const u16* __restrict__ B0, const u16* __restrict__ B1, const u16* __restrict__ B2,
                     const float* __restrict__ bias0, const float* __restrict__ bias1,
                     const float* __restrict__ bias2,
                     u16* __restrict__ O0, u16* __restrict__ O1, u16* __restrict__ O2) {
  const int bz = blockIdx.z;
  const u16* A = bz == 0 ? A0 : (bz == 1 ? A1 : A2);
  const u16* Bt = bz == 0 ? B0 : (bz == 1 ? B1 : B2);
  const float* bias = bz == 0 ? bias0 : (bz == 1 ? bias1 : bias2);
  u16* O = bz == 0 ? O0 : (bz == 1 ? O1 : O2);

  __shared__ u16 As[128 * 64];
  __shared__ u16 Bs[128 * 64];
  const int m0 = blockIdx.x * 128;
  const int n0 = blockIdx.y * 128;
  const int tid = threadIdx.x;
  const int wave = tid >> 6, lane = tid & 63;
  const int wr = wave >> 1, wc = wave & 1;
  const int lrow = lane >> 3;
  const int lcol = (lane & 7) * 8;

  f32x4 acc[4][4] = {};

  for (int kt = 0; kt < 1024; kt += 64) {
    __syncthreads();
#pragma unroll
    for (int j = 0; j < 4; ++j) {
      int c = wave * 4 + j;
      int row = c * 8 + lrow;
      async16(A + (size_t)(m0 + row) * 1024 + kt + lcol, As + c * 512);
      async16(Bt + (size_t)(n0 + row) * 1024 + kt + lcol, Bs + c * 512);
    }
    asm volatile("s_waitcnt vmcnt(0)" ::: "memory");
    __syncthreads();
#pragma unroll
    for (int kk = 0; kk < 64; kk += 32) {
      bf16x8 af[4], bfv[4];
#pragma unroll
      for (int i = 0; i < 4; ++i) {
        af[i] = *(const bf16x8*)(As + (wr * 64 + i * 16 + (lane & 15)) * 64 + kk + 8 * (lane >> 4));
        bfv[i] = *(const bf16x8*)(Bs + (wc * 64 + i * 16 + (lane & 15)) * 64 + kk + 8 * (lane >> 4));
      }
#pragma unroll
      for (int i = 0; i < 4; ++i)
#pragma unroll
        for (int j = 0; j < 4; ++j)
          acc[i][j] = MFMA(af[i], bfv[j], acc[i][j]);
    }
  }
  if (bz == 2) {
    // V^T: [B,H,D,S]
#pragma unroll
    for (int fm = 0; fm < 4; ++fm) {
#pragma unroll
      for (int fn = 0; fn < 4; ++fn) {
        int n = n0 + wc * 64 + fn * 16 + (lane & 15);
        int hh = n >> 6, d = n & 63;
        float bv = bias[n];
        int m_base = m0 + wr * 64 + fm * 16 + (lane >> 4) * 4;
        int b = m_base >> 11, s = m_base & 2047;
        union { u16 s4[4]; uint2 u2; } pk;
#pragma unroll
        for (int i = 0; i < 4; ++i) pk.s4[i] = f2bf(acc[fm][fn][i] + bv);
        *(uint2*)(&O[(((size_t)b * 16 + hh) * 64 + d) * 2048 + s]) = pk.u2;
      }
    }
  } else {
    const float oscale = (bz == 0) ? QSCALE : 1.0f;
#pragma unroll
    for (int fm = 0; fm < 4; ++fm) {
#pragma unroll
      for (int fn = 0; fn < 4; ++fn) {
        int n = n0 + wc * 64 + fn * 16 + (lane & 15);
        int hh = n >> 6, d = n & 63;
        float bv = bias[n];
#pragma unroll
        for (int i = 0; i < 4; ++i) {
          int m = m0 + wr * 64 + fm * 16 + (lane >> 4) * 4 + i;
          int b = m >> 11, s = m & 2047;
          O[(((size_t)b * 16 + hh) * 2048 + s) * 64 + d] = f2bf((acc[fm][fn][i] + bv) * oscale);
        }
      }
    }
  }
}

// ---------- kernel 5: causal flash attention, 32x32x16 MFMA, swapped operands ----------
// grid (16, 32) = (q-tile-id, b*16+h). 256 thr = 4 waves, 32 q-rows/wave.
// Q prescaled by log2(e)/8. K: [B,H,S,D]; Vt: [B,H,D,S]; z: [B,S,H*D].

__global__ __launch_bounds__(256)
void attn_kernel(const u16* __restrict__ q, const u16* __restrict__ k,
                 const u16* __restrict__ vt, u16* __restrict__ z) {
  const int bx = blockIdx.x, by = blockIdx.y;
  const int qb = (by < 16) ? bx : (15 - bx);
  const int bh = by;
  const int tid = threadIdx.x;
  const int w = tid >> 6, lane = tid & 63;
  const int l31 = lane & 31, h = lane >> 5;
  const int swz = lane & 7;
  const size_t base = (size_t)bh * (2048 * 64);

  __shared__ u16 Ks[2][64 * 64];
  __shared__ u16 Vs[2][64 * 64];

  const int wq0 = qb * 128 + w * 32;
  const int q_glob = wq0 + l31;

  // Q fragments: B-operand, lane holds Q[q=l31][d = 16*kk + 8*h + j]
  bf16x8 qf[4];
  {
    const u16* qp = q + base + (size_t)q_glob * 64 + 8 * h;
#pragma unroll
    for (int kk = 0; kk < 4; ++kk) qf[kk] = *(const bf16x8*)(qp + 16 * kk);
  }

  // staging geometry: lane writes LDS row chunk*8+(lane>>3), 16B-group lane&7 (linear);
  // source 16B-group pre-swizzled: (lane&7) ^ (lane>>3)  [involution]
  const int r8 = lane >> 3;
  const int cg = (lane & 7) ^ r8;
  const int c0 = 2 * w;

  f32x16 oa0 = {}, oa1 = {};   // O^T acc: lane holds q=l31, d rows
  float mreg = -1e30f, lsum = 0.f;

  const int ntiles = 2 * qb + 2;

  // prologue: stage tile 0 into buf 0
#pragma unroll
  for (int c = 0; c < 2; ++c) {
    int chunk = c0 + c;
    int row = chunk * 8 + r8;
    async16(k + base + (size_t)row * 64 + cg * 8, &Ks[0][chunk * 512]);
    async16(vt + base + (size_t)row * 2048 + cg * 8, &Vs[0][chunk * 512]);
  }

  int cur = 0;
  for (int t = 0; t < ntiles; ++t) {
    const int kv0 = t * 64;
    if (t + 1 < ntiles) {
      const int kv1 = kv0 + 64;
#pragma unroll
      for (int c = 0; c < 2; ++c) {
        int chunk = c0 + c;
        int row = chunk * 8 + r8;
        async16(k + base + (size_t)(kv1 + row) * 64 + cg * 8, &Ks[cur ^ 1][chunk * 512]);
        async16(vt + base + (size_t)row * 2048 + kv1 + cg * 8, &Vs[cur ^ 1][chunk * 512]);
      }
      asm volatile("s_waitcnt vmcnt(4)" ::: "memory");
    } else {
      asm volatile("s_waitcnt vmcnt(0)" ::: "memory");
    }
    __builtin_amdgcn_s_barrier();

    if (kv0 <= wq0 + 31) {  // skip fully-masked tiles (wave-uniform)
      // batch K fragment loads, then MFMA cluster
      bf16x8 kf0[4], kf1[4];
#pragma unroll
      for (int kk = 0; kk < 4; ++kk) {
        const int colo = ((2 * kk + h) ^ swz) * 8;
        kf0[kk] = *(const bf16x8*)(&Ks[cur][l31 * 64 + colo]);
        kf1[kk] = *(const bf16x8*)(&Ks[cur][(32 + l31) * 64 + colo]);
      }
      f32x16 sa0 = {}, sa1 = {};
      __builtin_amdgcn_s_setprio(1);
#pragma unroll
      for (int kk = 0; kk < 4; ++kk) {
        sa0 = MFMA32(kf0[kk], qf[kk], sa0);
        sa1 = MFMA32(kf1[kk], qf[kk], sa1);
      }
      __builtin_amdgcn_s_setprio(0);

      if (kv0 + 63 > wq0) {  // diagonal tile: apply causal mask
        int kvoff = kv0 + 4 * h - q_glob;
#pragma unroll
        for (int rg = 0; rg < 16; ++rg) {
          const int pat = (rg & 3) + 8 * (rg >> 2);
          if (pat + kvoff > 0) sa0[rg] = -1e30f;
          if (pat + 32 + kvoff > 0) sa1[rg] = -1e30f;
        }
      }

      // tree max over 32 values
      float mx[8];
#pragma unroll
      for (int i = 0; i < 8; ++i)
        mx[i] = fmaxf(fmaxf(sa0[i], sa0[i + 8]), fmaxf(sa1[i], sa1[i + 8]));
      float pmax = fmaxf(fmaxf(fmaxf(mx[0], mx[1]), fmaxf(mx[2], mx[3])),
                         fmaxf(fmaxf(mx[4], mx[5]), fmaxf(mx[6], mx[7])));
      pmax = fmaxf(pmax, __shfl_xor(pmax, 32));

      // defer-max: rescale only when max grew past threshold
      if (!__all(pmax <= mreg + 8.f)) {
        float mnew = fmaxf(mreg, pmax);
        float alpha = __builtin_amdgcn_exp2f(mreg - mnew);
        mreg = mnew;
        lsum *= alpha;
#pragma unroll
        for (int i = 0; i < 16; ++i) { oa0[i] *= alpha; oa1[i] *= alpha; }
      }

      // P = exp2(S - m), single-instruction exp2
      float p0a[16], p1a[16];
#pragma unroll
      for (int i = 0; i < 16; ++i) {
        p0a[i] = __builtin_amdgcn_exp2f(sa0[i] - mreg);
        p1a[i] = __builtin_amdgcn_exp2f(sa1[i] - mreg);
      }
      u32 P32[2][4][2];
#pragma unroll
      for (int tt = 0; tt < 4; ++tt)
#pragma unroll
        for (int cc = 0; cc < 2; ++cc) {
          P32[0][tt][cc] = cvtpk(p0a[4 * tt + 2 * cc], p0a[4 * tt + 2 * cc + 1]);
          P32[1][tt][cc] = cvtpk(p1a[4 * tt + 2 * cc], p1a[4 * tt + 2 * cc + 1]);
        }
      // tree row-sum
      float r8v[8];
#pragma unroll
      for (int i = 0; i < 8; ++i)
        r8v[i] = (p0a[i] + p0a[i + 8]) + (p1a[i] + p1a[i + 8]);
      float rsum = ((r8v[0] + r8v[1]) + (r8v[2] + r8v[3])) +
                   ((r8v[4] + r8v[5]) + (r8v[6] + r8v[7]));
      rsum += __shfl_xor(rsum, 32);
      lsum += rsum;

      // exchange P into B-fragment layout (kv = 16*kk + 8*h + j), batched shuffles
      u32 pbu[4][4];
#pragma unroll
      for (int kk = 0; kk < 4; ++kk) {
        const int fp = kk >> 1;
        const int ta = 2 * (kk & 1);
#pragma unroll
        for (int cc = 0; cc < 2; ++cc) {
          u32 a = P32[fp][ta][cc], b = P32[fp][ta + 1][cc];
          u32 sb = (u32)__shfl_xor((int)b, 32);
          u32 sa2 = (u32)__shfl_xor((int)a, 32);
          pbu[kk][cc] = h ? sb : a;
          pbu[kk][2 + cc] = h ? b : sa2;
        }
      }
      // batch V fragment loads, then PV MFMA cluster
      bf16x8 vf0[4], vf1[4];
#pragma unroll
      for (int kk = 0; kk < 4; ++kk) {
        const int colo = ((2 * kk + h) ^ swz) * 8;
        vf0[kk] = *(const bf16x8*)(&Vs[cur][l31 * 64 + colo]);
        vf1[kk] = *(const bf16x8*)(&Vs[cur][(32 + l31) * 64 + colo]);
      }
      __builtin_amdgcn_s_setprio(1);
#pragma unroll
      for (int kk = 0; kk < 4; ++kk) {
        union { u32 u[4]; bf16x8 v; } pb;
#pragma unroll
        for (int cc = 0; cc < 4; ++cc) pb.u[cc] = pbu[kk][cc];
        oa0 = MFMA32(vf0[kk], pb.v, oa0);
        oa1 = MFMA32(vf1[kk], pb.v, oa1);
      }
      __builtin_amdgcn_s_setprio(0);
    }
    asm volatile("s_waitcnt lgkmcnt(0)" ::: "memory");
    __builtin_amdgcn_s_barrier();
    cur ^= 1;
  }

  const float inv = 1.f / lsum;
  const int b_ = bh >> 4, head = bh & 15;
  u16* zp = z + ((size_t)b_ * 2048 + q_glob) * 1024 + head * 64;
#pragma unroll
  for (int fd = 0; fd < 2; ++fd)
#pragma unroll
    for (int tt = 0; tt < 4; ++tt) {
      union { u16 s[4]; uint2 u2; } pk;
#pragma unroll
      for (int i = 0; i < 4; ++i) {
        float ov = (fd ? oa1[4 * tt + i] : oa0[4 * tt + i]) * inv;
        pk.s[i] = f2bf(ov);
      }
      *(uint2*)(zp + fd * 32 + tt * 8 + 4 * h) = pk.u2;
    }
}

// ---------- kernel 6: output projection GEMM: z[4096,1024] x WoT -> fp32 out + b_O ----------

__global__ __launch_bounds__(256)
void gemm_out_kernel(const u16* __restrict__ A, const u16* __restrict__ Bt,
                     const float* __restrict__ bias, float* __restrict__ Out) {
  __shared__ u16 As[128 * 64];
  __shared__ u16 Bs[128 * 64];
  const int m0 = blockIdx.x * 128;
  const int n0 = blockIdx.y * 128;
  const int tid = threadIdx.x;
  const int wave = tid >> 6, lane = tid & 63;
  const int wr = wave >> 1, wc = wave & 1;
  const int lrow = lane >> 3;
  const int lcol = (lane & 7) * 8;

  f32x4 acc[4][4] = {};

  for (int kt = 0; kt < 1024; kt += 64) {
    __syncthreads();
#pragma unroll
    for (int j = 0; j < 4; ++j) {
      int c = wave * 4 + j;
      int row = c * 8 + lrow;
      async16(A + (size_t)(m0 + row) * 1024 + kt + lcol, As + c * 512);
      async16(Bt + (size_t)(n0 + row) * 1024 + kt + lcol, Bs + c * 512);
    }
    asm volatile("s_waitcnt vmcnt(0)" ::: "memory");
    __syncthreads();
#pragma unroll
    for (int kk = 0; kk < 64; kk += 32) {
      bf16x8 af[4], bfv[4];
#pragma unroll
      for (int i = 0; i < 4; ++i) {
        af[i] = *(const bf16x8*)(As + (wr * 64 + i * 16 + (lane & 15)) * 64 + kk + 8 * (lane >> 4));
        bfv[i] = *(const bf16x8*)(Bs + (wc * 64 + i * 16 + (lane & 15)) * 64 + kk + 8 * (lane >> 4));
      }
#pragma unroll
      for (int i = 0; i < 4; ++i)
#pragma unroll
        for (int j = 0; j < 4; ++j)
          acc[i][j] = MFMA(af[i], bfv[j], acc[i][j]);
    }
  }
#pragma unroll
  for (int fm = 0; fm < 4; ++fm) {
#pragma unroll
    for (int fn = 0; fn < 4; ++fn) {
      int n = n0 + wc * 64 + fn * 16 + (lane & 15);
      float bv = bias[n];
#pragma unroll
      for (int i = 0; i < 4; ++i) {
        int m = m0 + wr * 64 + fm * 16 + (lane >> 4) * 4 + i;
        Out[(size_t)m * 1024 + n] = acc[fm][fn][i] + bv;
      }
    }
  }
}

// ---------- launcher ----------

extern "C" void kernel_launch(void* const* d_in, const int* in_sizes, int n_in,
                              void* d_out, int out_size, void* d_ws, size_t ws_size,
                              hipStream_t stream) {
  const float* xq = (const float*)d_in[0];
  const float* xk = (const float*)d_in[1];
  const float* xv = (const float*)d_in[2];
  const float* WQ = (const float*)d_in[3];
  const float* WK = (const float*)d_in[4];
  const float* WV = (const float*)d_in[5];
  const float* WO = (const float*)d_in[6];
  const float* bQ = (const float*)d_in[7];
  const float* bK = (const float*)d_in[8];
  const float* bV = (const float*)d_in[9];
  const float* bO = (const float*)d_in[10];
  float* out = (float*)d_out;

  char* ws = (char*)d_ws;
  const size_t MB = 1024 * 1024;
  u16* Xq = (u16*)(ws);             // 8MB each (4096x1024 bf16)
  u16* Xk = (u16*)(ws + 8 * MB);
  u16* Xv = (u16*)(ws + 16 * MB);
  u16* WqT = (u16*)(ws + 24 * MB);  // 2MB each (1024x1024 bf16)
  u16* WkT = (u16*)(ws + 26 * MB);
  u16* WvT = (u16*)(ws + 28 * MB);
  u16* WoT = (u16*)(ws + 30 * MB);
  u16* Q = (u16*)(ws + 32 * MB);    // 8MB [B,H,S,D] (prescaled)
  u16* K = (u16*)(ws + 40 * MB);    // 8MB [B,H,S,D]
  u16* V = (u16*)(ws + 48 * MB);    // 8MB [B,H,D,S]  (transposed)
  u16* Z = (u16*)(ws + 56 * MB);    // 8MB [B,S,H,D]

  quant_inputs_kernel<<<dim3(2048, 3), 256, 0, stream>>>(xq, xk, xv, Xq, Xk, Xv);
  wqkv_transpose_kernel<<<dim3(16, 16, 3), 256, 0, stream>>>(WQ, WK, WV, WqT, WkT, WvT);
  wo_transpose_kernel<<<dim3(16, 16), 256, 0, stream>>>(WO, WoT);
  gemm_qkv_kernel<<<dim3(32, 8, 3), 256, 0, stream>>>(Xq, Xk, Xv, WqT, WkT, WvT, bQ, bK, bV, Q, K, V);
  attn_kernel<<<dim3(16, 32), 256, 0, stream>>>(Q, K, V, Z);
  gemm_out_kernel<<<dim3(32, 8), 256, 0, stream>>>(Z, WoT, bO, out);
}

// Round 4
// 155.827 us; speedup vs baseline: 1.4870x; 1.0113x over previous
//
#include <hip/hip_runtime.h>
#include <cstdint>
#include <cmath>

typedef __attribute__((ext_vector_type(4))) float f32x4;
typedef __attribute__((ext_vector_type(16))) float f32x16;
typedef __attribute__((ext_vector_type(8))) short bf16x8;
using u16 = unsigned short;
using u32 = uint32_t;

// ---------- helpers ----------

static __device__ __forceinline__ u16 f2bf(float f) {
  uint32_t u = __float_as_uint(f);
  u += 0x7fffu + ((u >> 16) & 1u);
  return (u16)(u >> 16);
}

static __device__ __forceinline__ float bf2f(u16 x) {
  return __uint_as_float((u32)x << 16);
}

// round f32 to float8_e4m3fn (RNE), return dequantized f32.
static __device__ __forceinline__ float quant_e4m3(float x) {
  uint32_t u = __float_as_uint(x);
  uint32_t absu = u & 0x7fffffffu;
  if (absu >= 0x3c800000u) {  // |x| >= 2^-6 : e4m3 normal, keep 3 mantissa bits RNE
    uint32_t lsb = (absu >> 20) & 1u;
    uint32_t r = (absu + 0x7ffffu + lsb) & ~0xfffffu;
    return __uint_as_float((u & 0x80000000u) | r);
  }
  return rintf(x * 512.0f) * 0.001953125f;
}

static __device__ __forceinline__ void async16(const void* g, void* l) {
  __builtin_amdgcn_global_load_lds(
      (const __attribute__((address_space(1))) void*)g,
      (__attribute__((address_space(3))) void*)l, 16, 0, 0);
}

static __device__ __forceinline__ u32 cvtpk(float a, float b) {
  u32 r;
  asm("v_cvt_pk_bf16_f32 %0, %1, %2" : "=v"(r) : "v"(a), "v"(b));
  return r;
}

#define MFMA(a, b, c) __builtin_amdgcn_mfma_f32_16x16x32_bf16(a, b, c, 0, 0, 0)
#define MFMA32(a, b, c) __builtin_amdgcn_mfma_f32_32x32x16_bf16(a, b, c, 0, 0, 0)

// log2(e)/sqrt(64): folded into Q at projection time so attn uses exp2 directly.
#define QSCALE 0.18033688011112042f

// ---------- kernel 1: merged prep (quantize inputs + weight transposes) ----------
// blocks [0,6144): quantize activations; [6144,6912): W_{Q,K,V} transpose;
// [6912,7168): W_O transpose.

__global__ __launch_bounds__(256)
void prep_kernel(const float* __restrict__ xq, const float* __restrict__ xk,
                 const float* __restrict__ xv,
                 u16* __restrict__ Xq, u16* __restrict__ Xk, u16* __restrict__ Xv,
                 const float* __restrict__ WQ, const float* __restrict__ WK,
                 const float* __restrict__ WV,
                 u16* __restrict__ WqT, u16* __restrict__ WkT, u16* __restrict__ WvT,
                 const float* __restrict__ WO, u16* __restrict__ WoT) {
  __shared__ u16 T[64][72];
  const int bid = blockIdx.x;
  const int t = threadIdx.x;

  if (bid < 6144) {  // activation quantize: fp32 -> e4m3 -> bf16
    const int which = bid >> 11, idx = bid & 2047;
    const float* x = which == 0 ? xq : (which == 1 ? xk : xv);
    u16* y = which == 0 ? Xq : (which == 1 ? Xk : Xv);
    int i = (idx * 256 + t) * 8;
    f32x4 a = *(const f32x4*)(x + i);
    f32x4 b = *(const f32x4*)(x + i + 4);
    union { bf16x8 v; u16 s[8]; } r;
#pragma unroll
    for (int j = 0; j < 4; ++j) r.s[j] = f2bf(quant_e4m3(a[j]));
#pragma unroll
    for (int j = 0; j < 4; ++j) r.s[4 + j] = f2bf(quant_e4m3(b[j]));
    *(bf16x8*)(y + i) = r.v;
    return;
  }

  if (bid < 6912) {  // W_{Q,K,V} [H,M,D] -> quant -> bf16 Bt[n=h*64+d][k=m]
    const int sub = bid - 6144;
    const int zz = sub >> 8;
    const int rem = sub & 255;
    const int h = rem >> 4;
    const int k0 = (rem & 15) * 64;
    const float* w = zz == 0 ? WQ : (zz == 1 ? WK : WV);
    u16* wt = zz == 0 ? WqT : (zz == 1 ? WkT : WvT);
    int ml = t >> 2, d0 = (t & 3) * 16;
    const float* src = w + ((size_t)h * 1024 + (k0 + ml)) * 64 + d0;
    u16 q16[16];
#pragma unroll
    for (int j = 0; j < 16; j += 4) {
      f32x4 f = *(const f32x4*)(src + j);
#pragma unroll
      for (int c = 0; c < 4; ++c) q16[j + c] = f2bf(quant_e4m3(f[c]));
    }
#pragma unroll
    for (int j = 0; j < 16; ++j) T[ml][d0 + j] = q16[j];
    __syncthreads();
    int d = t >> 2, cb = t & 3;
    union { bf16x8 v; u16 s[8]; } o0, o1;
#pragma unroll
    for (int j = 0; j < 8; ++j) { o0.s[j] = T[cb * 16 + j][d]; o1.s[j] = T[cb * 16 + 8 + j][d]; }
    u16* dst = wt + (size_t)(h * 64 + d) * 1024 + k0 + cb * 16;
    *(bf16x8*)(dst) = o0.v;
    *(bf16x8*)(dst + 8) = o1.v;
    return;
  }

  {  // W_O [H,D,M] -> bf16 Bt[n=m][k=h*64+d]
    const int sub = bid - 6912;
    const int r0 = (sub >> 4) * 64;
    const int c0 = (sub & 15) * 64;
    int rl = t >> 2, cl0 = (t & 3) * 16;
    const float* src = WO + (size_t)(r0 + rl) * 1024 + c0 + cl0;
    u16 q16[16];
#pragma unroll
    for (int j = 0; j < 16; j += 4) {
      f32x4 f = *(const f32x4*)(src + j);
#pragma unroll
      for (int c = 0; c < 4; ++c) q16[j + c] = f2bf(f[c]);
    }
#pragma unroll
    for (int j = 0; j < 16; ++j) T[rl][cl0 + j] = q16[j];
    __syncthreads();
    int ml = t >> 2, cb = t & 3;
    union { bf16x8 v; u16 s[8]; } o0, o1;
#pragma unroll
    for (int j = 0; j < 8; ++j) { o0.s[j] = T[cb * 16 + j][ml]; o1.s[j] = T[cb * 16 + 8 + j][ml]; }
    u16* dst = WoT + (size_t)(c0 + ml) * 1024 + r0 + cb * 16;
    *(bf16x8*)(dst) = o0.v;
    *(bf16x8*)(dst + 8) = o1.v;
  }
}

// ---------- kernel 2: QKV GEMM -> Q (prescaled), K: [B,H,S,D] bf16 ; V: [B,H,D,S] bf16 ----------

__global__ __launch_bounds__(256)
void gemm_qkv_kernel(const u16* __restrict__ A0, const u16* __restrict__ A1, const u16* __restrict__ A2,
                     const u16* __restrict__ B0, const u16* __restrict__ B1, const u16* __restrict__ B2,
                     const float* __restrict__ bias0, const float* __restrict__ bias1,
                     const float* __restrict__ bias2,
                     u16* __restrict__ O0, u16* __restrict__ O1, u16* __restrict__ O2) {
  const int bz = blockIdx.z;
  const u16* A = bz == 0 ? A0 : (bz == 1 ? A1 : A2);
  const u16* Bt = bz == 0 ? B0 : (bz == 1 ? B1 : B2);
  const float* bias = bz == 0 ? bias0 : (bz == 1 ? bias1 : bias2);
  u16* O = bz == 0 ? O0 : (bz == 1 ? O1 : O2);

  __shared__ u16 As[128 * 64];
  __shared__ u16 Bs[128 * 64];
  const int m0 = blockIdx.x * 128;
  const int n0 = blockIdx.y * 128;
  const int tid = threadIdx.x;
  const int wave = tid >> 6, lane = tid & 63;
  const int wr = wave >> 1, wc = wave & 1;
  const int lrow = lane >> 3;
  const int lcol = (lane & 7) * 8;

  f32x4 acc[4][4] = {};

  for (int kt = 0; kt < 1024; kt += 64) {
    __syncthreads();
#pragma unroll
    for (int j = 0; j < 4; ++j) {
      int c = wave * 4 + j;
      int row = c * 8 + lrow;
      async16(A + (size_t)(m0 + row) * 1024 + kt + lcol, As + c * 512);
      async16(Bt + (size_t)(n0 + row) * 1024 + kt + lcol, Bs + c * 512);
    }
    asm volatile("s_waitcnt vmcnt(0)" ::: "memory");
    __syncthreads();
#pragma unroll
    for (int kk = 0; kk < 64; kk += 32) {
      bf16x8 af[4], bfv[4];
#pragma unroll
      for (int i = 0; i < 4; ++i) {
        af[i] = *(const bf16x8*)(As + (wr * 64 + i * 16 + (lane & 15)) * 64 + kk + 8 * (lane >> 4));
        bfv[i] = *(const bf16x8*)(Bs + (wc * 64 + i * 16 + (lane & 15)) * 64 + kk + 8 * (lane >> 4));
      }
#pragma unroll
      for (int i = 0; i < 4; ++i)
#pragma unroll
        for (int j = 0; j < 4; ++j)
          acc[i][j] = MFMA(af[i], bfv[j], acc[i][j]);
    }
  }
  if (bz == 2) {
    // V^T: [B,H,D,S]
#pragma unroll
    for (int fm = 0; fm < 4; ++fm) {
#pragma unroll
      for (int fn = 0; fn < 4; ++fn) {
        int n = n0 + wc * 64 + fn * 16 + (lane & 15);
        int hh = n >> 6, d = n & 63;
        float bv = bias[n];
        int m_base = m0 + wr * 64 + fm * 16 + (lane >> 4) * 4;
        int b = m_base >> 11, s = m_base & 2047;
        union { u16 s4[4]; uint2 u2; } pk;
#pragma unroll
        for (int i = 0; i < 4; ++i) pk.s4[i] = f2bf(acc[fm][fn][i] + bv);
        *(uint2*)(&O[(((size_t)b * 16 + hh) * 64 + d) * 2048 + s]) = pk.u2;
      }
    }
  } else {
    const float oscale = (bz == 0) ? QSCALE : 1.0f;
#pragma unroll
    for (int fm = 0; fm < 4; ++fm) {
#pragma unroll
      for (int fn = 0; fn < 4; ++fn) {
        int n = n0 + wc * 64 + fn * 16 + (lane & 15);
        int hh = n >> 6, d = n & 63;
        float bv = bias[n];
#pragma unroll
        for (int i = 0; i < 4; ++i) {
          int m = m0 + wr * 64 + fm * 16 + (lane >> 4) * 4 + i;
          int b = m >> 11, s = m & 2047;
          O[(((size_t)b * 16 + hh) * 2048 + s) * 64 + d] = f2bf((acc[fm][fn][i] + bv) * oscale);
        }
      }
    }
  }
}

// ---------- kernel 3: causal flash attention, kv-split x2, 32x32x16 MFMA ----------
// grid (16, 32, 2) = (q-tile-id base, b*16+h, kv parity). 256 thr = 4 waves, 32 q-rows/wave.
// Q prescaled by log2(e)/8. K: [B,H,S,D]; Vt: [B,H,D,S].
// Writes normalized partial O (bf16) + m,l (f32) per split; combine kernel merges.

__global__ __launch_bounds__(256)
void attn_kernel(const u16* __restrict__ q, const u16* __restrict__ k,
                 const u16* __restrict__ vt,
                 u16* __restrict__ PO, float* __restrict__ PM, float* __restrict__ PL) {
  const int bx = blockIdx.x, by = blockIdx.y;
  const int qb = (by < 16) ? bx : (15 - bx);
  const int bh = by;
  const int zsp = blockIdx.z;      // kv tile parity this block handles
  const int tid = threadIdx.x;
  const int w = tid >> 6, lane = tid & 63;
  const int l31 = lane & 31, h = lane >> 5;
  const int swz = lane & 7;
  const size_t base = (size_t)bh * (2048 * 64);

  __shared__ u16 Ks[2][64 * 64];
  __shared__ u16 Vs[2][64 * 64];

  const int wq0 = qb * 128 + w * 32;
  const int q_glob = wq0 + l31;

  // Q fragments: B-operand, lane holds Q[q=l31][d = 16*kk + 8*h + j]
  bf16x8 qf[4];
  {
    const u16* qp = q + base + (size_t)q_glob * 64 + 8 * h;
#pragma unroll
    for (int kk = 0; kk < 4; ++kk) qf[kk] = *(const bf16x8*)(qp + 16 * kk);
  }

  // staging: lane writes LDS 16B-group lane&7 (linear); source pre-swizzled by ^ (lane>>3)
  const int r8 = lane >> 3;
  const int cg = (lane & 7) ^ r8;
  const int c0 = 2 * w;

  f32x16 oa0 = {}, oa1 = {};   // O^T acc: lane holds q=l31, d rows
  float mreg = -1e30f, lsum = 0.f;

  const int nj = qb + 1;  // tiles of parity zsp in [0, 2qb+1]

  // prologue: stage tile t=zsp into buf 0
#pragma unroll
  for (int c = 0; c < 2; ++c) {
    int chunk = c0 + c;
    int row = chunk * 8 + r8;
    async16(k + base + (size_t)(zsp * 64 + row) * 64 + cg * 8, &Ks[0][chunk * 512]);
    async16(vt + base + (size_t)row * 2048 + zsp * 64 + cg * 8, &Vs[0][chunk * 512]);
  }

  int cur = 0;
  for (int j = 0; j < nj; ++j) {
    const int kv0 = (zsp + 2 * j) * 64;
    if (j + 1 < nj) {
      const int kv1 = kv0 + 128;
#pragma unroll
      for (int c = 0; c < 2; ++c) {
        int chunk = c0 + c;
        int row = chunk * 8 + r8;
        async16(k + base + (size_t)(kv1 + row) * 64 + cg * 8, &Ks[cur ^ 1][chunk * 512]);
        async16(vt + base + (size_t)row * 2048 + kv1 + cg * 8, &Vs[cur ^ 1][chunk * 512]);
      }
      asm volatile("s_waitcnt vmcnt(4)" ::: "memory");
    } else {
      asm volatile("s_waitcnt vmcnt(0)" ::: "memory");
    }
    __builtin_amdgcn_s_barrier();

    if (kv0 <= wq0 + 31) {  // skip fully-masked tiles (wave-uniform)
      bf16x8 kf0[4], kf1[4];
#pragma unroll
      for (int kk = 0; kk < 4; ++kk) {
        const int colo = ((2 * kk + h) ^ swz) * 8;
        kf0[kk] = *(const bf16x8*)(&Ks[cur][l31 * 64 + colo]);
        kf1[kk] = *(const bf16x8*)(&Ks[cur][(32 + l31) * 64 + colo]);
      }
      f32x16 sa0 = {}, sa1 = {};
      __builtin_amdgcn_s_setprio(1);
#pragma unroll
      for (int kk = 0; kk < 4; ++kk) {
        sa0 = MFMA32(kf0[kk], qf[kk], sa0);
        sa1 = MFMA32(kf1[kk], qf[kk], sa1);
      }
      __builtin_amdgcn_s_setprio(0);

      if (kv0 + 63 > wq0) {  // diagonal tile: apply causal mask
        int kvoff = kv0 + 4 * h - q_glob;
#pragma unroll
        for (int rg = 0; rg < 16; ++rg) {
          const int pat = (rg & 3) + 8 * (rg >> 2);
          if (pat + kvoff > 0) sa0[rg] = -1e30f;
          if (pat + 32 + kvoff > 0) sa1[rg] = -1e30f;
        }
      }

      // tree max over 32 values
      float mx[8];
#pragma unroll
      for (int i = 0; i < 8; ++i)
        mx[i] = fmaxf(fmaxf(sa0[i], sa0[i + 8]), fmaxf(sa1[i], sa1[i + 8]));
      float pmax = fmaxf(fmaxf(fmaxf(mx[0], mx[1]), fmaxf(mx[2], mx[3])),
                         fmaxf(fmaxf(mx[4], mx[5]), fmaxf(mx[6], mx[7])));
      pmax = fmaxf(pmax, __shfl_xor(pmax, 32));

      // defer-max: rescale only when max grew past threshold
      if (!__all(pmax <= mreg + 8.f)) {
        float mnew = fmaxf(mreg, pmax);
        float alpha = __builtin_amdgcn_exp2f(mreg - mnew);
        mreg = mnew;
        lsum *= alpha;
#pragma unroll
        for (int i = 0; i < 16; ++i) { oa0[i] *= alpha; oa1[i] *= alpha; }
      }

      // P = exp2(S - m)
      float p0a[16], p1a[16];
#pragma unroll
      for (int i = 0; i < 16; ++i) {
        p0a[i] = __builtin_amdgcn_exp2f(sa0[i] - mreg);
        p1a[i] = __builtin_amdgcn_exp2f(sa1[i] - mreg);
      }
      u32 P32[2][4][2];
#pragma unroll
      for (int tt = 0; tt < 4; ++tt)
#pragma unroll
        for (int cc = 0; cc < 2; ++cc) {
          P32[0][tt][cc] = cvtpk(p0a[4 * tt + 2 * cc], p0a[4 * tt + 2 * cc + 1]);
          P32[1][tt][cc] = cvtpk(p1a[4 * tt + 2 * cc], p1a[4 * tt + 2 * cc + 1]);
        }
      // tree row-sum
      float r8v[8];
#pragma unroll
      for (int i = 0; i < 8; ++i)
        r8v[i] = (p0a[i] + p0a[i + 8]) + (p1a[i] + p1a[i + 8]);
      float rsum = ((r8v[0] + r8v[1]) + (r8v[2] + r8v[3])) +
                   ((r8v[4] + r8v[5]) + (r8v[6] + r8v[7]));
      rsum += __shfl_xor(rsum, 32);
      lsum += rsum;

      // exchange P into B-fragment layout (kv = 16*kk + 8*h + j)
      u32 pbu[4][4];
#pragma unroll
      for (int kk = 0; kk < 4; ++kk) {
        const int fp = kk >> 1;
        const int ta = 2 * (kk & 1);
#pragma unroll
        for (int cc = 0; cc < 2; ++cc) {
          u32 a = P32[fp][ta][cc], b = P32[fp][ta + 1][cc];
          u32 sb = (u32)__shfl_xor((int)b, 32);
          u32 sa2 = (u32)__shfl_xor((int)a, 32);
          pbu[kk][cc] = h ? sb : a;
          pbu[kk][2 + cc] = h ? b : sa2;
        }
      }
      bf16x8 vf0[4], vf1[4];
#pragma unroll
      for (int kk = 0; kk < 4; ++kk) {
        const int colo = ((2 * kk + h) ^ swz) * 8;
        vf0[kk] = *(const bf16x8*)(&Vs[cur][l31 * 64 + colo]);
        vf1[kk] = *(const bf16x8*)(&Vs[cur][(32 + l31) * 64 + colo]);
      }
      __builtin_amdgcn_s_setprio(1);
#pragma unroll
      for (int kk = 0; kk < 4; ++kk) {
        union { u32 u[4]; bf16x8 v; } pb;
#pragma unroll
        for (int cc = 0; cc < 4; ++cc) pb.u[cc] = pbu[kk][cc];
        oa0 = MFMA32(vf0[kk], pb.v, oa0);
        oa1 = MFMA32(vf1[kk], pb.v, oa1);
      }
      __builtin_amdgcn_s_setprio(0);
    }
    asm volatile("s_waitcnt lgkmcnt(0)" ::: "memory");
    __builtin_amdgcn_s_barrier();
    cur ^= 1;
  }

  // write normalized partial O (bf16) + m,l (f32)
  const float inv = lsum > 0.f ? 1.f / lsum : 0.f;
  const size_t prow = (size_t)(zsp * 32 + bh) * 2048 + q_glob;
  u16* pop = PO + prow * 64;
#pragma unroll
  for (int fd = 0; fd < 2; ++fd)
#pragma unroll
    for (int tt = 0; tt < 4; ++tt) {
      union { u16 s[4]; uint2 u2; } pk;
#pragma unroll
      for (int i = 0; i < 4; ++i) {
        float ov = (fd ? oa1[4 * tt + i] : oa0[4 * tt + i]) * inv;
        pk.s[i] = f2bf(ov);
      }
      *(uint2*)(pop + fd * 32 + tt * 8 + 4 * h) = pk.u2;
    }
  if (h == 0) {
    PM[prow] = mreg;
    PL[prow] = lsum;
  }
}

// ---------- kernel 4: combine kv-split partials -> Z [B,S,H,D] bf16 ----------

__global__ __launch_bounds__(256)
void combine_kernel(const u16* __restrict__ PO, const float* __restrict__ PM,
                    const float* __restrict__ PL, u16* __restrict__ z) {
  const int g = blockIdx.x * 256 + threadIdx.x;  // 4 threads per q-row
  const int row = g >> 2, dp = (g & 3) * 16;
  const int bh = row >> 11, qq = row & 2047;
  const int b = bh >> 4, head = bh & 15;
  float m0 = PM[row], m1 = PM[65536 + row];
  float l0 = PL[row], l1 = PL[65536 + row];
  float m = fmaxf(m0, m1);
  float a0 = l0 * __builtin_amdgcn_exp2f(m0 - m);
  float a1 = l1 * __builtin_amdgcn_exp2f(m1 - m);
  float inv = 1.f / (a0 + a1);
  a0 *= inv; a1 *= inv;
  const u16* p0 = PO + (size_t)row * 64 + dp;
  const u16* p1 = PO + (size_t)(65536 + row) * 64 + dp;
  union { bf16x8 v; u16 s[8]; } i0a, i0b, i1a, i1b, oA, oB;
  i0a.v = *(const bf16x8*)(p0);
  i0b.v = *(const bf16x8*)(p0 + 8);
  i1a.v = *(const bf16x8*)(p1);
  i1b.v = *(const bf16x8*)(p1 + 8);
#pragma unroll
  for (int j = 0; j < 8; ++j) {
    oA.s[j] = f2bf(bf2f(i0a.s[j]) * a0 + bf2f(i1a.s[j]) * a1);
    oB.s[j] = f2bf(bf2f(i0b.s[j]) * a0 + bf2f(i1b.s[j]) * a1);
  }
  u16* zp = z + (((size_t)b * 2048 + qq) * 16 + head) * 64 + dp;
  *(bf16x8*)(zp) = oA.v;
  *(bf16x8*)(zp + 8) = oB.v;
}

// ---------- kernel 5: output projection GEMM: z[4096,1024] x WoT -> fp32 out + b_O ----------

__global__ __launch_bounds__(256)
void gemm_out_kernel(const u16* __restrict__ A, const u16* __restrict__ Bt,
                     const float* __restrict__ bias, float* __restrict__ Out) {
  __shared__ u16 As[128 * 64];
  __shared__ u16 Bs[128 * 64];
  const int m0 = blockIdx.x * 128;
  const int n0 = blockIdx.y * 128;
  const int tid = threadIdx.x;
  const int wave = tid >> 6, lane = tid & 63;
  const int wr = wave >> 1, wc = wave & 1;
  const int lrow = lane >> 3;
  const int lcol = (lane & 7) * 8;

  f32x4 acc[4][4] = {};

  for (int kt = 0; kt < 1024; kt += 64) {
    __syncthreads();
#pragma unroll
    for (int j = 0; j < 4; ++j) {
      int c = wave * 4 + j;
      int row = c * 8 + lrow;
      async16(A + (size_t)(m0 + row) * 1024 + kt + lcol, As + c * 512);
      async16(Bt + (size_t)(n0 + row) * 1024 + kt + lcol, Bs + c * 512);
    }
    asm volatile("s_waitcnt vmcnt(0)" ::: "memory");
    __syncthreads();
#pragma unroll
    for (int kk = 0; kk < 64; kk += 32) {
      bf16x8 af[4], bfv[4];
#pragma unroll
      for (int i = 0; i < 4; ++i) {
        af[i] = *(const bf16x8*)(As + (wr * 64 + i * 16 + (lane & 15)) * 64 + kk + 8 * (lane >> 4));
        bfv[i] = *(const bf16x8*)(Bs + (wc * 64 + i * 16 + (lane & 15)) * 64 + kk + 8 * (lane >> 4));
      }
#pragma unroll
      for (int i = 0; i < 4; ++i)
#pragma unroll
        for (int j = 0; j < 4; ++j)
          acc[i][j] = MFMA(af[i], bfv[j], acc[i][j]);
    }
  }
#pragma unroll
  for (int fm = 0; fm < 4; ++fm) {
#pragma unroll
    for (int fn = 0; fn < 4; ++fn) {
      int n = n0 + wc * 64 + fn * 16 + (lane & 15);
      float bv = bias[n];
#pragma unroll
      for (int i = 0; i < 4; ++i) {
        int m = m0 + wr * 64 + fm * 16 + (lane >> 4) * 4 + i;
        Out[(size_t)m * 1024 + n] = acc[fm][fn][i] + bv;
      }
    }
  }
}

// ---------- launcher ----------

extern "C" void kernel_launch(void* const* d_in, const int* in_sizes, int n_in,
                              void* d_out, int out_size, void* d_ws, size_t ws_size,
                              hipStream_t stream) {
  const float* xq = (const float*)d_in[0];
  const float* xk = (const float*)d_in[1];
  const float* xv = (const float*)d_in[2];
  const float* WQ = (const float*)d_in[3];
  const float* WK = (const float*)d_in[4];
  const float* WV = (const float*)d_in[5];
  const float* WO = (const float*)d_in[6];
  const float* bQ = (const float*)d_in[7];
  const float* bK = (const float*)d_in[8];
  const float* bV = (const float*)d_in[9];
  const float* bO = (const float*)d_in[10];
  float* out = (float*)d_out;

  char* ws = (char*)d_ws;
  const size_t MB = 1024 * 1024;
  u16* Xq = (u16*)(ws);             // 8MB each (4096x1024 bf16); dead after gemm_qkv
  u16* Xk = (u16*)(ws + 8 * MB);
  u16* Xv = (u16*)(ws + 16 * MB);
  u16* WqT = (u16*)(ws + 24 * MB);  // 2MB each; dead after gemm_qkv
  u16* WkT = (u16*)(ws + 26 * MB);
  u16* WvT = (u16*)(ws + 28 * MB);
  u16* WoT = (u16*)(ws + 30 * MB);  // live until gemm_out
  u16* Q = (u16*)(ws + 32 * MB);    // 8MB [B,H,S,D] (prescaled)
  u16* K = (u16*)(ws + 40 * MB);    // 8MB [B,H,S,D]
  u16* V = (u16*)(ws + 48 * MB);    // 8MB [B,H,D,S]  (transposed)
  u16* Z = (u16*)(ws + 56 * MB);    // 8MB [B,S,H,D]
  // kv-split partials overlay the dead Xq/Xk/Xv region:
  u16* PO = (u16*)(ws);                       // 16MB: [2][32][2048][64] bf16
  float* PM = (float*)(ws + 17 * MB);         // 512KB: [2][32][2048] f32
  float* PL = (float*)(ws + 17 * MB + 524288);// 512KB

  prep_kernel<<<dim3(7168), 256, 0, stream>>>(xq, xk, xv, Xq, Xk, Xv,
                                              WQ, WK, WV, WqT, WkT, WvT, WO, WoT);
  gemm_qkv_kernel<<<dim3(32, 8, 3), 256, 0, stream>>>(Xq, Xk, Xv, WqT, WkT, WvT,
                                                      bQ, bK, bV, Q, K, V);
  attn_kernel<<<dim3(16, 32, 2), 256, 0, stream>>>(Q, K, V, PO, PM, PL);
  combine_kernel<<<dim3(1024), 256, 0, stream>>>(PO, PM, PL, Z);
  gemm_out_kernel<<<dim3(32, 8), 256, 0, stream>>>(Z, WoT, bO, out);
}

// Round 5
// 155.495 us; speedup vs baseline: 1.4902x; 1.0021x over previous
//
#include <hip/hip_runtime.h>
#include <cstdint>
#include <cmath>

typedef __attribute__((ext_vector_type(4))) float f32x4;
typedef __attribute__((ext_vector_type(16))) float f32x16;
typedef __attribute__((ext_vector_type(8))) short bf16x8;
using u16 = unsigned short;
using u32 = uint32_t;

// ---------- helpers ----------

static __device__ __forceinline__ u16 f2bf(float f) {
  uint32_t u = __float_as_uint(f);
  u += 0x7fffu + ((u >> 16) & 1u);
  return (u16)(u >> 16);
}

static __device__ __forceinline__ float bf2f(u16 x) {
  return __uint_as_float((u32)x << 16);
}

// round f32 to float8_e4m3fn (RNE), return dequantized f32.
static __device__ __forceinline__ float quant_e4m3(float x) {
  uint32_t u = __float_as_uint(x);
  uint32_t absu = u & 0x7fffffffu;
  if (absu >= 0x3c800000u) {  // |x| >= 2^-6 : e4m3 normal, keep 3 mantissa bits RNE
    uint32_t lsb = (absu >> 20) & 1u;
    uint32_t r = (absu + 0x7ffffu + lsb) & ~0xfffffu;
    return __uint_as_float((u & 0x80000000u) | r);
  }
  return rintf(x * 512.0f) * 0.001953125f;
}

static __device__ __forceinline__ void async16(const void* g, void* l) {
  __builtin_amdgcn_global_load_lds(
      (const __attribute__((address_space(1))) void*)g,
      (__attribute__((address_space(3))) void*)l, 16, 0, 0);
}

static __device__ __forceinline__ u32 cvtpk(float a, float b) {
  u32 r;
  asm("v_cvt_pk_bf16_f32 %0, %1, %2" : "=v"(r) : "v"(a), "v"(b));
  return r;
}

#define MFMA(a, b, c) __builtin_amdgcn_mfma_f32_16x16x32_bf16(a, b, c, 0, 0, 0)
#define MFMA32(a, b, c) __builtin_amdgcn_mfma_f32_32x32x16_bf16(a, b, c, 0, 0, 0)

// log2(e)/sqrt(64): folded into Q at projection time so attn uses exp2 directly.
#define QSCALE 0.18033688011112042f

// ---------- kernel 1: merged prep (quantize inputs + weight transposes) ----------

__global__ __launch_bounds__(256)
void prep_kernel(const float* __restrict__ xq, const float* __restrict__ xk,
                 const float* __restrict__ xv,
                 u16* __restrict__ Xq, u16* __restrict__ Xk, u16* __restrict__ Xv,
                 const float* __restrict__ WQ, const float* __restrict__ WK,
                 const float* __restrict__ WV,
                 u16* __restrict__ WqT, u16* __restrict__ WkT, u16* __restrict__ WvT,
                 const float* __restrict__ WO, u16* __restrict__ WoT) {
  __shared__ u16 T[64][72];
  const int bid = blockIdx.x;
  const int t = threadIdx.x;

  if (bid < 6144) {  // activation quantize: fp32 -> e4m3 -> bf16
    const int which = bid >> 11, idx = bid & 2047;
    const float* x = which == 0 ? xq : (which == 1 ? xk : xv);
    u16* y = which == 0 ? Xq : (which == 1 ? Xk : Xv);
    int i = (idx * 256 + t) * 8;
    f32x4 a = *(const f32x4*)(x + i);
    f32x4 b = *(const f32x4*)(x + i + 4);
    union { bf16x8 v; u16 s[8]; } r;
#pragma unroll
    for (int j = 0; j < 4; ++j) r.s[j] = f2bf(quant_e4m3(a[j]));
#pragma unroll
    for (int j = 0; j < 4; ++j) r.s[4 + j] = f2bf(quant_e4m3(b[j]));
    *(bf16x8*)(y + i) = r.v;
    return;
  }

  if (bid < 6912) {  // W_{Q,K,V} [H,M,D] -> quant -> bf16 Bt[n=h*64+d][k=m]
    const int sub = bid - 6144;
    const int zz = sub >> 8;
    const int rem = sub & 255;
    const int h = rem >> 4;
    const int k0 = (rem & 15) * 64;
    const float* w = zz == 0 ? WQ : (zz == 1 ? WK : WV);
    u16* wt = zz == 0 ? WqT : (zz == 1 ? WkT : WvT);
    int ml = t >> 2, d0 = (t & 3) * 16;
    const float* src = w + ((size_t)h * 1024 + (k0 + ml)) * 64 + d0;
    u16 q16[16];
#pragma unroll
    for (int j = 0; j < 16; j += 4) {
      f32x4 f = *(const f32x4*)(src + j);
#pragma unroll
      for (int c = 0; c < 4; ++c) q16[j + c] = f2bf(quant_e4m3(f[c]));
    }
#pragma unroll
    for (int j = 0; j < 16; ++j) T[ml][d0 + j] = q16[j];
    __syncthreads();
    int d = t >> 2, cb = t & 3;
    union { bf16x8 v; u16 s[8]; } o0, o1;
#pragma unroll
    for (int j = 0; j < 8; ++j) { o0.s[j] = T[cb * 16 + j][d]; o1.s[j] = T[cb * 16 + 8 + j][d]; }
    u16* dst = wt + (size_t)(h * 64 + d) * 1024 + k0 + cb * 16;
    *(bf16x8*)(dst) = o0.v;
    *(bf16x8*)(dst + 8) = o1.v;
    return;
  }

  {  // W_O [H,D,M] -> bf16 Bt[n=m][k=h*64+d]
    const int sub = bid - 6912;
    const int r0 = (sub >> 4) * 64;
    const int c0 = (sub & 15) * 64;
    int rl = t >> 2, cl0 = (t & 3) * 16;
    const float* src = WO + (size_t)(r0 + rl) * 1024 + c0 + cl0;
    u16 q16[16];
#pragma unroll
    for (int j = 0; j < 16; j += 4) {
      f32x4 f = *(const f32x4*)(src + j);
#pragma unroll
      for (int c = 0; c < 4; ++c) q16[j + c] = f2bf(f[c]);
    }
#pragma unroll
    for (int j = 0; j < 16; ++j) T[rl][cl0 + j] = q16[j];
    __syncthreads();
    int ml = t >> 2, cb = t & 3;
    union { bf16x8 v; u16 s[8]; } o0, o1;
#pragma unroll
    for (int j = 0; j < 8; ++j) { o0.s[j] = T[cb * 16 + j][ml]; o1.s[j] = T[cb * 16 + 8 + j][ml]; }
    u16* dst = WoT + (size_t)(c0 + ml) * 1024 + r0 + cb * 16;
    *(bf16x8*)(dst) = o0.v;
    *(bf16x8*)(dst + 8) = o1.v;
  }
}

// ---------- kernel 2: QKV GEMM -> Q (prescaled), K: [B,H,S,D] bf16 ; V: [B,H,D,S] bf16 ----------

__global__ __launch_bounds__(256)
void gemm_qkv_kernel(const u16* __restrict__ A0, const u16* __restrict__ A1, const u16* __restrict__ A2,
                     const u16* __restrict__ B0, const u16* __restrict__ B1, const u16* __restrict__ B2,
                     const float* __restrict__ bias0, const float* __restrict__ bias1,
                     const float* __restrict__ bias2,
                     u16* __restrict__ O0, u16* __restrict__ O1, u16* __restrict__ O2) {
  const int bz = blockIdx.z;
  const u16* A = bz == 0 ? A0 : (bz == 1 ? A1 : A2);
  const u16* Bt = bz == 0 ? B0 : (bz == 1 ? B1 : B2);
  const float* bias = bz == 0 ? bias0 : (bz == 1 ? bias1 : bias2);
  u16* O = bz == 0 ? O0 : (bz == 1 ? O1 : O2);

  __shared__ u16 As[128 * 64];
  __shared__ u16 Bs[128 * 64];
  const int m0 = blockIdx.x * 128;
  const int n0 = blockIdx.y * 128;
  const int tid = threadIdx.x;
  const int wave = tid >> 6, lane = tid & 63;
  const int wr = wave >> 1, wc = wave & 1;
  const int lrow = lane >> 3;
  const int lcol = (lane & 7) * 8;

  f32x4 acc[4][4] = {};

  for (int kt = 0; kt < 1024; kt += 64) {
    __syncthreads();
#pragma unroll
    for (int j = 0; j < 4; ++j) {
      int c = wave * 4 + j;
      int row = c * 8 + lrow;
      async16(A + (size_t)(m0 + row) * 1024 + kt + lcol, As + c * 512);
      async16(Bt + (size_t)(n0 + row) * 1024 + kt + lcol, Bs + c * 512);
    }
    asm volatile("s_waitcnt vmcnt(0)" ::: "memory");
    __syncthreads();
#pragma unroll
    for (int kk = 0; kk < 64; kk += 32) {
      bf16x8 af[4], bfv[4];
#pragma unroll
      for (int i = 0; i < 4; ++i) {
        af[i] = *(const bf16x8*)(As + (wr * 64 + i * 16 + (lane & 15)) * 64 + kk + 8 * (lane >> 4));
        bfv[i] = *(const bf16x8*)(Bs + (wc * 64 + i * 16 + (lane & 15)) * 64 + kk + 8 * (lane >> 4));
      }
#pragma unroll
      for (int i = 0; i < 4; ++i)
#pragma unroll
        for (int j = 0; j < 4; ++j)
          acc[i][j] = MFMA(af[i], bfv[j], acc[i][j]);
    }
  }
  if (bz == 2) {
    // V^T: [B,H,D,S]
#pragma unroll
    for (int fm = 0; fm < 4; ++fm) {
#pragma unroll
      for (int fn = 0; fn < 4; ++fn) {
        int n = n0 + wc * 64 + fn * 16 + (lane & 15);
        int hh = n >> 6, d = n & 63;
        float bv = bias[n];
        int m_base = m0 + wr * 64 + fm * 16 + (lane >> 4) * 4;
        int b = m_base >> 11, s = m_base & 2047;
        union { u16 s4[4]; uint2 u2; } pk;
#pragma unroll
        for (int i = 0; i < 4; ++i) pk.s4[i] = f2bf(acc[fm][fn][i] + bv);
        *(uint2*)(&O[(((size_t)b * 16 + hh) * 64 + d) * 2048 + s]) = pk.u2;
      }
    }
  } else {
    const float oscale = (bz == 0) ? QSCALE : 1.0f;
#pragma unroll
    for (int fm = 0; fm < 4; ++fm) {
#pragma unroll
      for (int fn = 0; fn < 4; ++fn) {
        int n = n0 + wc * 64 + fn * 16 + (lane & 15);
        int hh = n >> 6, d = n & 63;
        float bv = bias[n];
#pragma unroll
        for (int i = 0; i < 4; ++i) {
          int m = m0 + wr * 64 + fm * 16 + (lane >> 4) * 4 + i;
          int b = m >> 11, s = m & 2047;
          O[(((size_t)b * 16 + hh) * 2048 + s) * 64 + d] = f2bf((acc[fm][fn][i] + bv) * oscale);
        }
      }
    }
  }
}

// ---------- kernel 3: causal flash attention, kv-split x2, 3-buffer 2-deep pipeline ----------
// grid (16, 32, 2). 256 thr = 4 waves, 32 q-rows/wave. ONE barrier per iter, counted vmcnt.

__global__ __launch_bounds__(256)
void attn_kernel(const u16* __restrict__ q, const u16* __restrict__ k,
                 const u16* __restrict__ vt,
                 u16* __restrict__ PO, float* __restrict__ PM, float* __restrict__ PL) {
  const int bx = blockIdx.x, by = blockIdx.y;
  const int qb = (by < 16) ? bx : (15 - bx);
  const int bh = by;
  const int zsp = blockIdx.z;      // kv tile parity this block handles
  const int tid = threadIdx.x;
  const int w = tid >> 6, lane = tid & 63;
  const int l31 = lane & 31, h = lane >> 5;
  const int swz = lane & 7;
  const size_t base = (size_t)bh * (2048 * 64);

  __shared__ u16 Ks[3][64 * 64];
  __shared__ u16 Vs[3][64 * 64];

  const int wq0 = qb * 128 + w * 32;
  const int q_glob = wq0 + l31;

  // Q fragments: B-operand, lane holds Q[q=l31][d = 16*kk + 8*h + j]
  bf16x8 qf[4];
  {
    const u16* qp = q + base + (size_t)q_glob * 64 + 8 * h;
#pragma unroll
    for (int kk = 0; kk < 4; ++kk) qf[kk] = *(const bf16x8*)(qp + 16 * kk);
  }

  // staging: lane writes LDS 16B-group lane&7 (linear); source pre-swizzled by ^ (lane>>3)
  const int r8 = lane >> 3;
  const int cg = (lane & 7) ^ r8;
  const int c0 = 2 * w;

  f32x16 oa0 = {}, oa1 = {};   // O^T acc: lane holds q=l31, d rows
  float mreg = -1e30f, lsum = 0.f;

  const int nj = qb + 1;  // tiles of parity zsp in [0, 2qb+1]

#define STAGE(J, B)                                                              \
  {                                                                              \
    const int kv_ = ((zsp) + 2 * (J)) * 64;                                      \
    _Pragma("unroll")                                                            \
    for (int c_ = 0; c_ < 2; ++c_) {                                             \
      int chunk_ = c0 + c_;                                                      \
      int row_ = chunk_ * 8 + r8;                                                \
      async16(k + base + (size_t)(kv_ + row_) * 64 + cg * 8, &Ks[B][chunk_ * 512]); \
      async16(vt + base + (size_t)row_ * 2048 + kv_ + cg * 8, &Vs[B][chunk_ * 512]); \
    }                                                                            \
  }

  // prologue: tile 0 staged + visible to all waves; tile 1 in flight
  STAGE(0, 0);
  asm volatile("s_waitcnt vmcnt(0)" ::: "memory");
  __builtin_amdgcn_s_barrier();
  if (nj > 1) STAGE(1, 1);

  int bcur = 0;
  for (int t = 0; t < nj; ++t) {
    const int kv0 = (zsp + 2 * t) * 64;
    if (t + 2 < nj) {
      const int bnext2 = (bcur + 2) % 3;
      STAGE(t + 2, bnext2);
    }

    if (kv0 <= wq0 + 31) {  // skip fully-masked tiles (wave-uniform)
      bf16x8 kf0[4], kf1[4];
#pragma unroll
      for (int kk = 0; kk < 4; ++kk) {
        const int colo = ((2 * kk + h) ^ swz) * 8;
        kf0[kk] = *(const bf16x8*)(&Ks[bcur][l31 * 64 + colo]);
        kf1[kk] = *(const bf16x8*)(&Ks[bcur][(32 + l31) * 64 + colo]);
      }
      f32x16 sa0 = {}, sa1 = {};
      __builtin_amdgcn_s_setprio(1);
#pragma unroll
      for (int kk = 0; kk < 4; ++kk) {
        sa0 = MFMA32(kf0[kk], qf[kk], sa0);
        sa1 = MFMA32(kf1[kk], qf[kk], sa1);
      }
      __builtin_amdgcn_s_setprio(0);

      if (kv0 + 63 > wq0) {  // diagonal tile: apply causal mask
        int kvoff = kv0 + 4 * h - q_glob;
#pragma unroll
        for (int rg = 0; rg < 16; ++rg) {
          const int pat = (rg & 3) + 8 * (rg >> 2);
          if (pat + kvoff > 0) sa0[rg] = -1e30f;
          if (pat + 32 + kvoff > 0) sa1[rg] = -1e30f;
        }
      }

      // tree max over 32 values
      float mx[8];
#pragma unroll
      for (int i = 0; i < 8; ++i)
        mx[i] = fmaxf(fmaxf(sa0[i], sa0[i + 8]), fmaxf(sa1[i], sa1[i + 8]));
      float pmax = fmaxf(fmaxf(fmaxf(mx[0], mx[1]), fmaxf(mx[2], mx[3])),
                         fmaxf(fmaxf(mx[4], mx[5]), fmaxf(mx[6], mx[7])));
      pmax = fmaxf(pmax, __shfl_xor(pmax, 32));

      // defer-max: rescale only when max grew past threshold
      if (!__all(pmax <= mreg + 8.f)) {
        float mnew = fmaxf(mreg, pmax);
        float alpha = __builtin_amdgcn_exp2f(mreg - mnew);
        mreg = mnew;
        lsum *= alpha;
#pragma unroll
        for (int i = 0; i < 16; ++i) { oa0[i] *= alpha; oa1[i] *= alpha; }
      }

      // P = exp2(S - m)
      float p0a[16], p1a[16];
#pragma unroll
      for (int i = 0; i < 16; ++i) {
        p0a[i] = __builtin_amdgcn_exp2f(sa0[i] - mreg);
        p1a[i] = __builtin_amdgcn_exp2f(sa1[i] - mreg);
      }
      u32 P32[2][4][2];
#pragma unroll
      for (int tt = 0; tt < 4; ++tt)
#pragma unroll
        for (int cc = 0; cc < 2; ++cc) {
          P32[0][tt][cc] = cvtpk(p0a[4 * tt + 2 * cc], p0a[4 * tt + 2 * cc + 1]);
          P32[1][tt][cc] = cvtpk(p1a[4 * tt + 2 * cc], p1a[4 * tt + 2 * cc + 1]);
        }
      // tree row-sum
      float r8v[8];
#pragma unroll
      for (int i = 0; i < 8; ++i)
        r8v[i] = (p0a[i] + p0a[i + 8]) + (p1a[i] + p1a[i + 8]);
      float rsum = ((r8v[0] + r8v[1]) + (r8v[2] + r8v[3])) +
                   ((r8v[4] + r8v[5]) + (r8v[6] + r8v[7]));
      rsum += __shfl_xor(rsum, 32);
      lsum += rsum;

      // exchange P into B-fragment layout (kv = 16*kk + 8*h + j)
      u32 pbu[4][4];
#pragma unroll
      for (int kk = 0; kk < 4; ++kk) {
        const int fp = kk >> 1;
        const int ta = 2 * (kk & 1);
#pragma unroll
        for (int cc = 0; cc < 2; ++cc) {
          u32 a = P32[fp][ta][cc], b = P32[fp][ta + 1][cc];
          u32 sb = (u32)__shfl_xor((int)b, 32);
          u32 sa2 = (u32)__shfl_xor((int)a, 32);
          pbu[kk][cc] = h ? sb : a;
          pbu[kk][2 + cc] = h ? b : sa2;
        }
      }
      bf16x8 vf0[4], vf1[4];
#pragma unroll
      for (int kk = 0; kk < 4; ++kk) {
        const int colo = ((2 * kk + h) ^ swz) * 8;
        vf0[kk] = *(const bf16x8*)(&Vs[bcur][l31 * 64 + colo]);
        vf1[kk] = *(const bf16x8*)(&Vs[bcur][(32 + l31) * 64 + colo]);
      }
      __builtin_amdgcn_s_setprio(1);
#pragma unroll
      for (int kk = 0; kk < 4; ++kk) {
        union { u32 u[4]; bf16x8 v; } pb;
#pragma unroll
        for (int cc = 0; cc < 4; ++cc) pb.u[cc] = pbu[kk][cc];
        oa0 = MFMA32(vf0[kk], pb.v, oa0);
        oa1 = MFMA32(vf1[kk], pb.v, oa1);
      }
      __builtin_amdgcn_s_setprio(0);
    }

    // end-of-iter: ensure tile t+1 loads (mine) are complete; t+2 stays in flight.
    if (t + 1 < nj) {
      if (t + 2 < nj) {
        asm volatile("s_waitcnt vmcnt(4) lgkmcnt(0)" ::: "memory");
      } else {
        asm volatile("s_waitcnt vmcnt(0) lgkmcnt(0)" ::: "memory");
      }
      __builtin_amdgcn_s_barrier();
    }
    bcur = (bcur + 1) % 3;
  }
#undef STAGE

  // write normalized partial O (bf16) + m,l (f32)
  const float inv = lsum > 0.f ? 1.f / lsum : 0.f;
  const size_t prow = (size_t)(zsp * 32 + bh) * 2048 + q_glob;
  u16* pop = PO + prow * 64;
#pragma unroll
  for (int fd = 0; fd < 2; ++fd)
#pragma unroll
    for (int tt = 0; tt < 4; ++tt) {
      union { u16 s[4]; uint2 u2; } pk;
#pragma unroll
      for (int i = 0; i < 4; ++i) {
        float ov = (fd ? oa1[4 * tt + i] : oa0[4 * tt + i]) * inv;
        pk.s[i] = f2bf(ov);
      }
      *(uint2*)(pop + fd * 32 + tt * 8 + 4 * h) = pk.u2;
    }
  if (h == 0) {
    PM[prow] = mreg;
    PL[prow] = lsum;
  }
}

// ---------- kernel 4: combine kv-split partials -> Z [B,S,H,D] bf16 ----------

__global__ __launch_bounds__(256)
void combine_kernel(const u16* __restrict__ PO, const float* __restrict__ PM,
                    const float* __restrict__ PL, u16* __restrict__ z) {
  const int g = blockIdx.x * 256 + threadIdx.x;  // 4 threads per q-row
  const int row = g >> 2, dp = (g & 3) * 16;
  const int bh = row >> 11, qq = row & 2047;
  const int b = bh >> 4, head = bh & 15;
  float m0 = PM[row], m1 = PM[65536 + row];
  float l0 = PL[row], l1 = PL[65536 + row];
  float m = fmaxf(m0, m1);
  float a0 = l0 * __builtin_amdgcn_exp2f(m0 - m);
  float a1 = l1 * __builtin_amdgcn_exp2f(m1 - m);
  float inv = 1.f / (a0 + a1);
  a0 *= inv; a1 *= inv;
  const u16* p0 = PO + (size_t)row * 64 + dp;
  const u16* p1 = PO + (size_t)(65536 + row) * 64 + dp;
  union { bf16x8 v; u16 s[8]; } i0a, i0b, i1a, i1b, oA, oB;
  i0a.v = *(const bf16x8*)(p0);
  i0b.v = *(const bf16x8*)(p0 + 8);
  i1a.v = *(const bf16x8*)(p1);
  i1b.v = *(const bf16x8*)(p1 + 8);
#pragma unroll
  for (int j = 0; j < 8; ++j) {
    oA.s[j] = f2bf(bf2f(i0a.s[j]) * a0 + bf2f(i1a.s[j]) * a1);
    oB.s[j] = f2bf(bf2f(i0b.s[j]) * a0 + bf2f(i1b.s[j]) * a1);
  }
  u16* zp = z + (((size_t)b * 2048 + qq) * 16 + head) * 64 + dp;
  *(bf16x8*)(zp) = oA.v;
  *(bf16x8*)(zp + 8) = oB.v;
}

// ---------- kernel 5: output projection GEMM: z[4096,1024] x WoT -> fp32 out + b_O ----------

__global__ __launch_bounds__(256)
void gemm_out_kernel(const u16* __restrict__ A, const u16* __restrict__ Bt,
                     const float* __restrict__ bias, float* __restrict__ Out) {
  __shared__ u16 As[128 * 64];
  __shared__ u16 Bs[128 * 64];
  const int m0 = blockIdx.x * 128;
  const int n0 = blockIdx.y * 128;
  const int tid = threadIdx.x;
  const int wave = tid >> 6, lane = tid & 63;
  const int wr = wave >> 1, wc = wave & 1;
  const int lrow = lane >> 3;
  const int lcol = (lane & 7) * 8;

  f32x4 acc[4][4] = {};

  for (int kt = 0; kt < 1024; kt += 64) {
    __syncthreads();
#pragma unroll
    for (int j = 0; j < 4; ++j) {
      int c = wave * 4 + j;
      int row = c * 8 + lrow;
      async16(A + (size_t)(m0 + row) * 1024 + kt + lcol, As + c * 512);
      async16(Bt + (size_t)(n0 + row) * 1024 + kt + lcol, Bs + c * 512);
    }
    asm volatile("s_waitcnt vmcnt(0)" ::: "memory");
    __syncthreads();
#pragma unroll
    for (int kk = 0; kk < 64; kk += 32) {
      bf16x8 af[4], bfv[4];
#pragma unroll
      for (int i = 0; i < 4; ++i) {
        af[i] = *(const bf16x8*)(As + (wr * 64 + i * 16 + (lane & 15)) * 64 + kk + 8 * (lane >> 4));
        bfv[i] = *(const bf16x8*)(Bs + (wc * 64 + i * 16 + (lane & 15)) * 64 + kk + 8 * (lane >> 4));
      }
#pragma unroll
      for (int i = 0; i < 4; ++i)
#pragma unroll
        for (int j = 0; j < 4; ++j)
          acc[i][j] = MFMA(af[i], bfv[j], acc[i][j]);
    }
  }
#pragma unroll
  for (int fm = 0; fm < 4; ++fm) {
#pragma unroll
    for (int fn = 0; fn < 4; ++fn) {
      int n = n0 + wc * 64 + fn * 16 + (lane & 15);
      float bv = bias[n];
#pragma unroll
      for (int i = 0; i < 4; ++i) {
        int m = m0 + wr * 64 + fm * 16 + (lane >> 4) * 4 + i;
        Out[(size_t)m * 1024 + n] = acc[fm][fn][i] + bv;
      }
    }
  }
}

// ---------- launcher ----------

extern "C" void kernel_launch(void* const* d_in, const int* in_sizes, int n_in,
                              void* d_out, int out_size, void* d_ws, size_t ws_size,
                              hipStream_t stream) {
  const float* xq = (const float*)d_in[0];
  const float* xk = (const float*)d_in[1];
  const float* xv = (const float*)d_in[2];
  const float* WQ = (const float*)d_in[3];
  const float* WK = (const float*)d_in[4];
  const float* WV = (const float*)d_in[5];
  const float* WO = (const float*)d_in[6];
  const float* bQ = (const float*)d_in[7];
  const float* bK = (const float*)d_in[8];
  const float* bV = (const float*)d_in[9];
  const float* bO = (const float*)d_in[10];
  float* out = (float*)d_out;

  char* ws = (char*)d_ws;
  const size_t MB = 1024 * 1024;
  u16* Xq = (u16*)(ws);             // 8MB each (4096x1024 bf16); dead after gemm_qkv
  u16* Xk = (u16*)(ws + 8 * MB);
  u16* Xv = (u16*)(ws + 16 * MB);
  u16* WqT = (u16*)(ws + 24 * MB);  // 2MB each; dead after gemm_qkv
  u16* WkT = (u16*)(ws + 26 * MB);
  u16* WvT = (u16*)(ws + 28 * MB);
  u16* WoT = (u16*)(ws + 30 * MB);  // live until gemm_out
  u16* Q = (u16*)(ws + 32 * MB);    // 8MB [B,H,S,D] (prescaled)
  u16* K = (u16*)(ws + 40 * MB);    // 8MB [B,H,S,D]
  u16* V = (u16*)(ws + 48 * MB);    // 8MB [B,H,D,S]  (transposed)
  u16* Z = (u16*)(ws + 56 * MB);    // 8MB [B,S,H,D]
  // kv-split partials overlay the dead Xq/Xk/Xv region:
  u16* PO = (u16*)(ws);                       // 16MB: [2][32][2048][64] bf16
  float* PM = (float*)(ws + 17 * MB);         // 512KB: [2][32][2048] f32
  float* PL = (float*)(ws + 17 * MB + 524288);// 512KB

  prep_kernel<<<dim3(7168), 256, 0, stream>>>(xq, xk, xv, Xq, Xk, Xv,
                                              WQ, WK, WV, WqT, WkT, WvT, WO, WoT);
  gemm_qkv_kernel<<<dim3(32, 8, 3), 256, 0, stream>>>(Xq, Xk, Xv, WqT, WkT, WvT,
                                                      bQ, bK, bV, Q, K, V);
  attn_kernel<<<dim3(16, 32, 2), 256, 0, stream>>>(Q, K, V, PO, PM, PL);
  combine_kernel<<<dim3(1024), 256, 0, stream>>>(PO, PM, PL, Z);
  gemm_out_kernel<<<dim3(32, 8), 256, 0, stream>>>(Z, WoT, bO, out);
}

// Round 6
// 153.794 us; speedup vs baseline: 1.5067x; 1.0111x over previous
//
#include <hip/hip_runtime.h>
#include <cstdint>
#include <cmath>

typedef __attribute__((ext_vector_type(4))) float f32x4;
typedef __attribute__((ext_vector_type(16))) float f32x16;
typedef __attribute__((ext_vector_type(8))) short bf16x8;
using u16 = unsigned short;
using u32 = uint32_t;

// ---------- helpers ----------

static __device__ __forceinline__ u16 f2bf(float f) {
  uint32_t u = __float_as_uint(f);
  u += 0x7fffu + ((u >> 16) & 1u);
  return (u16)(u >> 16);
}

static __device__ __forceinline__ float bf2f(u16 x) {
  return __uint_as_float((u32)x << 16);
}

// round f32 to float8_e4m3fn (RNE), return dequantized f32.
static __device__ __forceinline__ float quant_e4m3(float x) {
  uint32_t u = __float_as_uint(x);
  uint32_t absu = u & 0x7fffffffu;
  if (absu >= 0x3c800000u) {  // |x| >= 2^-6 : e4m3 normal, keep 3 mantissa bits RNE
    uint32_t lsb = (absu >> 20) & 1u;
    uint32_t r = (absu + 0x7ffffu + lsb) & ~0xfffffu;
    return __uint_as_float((u & 0x80000000u) | r);
  }
  return rintf(x * 512.0f) * 0.001953125f;
}

static __device__ __forceinline__ void async16(const void* g, void* l) {
  __builtin_amdgcn_global_load_lds(
      (const __attribute__((address_space(1))) void*)g,
      (__attribute__((address_space(3))) void*)l, 16, 0, 0);
}

static __device__ __forceinline__ u32 cvtpk(float a, float b) {
  u32 r;
  asm("v_cvt_pk_bf16_f32 %0, %1, %2" : "=v"(r) : "v"(a), "v"(b));
  return r;
}

#define MFMA(a, b, c) __builtin_amdgcn_mfma_f32_16x16x32_bf16(a, b, c, 0, 0, 0)
#define MFMA32(a, b, c) __builtin_amdgcn_mfma_f32_32x32x16_bf16(a, b, c, 0, 0, 0)

// log2(e)/sqrt(64): folded into Q at projection time so attn uses exp2 directly.
#define QSCALE 0.18033688011112042f

// ---------- kernel 1: merged prep (quantize inputs + weight transposes) ----------

__global__ __launch_bounds__(256)
void prep_kernel(const float* __restrict__ xq, const float* __restrict__ xk,
                 const float* __restrict__ xv,
                 u16* __restrict__ Xq, u16* __restrict__ Xk, u16* __restrict__ Xv,
                 const float* __restrict__ WQ, const float* __restrict__ WK,
                 const float* __restrict__ WV,
                 u16* __restrict__ WqT, u16* __restrict__ WkT, u16* __restrict__ WvT,
                 const float* __restrict__ WO, u16* __restrict__ WoT) {
  __shared__ u16 T[64][72];
  const int bid = blockIdx.x;
  const int t = threadIdx.x;

  if (bid < 6144) {  // activation quantize: fp32 -> e4m3 -> bf16
    const int which = bid >> 11, idx = bid & 2047;
    const float* x = which == 0 ? xq : (which == 1 ? xk : xv);
    u16* y = which == 0 ? Xq : (which == 1 ? Xk : Xv);
    int i = (idx * 256 + t) * 8;
    f32x4 a = *(const f32x4*)(x + i);
    f32x4 b = *(const f32x4*)(x + i + 4);
    union { bf16x8 v; u16 s[8]; } r;
#pragma unroll
    for (int j = 0; j < 4; ++j) r.s[j] = f2bf(quant_e4m3(a[j]));
#pragma unroll
    for (int j = 0; j < 4; ++j) r.s[4 + j] = f2bf(quant_e4m3(b[j]));
    *(bf16x8*)(y + i) = r.v;
    return;
  }

  if (bid < 6912) {  // W_{Q,K,V} [H,M,D] -> quant -> bf16 Bt[n=h*64+d][k=m]
    const int sub = bid - 6144;
    const int zz = sub >> 8;
    const int rem = sub & 255;
    const int h = rem >> 4;
    const int k0 = (rem & 15) * 64;
    const float* w = zz == 0 ? WQ : (zz == 1 ? WK : WV);
    u16* wt = zz == 0 ? WqT : (zz == 1 ? WkT : WvT);
    int ml = t >> 2, d0 = (t & 3) * 16;
    const float* src = w + ((size_t)h * 1024 + (k0 + ml)) * 64 + d0;
    u16 q16[16];
#pragma unroll
    for (int j = 0; j < 16; j += 4) {
      f32x4 f = *(const f32x4*)(src + j);
#pragma unroll
      for (int c = 0; c < 4; ++c) q16[j + c] = f2bf(quant_e4m3(f[c]));
    }
#pragma unroll
    for (int j = 0; j < 16; ++j) T[ml][d0 + j] = q16[j];
    __syncthreads();
    int d = t >> 2, cb = t & 3;
    union { bf16x8 v; u16 s[8]; } o0, o1;
#pragma unroll
    for (int j = 0; j < 8; ++j) { o0.s[j] = T[cb * 16 + j][d]; o1.s[j] = T[cb * 16 + 8 + j][d]; }
    u16* dst = wt + (size_t)(h * 64 + d) * 1024 + k0 + cb * 16;
    *(bf16x8*)(dst) = o0.v;
    *(bf16x8*)(dst + 8) = o1.v;
    return;
  }

  {  // W_O [H,D,M] -> bf16 Bt[n=m][k=h*64+d]
    const int sub = bid - 6912;
    const int r0 = (sub >> 4) * 64;
    const int c0 = (sub & 15) * 64;
    int rl = t >> 2, cl0 = (t & 3) * 16;
    const float* src = WO + (size_t)(r0 + rl) * 1024 + c0 + cl0;
    u16 q16[16];
#pragma unroll
    for (int j = 0; j < 16; j += 4) {
      f32x4 f = *(const f32x4*)(src + j);
#pragma unroll
      for (int c = 0; c < 4; ++c) q16[j + c] = f2bf(f[c]);
    }
#pragma unroll
    for (int j = 0; j < 16; ++j) T[rl][cl0 + j] = q16[j];
    __syncthreads();
    int ml = t >> 2, cb = t & 3;
    union { bf16x8 v; u16 s[8]; } o0, o1;
#pragma unroll
    for (int j = 0; j < 8; ++j) { o0.s[j] = T[cb * 16 + j][ml]; o1.s[j] = T[cb * 16 + 8 + j][ml]; }
    u16* dst = WoT + (size_t)(c0 + ml) * 1024 + r0 + cb * 16;
    *(bf16x8*)(dst) = o0.v;
    *(bf16x8*)(dst + 8) = o1.v;
  }
}

// ---------- kernel 2: QKV GEMM -> Q (prescaled), K: [B,H,S,D] bf16 ; V: [B,H,D,S] bf16 ----------

__global__ __launch_bounds__(256)
void gemm_qkv_kernel(const u16* __restrict__ A0, const u16* __restrict__ A1, const u16* __restrict__ A2,
                     const u16* __restrict__ B0, const u16* __restrict__ B1, const u16* __restrict__ B2,
                     const float* __restrict__ bias0, const float* __restrict__ bias1,
                     const float* __restrict__ bias2,
                     u16* __restrict__ O0, u16* __restrict__ O1, u16* __restrict__ O2) {
  const int bz = blockIdx.z;
  const u16* A = bz == 0 ? A0 : (bz == 1 ? A1 : A2);
  const u16* Bt = bz == 0 ? B0 : (bz == 1 ? B1 : B2);
  const float* bias = bz == 0 ? bias0 : (bz == 1 ? bias1 : bias2);
  u16* O = bz == 0 ? O0 : (bz == 1 ? O1 : O2);

  __shared__ u16 As[128 * 64];
  __shared__ u16 Bs[128 * 64];
  const int m0 = blockIdx.x * 128;
  const int n0 = blockIdx.y * 128;
  const int tid = threadIdx.x;
  const int wave = tid >> 6, lane = tid & 63;
  const int wr = wave >> 1, wc = wave & 1;
  const int lrow = lane >> 3;
  const int lcol = (lane & 7) * 8;

  f32x4 acc[4][4] = {};

  for (int kt = 0; kt < 1024; kt += 64) {
    __syncthreads();
#pragma unroll
    for (int j = 0; j < 4; ++j) {
      int c = wave * 4 + j;
      int row = c * 8 + lrow;
      async16(A + (size_t)(m0 + row) * 1024 + kt + lcol, As + c * 512);
      async16(Bt + (size_t)(n0 + row) * 1024 + kt + lcol, Bs + c * 512);
    }
    asm volatile("s_waitcnt vmcnt(0)" ::: "memory");
    __syncthreads();
#pragma unroll
    for (int kk = 0; kk < 64; kk += 32) {
      bf16x8 af[4], bfv[4];
#pragma unroll
      for (int i = 0; i < 4; ++i) {
        af[i] = *(const bf16x8*)(As + (wr * 64 + i * 16 + (lane & 15)) * 64 + kk + 8 * (lane >> 4));
        bfv[i] = *(const bf16x8*)(Bs + (wc * 64 + i * 16 + (lane & 15)) * 64 + kk + 8 * (lane >> 4));
      }
#pragma unroll
      for (int i = 0; i < 4; ++i)
#pragma unroll
        for (int j = 0; j < 4; ++j)
          acc[i][j] = MFMA(af[i], bfv[j], acc[i][j]);
    }
  }
  if (bz == 2) {
    // V^T: [B,H,D,S]
#pragma unroll
    for (int fm = 0; fm < 4; ++fm) {
#pragma unroll
      for (int fn = 0; fn < 4; ++fn) {
        int n = n0 + wc * 64 + fn * 16 + (lane & 15);
        int hh = n >> 6, d = n & 63;
        float bv = bias[n];
        int m_base = m0 + wr * 64 + fm * 16 + (lane >> 4) * 4;
        int b = m_base >> 11, s = m_base & 2047;
        union { u16 s4[4]; uint2 u2; } pk;
#pragma unroll
        for (int i = 0; i < 4; ++i) pk.s4[i] = f2bf(acc[fm][fn][i] + bv);
        *(uint2*)(&O[(((size_t)b * 16 + hh) * 64 + d) * 2048 + s]) = pk.u2;
      }
    }
  } else {
    const float oscale = (bz == 0) ? QSCALE : 1.0f;
#pragma unroll
    for (int fm = 0; fm < 4; ++fm) {
#pragma unroll
      for (int fn = 0; fn < 4; ++fn) {
        int n = n0 + wc * 64 + fn * 16 + (lane & 15);
        int hh = n >> 6, d = n & 63;
        float bv = bias[n];
#pragma unroll
        for (int i = 0; i < 4; ++i) {
          int m = m0 + wr * 64 + fm * 16 + (lane >> 4) * 4 + i;
          int b = m >> 11, s = m & 2047;
          O[(((size_t)b * 16 + hh) * 2048 + s) * 64 + d] = f2bf((acc[fm][fn][i] + bv) * oscale);
        }
      }
    }
  }
}

// ---------- kernel 3: causal flash attention, uniform-work blocks ----------
// grid (8, 32, 3): x -> q-tile pair {x, 15-x} (exactly 34 kv tiles/pair), y = b*16+h,
// z = kv-split (tiles t with t%3==z). 256 thr = 4 waves, 32 q-rows/wave.
// Every block does 11-12 tile-iterations -> uniform duration, no tail.

__global__ __launch_bounds__(256)
void attn_kernel(const u16* __restrict__ q, const u16* __restrict__ k,
                 const u16* __restrict__ vt,
                 u16* __restrict__ PO, float* __restrict__ PM, float* __restrict__ PL) {
  const int x = blockIdx.x, bh = blockIdx.y, zs = blockIdx.z;
  const int tid = threadIdx.x;
  const int w = tid >> 6, lane = tid & 63;
  const int l31 = lane & 31, h = lane >> 5;
  const int swz = lane & 7;
  const size_t base = (size_t)bh * (2048 * 64);

  __shared__ u16 Ks[3][64 * 64];
  __shared__ u16 Vs[3][64 * 64];

  // staging: lane writes LDS 16B-group lane&7 (linear); source pre-swizzled by ^ (lane>>3)
  const int r8 = lane >> 3;
  const int cg = (lane & 7) ^ r8;
  const int c0 = 2 * w;

#define STAGE(J, B)                                                              \
  {                                                                              \
    const int kv_ = (zs + 3 * (J)) * 64;                                         \
    _Pragma("unroll")                                                            \
    for (int c_ = 0; c_ < 2; ++c_) {                                             \
      int chunk_ = c0 + c_;                                                      \
      int row_ = chunk_ * 8 + r8;                                                \
      async16(k + base + (size_t)(kv_ + row_) * 64 + cg * 8, &Ks[B][chunk_ * 512]); \
      async16(vt + base + (size_t)row_ * 2048 + kv_ + cg * 8, &Vs[B][chunk_ * 512]); \
    }                                                                            \
  }

  int bcur = 0;
#pragma unroll 1
  for (int seg = 0; seg < 2; ++seg) {
    const int qb = seg ? 15 - x : x;
    const int nj = (2 * qb + 4 - zs) / 3;  // tiles t = zs + 3j in [0, 2qb+2)
    const int wq0 = qb * 128 + w * 32;
    const int q_glob = wq0 + l31;

    // Q fragments: B-operand, lane holds Q[q=l31][d = 16*kk + 8*h + j]
    bf16x8 qf[4];
    {
      const u16* qp = q + base + (size_t)q_glob * 64 + 8 * h;
#pragma unroll
      for (int kk = 0; kk < 4; ++kk) qf[kk] = *(const bf16x8*)(qp + 16 * kk);
    }

    f32x16 oa0 = {}, oa1 = {};   // O^T acc: lane holds q=l31, d rows
    float mreg = -1e30f, lsum = 0.f;

    __builtin_amdgcn_s_barrier();  // guard LDS reuse across segments
    if (nj > 0) {
      STAGE(0, bcur);
      asm volatile("s_waitcnt vmcnt(0)" ::: "memory");
      __builtin_amdgcn_s_barrier();
      if (nj > 1) STAGE(1, (bcur + 1) % 3);

      for (int t = 0; t < nj; ++t) {
        const int kv0 = (zs + 3 * t) * 64;
        if (t + 2 < nj) STAGE(t + 2, (bcur + 2) % 3);

        if (kv0 <= wq0 + 31) {  // skip fully-masked tiles (wave-uniform)
          bf16x8 kf0[4], kf1[4];
#pragma unroll
          for (int kk = 0; kk < 4; ++kk) {
            const int colo = ((2 * kk + h) ^ swz) * 8;
            kf0[kk] = *(const bf16x8*)(&Ks[bcur][l31 * 64 + colo]);
            kf1[kk] = *(const bf16x8*)(&Ks[bcur][(32 + l31) * 64 + colo]);
          }
          f32x16 sa0 = {}, sa1 = {};
          __builtin_amdgcn_s_setprio(1);
#pragma unroll
          for (int kk = 0; kk < 4; ++kk) {
            sa0 = MFMA32(kf0[kk], qf[kk], sa0);
            sa1 = MFMA32(kf1[kk], qf[kk], sa1);
          }
          __builtin_amdgcn_s_setprio(0);

          if (kv0 + 63 > wq0) {  // diagonal tile: apply causal mask
            int kvoff = kv0 + 4 * h - q_glob;
#pragma unroll
            for (int rg = 0; rg < 16; ++rg) {
              const int pat = (rg & 3) + 8 * (rg >> 2);
              if (pat + kvoff > 0) sa0[rg] = -1e30f;
              if (pat + 32 + kvoff > 0) sa1[rg] = -1e30f;
            }
          }

          // tree max over 32 values
          float mx[8];
#pragma unroll
          for (int i = 0; i < 8; ++i)
            mx[i] = fmaxf(fmaxf(sa0[i], sa0[i + 8]), fmaxf(sa1[i], sa1[i + 8]));
          float pmax = fmaxf(fmaxf(fmaxf(mx[0], mx[1]), fmaxf(mx[2], mx[3])),
                             fmaxf(fmaxf(mx[4], mx[5]), fmaxf(mx[6], mx[7])));
          pmax = fmaxf(pmax, __shfl_xor(pmax, 32));

          // defer-max: rescale only when max grew past threshold
          if (!__all(pmax <= mreg + 8.f)) {
            float mnew = fmaxf(mreg, pmax);
            float alpha = __builtin_amdgcn_exp2f(mreg - mnew);
            mreg = mnew;
            lsum *= alpha;
#pragma unroll
            for (int i = 0; i < 16; ++i) { oa0[i] *= alpha; oa1[i] *= alpha; }
          }

          // P = exp2(S - m)
          float p0a[16], p1a[16];
#pragma unroll
          for (int i = 0; i < 16; ++i) {
            p0a[i] = __builtin_amdgcn_exp2f(sa0[i] - mreg);
            p1a[i] = __builtin_amdgcn_exp2f(sa1[i] - mreg);
          }
          u32 P32[2][4][2];
#pragma unroll
          for (int tt = 0; tt < 4; ++tt)
#pragma unroll
            for (int cc = 0; cc < 2; ++cc) {
              P32[0][tt][cc] = cvtpk(p0a[4 * tt + 2 * cc], p0a[4 * tt + 2 * cc + 1]);
              P32[1][tt][cc] = cvtpk(p1a[4 * tt + 2 * cc], p1a[4 * tt + 2 * cc + 1]);
            }
          // tree row-sum
          float r8v[8];
#pragma unroll
          for (int i = 0; i < 8; ++i)
            r8v[i] = (p0a[i] + p0a[i + 8]) + (p1a[i] + p1a[i + 8]);
          float rsum = ((r8v[0] + r8v[1]) + (r8v[2] + r8v[3])) +
                       ((r8v[4] + r8v[5]) + (r8v[6] + r8v[7]));
          rsum += __shfl_xor(rsum, 32);
          lsum += rsum;

          // exchange P into B-fragment layout (kv = 16*kk + 8*h + j)
          u32 pbu[4][4];
#pragma unroll
          for (int kk = 0; kk < 4; ++kk) {
            const int fp = kk >> 1;
            const int ta = 2 * (kk & 1);
#pragma unroll
            for (int cc = 0; cc < 2; ++cc) {
              u32 a = P32[fp][ta][cc], b = P32[fp][ta + 1][cc];
              u32 sb = (u32)__shfl_xor((int)b, 32);
              u32 sa2 = (u32)__shfl_xor((int)a, 32);
              pbu[kk][cc] = h ? sb : a;
              pbu[kk][2 + cc] = h ? b : sa2;
            }
          }
          bf16x8 vf0[4], vf1[4];
#pragma unroll
          for (int kk = 0; kk < 4; ++kk) {
            const int colo = ((2 * kk + h) ^ swz) * 8;
            vf0[kk] = *(const bf16x8*)(&Vs[bcur][l31 * 64 + colo]);
            vf1[kk] = *(const bf16x8*)(&Vs[bcur][(32 + l31) * 64 + colo]);
          }
          __builtin_amdgcn_s_setprio(1);
#pragma unroll
          for (int kk = 0; kk < 4; ++kk) {
            union { u32 u[4]; bf16x8 v; } pb;
#pragma unroll
            for (int cc = 0; cc < 4; ++cc) pb.u[cc] = pbu[kk][cc];
            oa0 = MFMA32(vf0[kk], pb.v, oa0);
            oa1 = MFMA32(vf1[kk], pb.v, oa1);
          }
          __builtin_amdgcn_s_setprio(0);
        }

        if (t + 1 < nj) {
          if (t + 2 < nj) {
            asm volatile("s_waitcnt vmcnt(4) lgkmcnt(0)" ::: "memory");
          } else {
            asm volatile("s_waitcnt vmcnt(0) lgkmcnt(0)" ::: "memory");
          }
          __builtin_amdgcn_s_barrier();
        }
        bcur = (bcur + 1) % 3;
      }
    }

    // write normalized partial O (bf16) + m,l (f32) for this segment's q-tile
    const float inv = lsum > 0.f ? 1.f / lsum : 0.f;
    const size_t prow = (size_t)(zs * 32 + bh) * 2048 + q_glob;
    u16* pop = PO + prow * 64;
#pragma unroll
    for (int fd = 0; fd < 2; ++fd)
#pragma unroll
      for (int tt = 0; tt < 4; ++tt) {
        union { u16 s[4]; uint2 u2; } pk;
#pragma unroll
        for (int i = 0; i < 4; ++i) {
          float ov = (fd ? oa1[4 * tt + i] : oa0[4 * tt + i]) * inv;
          pk.s[i] = f2bf(ov);
        }
        *(uint2*)(pop + fd * 32 + tt * 8 + 4 * h) = pk.u2;
      }
    if (h == 0) {
      PM[prow] = mreg;
      PL[prow] = lsum;
    }
  }
#undef STAGE
}

// ---------- kernel 4: combine 3 kv-split partials -> Z [B,S,H,D] bf16 ----------

__global__ __launch_bounds__(256)
void combine_kernel(const u16* __restrict__ PO, const float* __restrict__ PM,
                    const float* __restrict__ PL, u16* __restrict__ z) {
  const int g = blockIdx.x * 256 + threadIdx.x;  // 4 threads per q-row
  const int row = g >> 2, dp = (g & 3) * 16;
  const int bh = row >> 11, qq = row & 2047;
  const int b = bh >> 4, head = bh & 15;
  float m0 = PM[row], m1 = PM[65536 + row], m2 = PM[131072 + row];
  float l0 = PL[row], l1 = PL[65536 + row], l2 = PL[131072 + row];
  float m = fmaxf(m0, fmaxf(m1, m2));
  float a0 = l0 * __builtin_amdgcn_exp2f(m0 - m);
  float a1 = l1 * __builtin_amdgcn_exp2f(m1 - m);
  float a2 = l2 * __builtin_amdgcn_exp2f(m2 - m);
  float inv = 1.f / (a0 + a1 + a2);
  a0 *= inv; a1 *= inv; a2 *= inv;
  const u16* p0 = PO + (size_t)row * 64 + dp;
  const u16* p1 = PO + (size_t)(65536 + row) * 64 + dp;
  const u16* p2 = PO + (size_t)(131072 + row) * 64 + dp;
  union { bf16x8 v; u16 s[8]; } i0a, i0b, i1a, i1b, i2a, i2b, oA, oB;
  i0a.v = *(const bf16x8*)(p0);
  i0b.v = *(const bf16x8*)(p0 + 8);
  i1a.v = *(const bf16x8*)(p1);
  i1b.v = *(const bf16x8*)(p1 + 8);
  i2a.v = *(const bf16x8*)(p2);
  i2b.v = *(const bf16x8*)(p2 + 8);
#pragma unroll
  for (int j = 0; j < 8; ++j) {
    oA.s[j] = f2bf(bf2f(i0a.s[j]) * a0 + bf2f(i1a.s[j]) * a1 + bf2f(i2a.s[j]) * a2);
    oB.s[j] = f2bf(bf2f(i0b.s[j]) * a0 + bf2f(i1b.s[j]) * a1 + bf2f(i2b.s[j]) * a2);
  }
  u16* zp = z + (((size_t)b * 2048 + qq) * 16 + head) * 64 + dp;
  *(bf16x8*)(zp) = oA.v;
  *(bf16x8*)(zp + 8) = oB.v;
}

// ---------- kernel 5: output projection GEMM: z[4096,1024] x WoT -> fp32 out + b_O ----------

__global__ __launch_bounds__(256)
void gemm_out_kernel(const u16* __restrict__ A, const u16* __restrict__ Bt,
                     const float* __restrict__ bias, float* __restrict__ Out) {
  __shared__ u16 As[128 * 64];
  __shared__ u16 Bs[128 * 64];
  const int m0 = blockIdx.x * 128;
  const int n0 = blockIdx.y * 128;
  const int tid = threadIdx.x;
  const int wave = tid >> 6, lane = tid & 63;
  const int wr = wave >> 1, wc = wave & 1;
  const int lrow = lane >> 3;
  const int lcol = (lane & 7) * 8;

  f32x4 acc[4][4] = {};

  for (int kt = 0; kt < 1024; kt += 64) {
    __syncthreads();
#pragma unroll
    for (int j = 0; j < 4; ++j) {
      int c = wave * 4 + j;
      int row = c * 8 + lrow;
      async16(A + (size_t)(m0 + row) * 1024 + kt + lcol, As + c * 512);
      async16(Bt + (size_t)(n0 + row) * 1024 + kt + lcol, Bs + c * 512);
    }
    asm volatile("s_waitcnt vmcnt(0)" ::: "memory");
    __syncthreads();
#pragma unroll
    for (int kk = 0; kk < 64; kk += 32) {
      bf16x8 af[4], bfv[4];
#pragma unroll
      for (int i = 0; i < 4; ++i) {
        af[i] = *(const bf16x8*)(As + (wr * 64 + i * 16 + (lane & 15)) * 64 + kk + 8 * (lane >> 4));
        bfv[i] = *(const bf16x8*)(Bs + (wc * 64 + i * 16 + (lane & 15)) * 64 + kk + 8 * (lane >> 4));
      }
#pragma unroll
      for (int i = 0; i < 4; ++i)
#pragma unroll
        for (int j = 0; j < 4; ++j)
          acc[i][j] = MFMA(af[i], bfv[j], acc[i][j]);
    }
  }
#pragma unroll
  for (int fm = 0; fm < 4; ++fm) {
#pragma unroll
    for (int fn = 0; fn < 4; ++fn) {
      int n = n0 + wc * 64 + fn * 16 + (lane & 15);
      float bv = bias[n];
#pragma unroll
      for (int i = 0; i < 4; ++i) {
        int m = m0 + wr * 64 + fm * 16 + (lane >> 4) * 4 + i;
        Out[(size_t)m * 1024 + n] = acc[fm][fn][i] + bv;
      }
    }
  }
}

// ---------- launcher ----------

extern "C" void kernel_launch(void* const* d_in, const int* in_sizes, int n_in,
                              void* d_out, int out_size, void* d_ws, size_t ws_size,
                              hipStream_t stream) {
  const float* xq = (const float*)d_in[0];
  const float* xk = (const float*)d_in[1];
  const float* xv = (const float*)d_in[2];
  const float* WQ = (const float*)d_in[3];
  const float* WK = (const float*)d_in[4];
  const float* WV = (const float*)d_in[5];
  const float* WO = (const float*)d_in[6];
  const float* bQ = (const float*)d_in[7];
  const float* bK = (const float*)d_in[8];
  const float* bV = (const float*)d_in[9];
  const float* bO = (const float*)d_in[10];
  float* out = (float*)d_out;

  char* ws = (char*)d_ws;
  const size_t MB = 1024 * 1024;
  u16* Xq = (u16*)(ws);             // 8MB each (4096x1024 bf16); dead after gemm_qkv
  u16* Xk = (u16*)(ws + 8 * MB);
  u16* Xv = (u16*)(ws + 16 * MB);
  u16* WqT = (u16*)(ws + 24 * MB);  // 2MB each; dead after gemm_qkv
  u16* WkT = (u16*)(ws + 26 * MB);
  u16* WvT = (u16*)(ws + 28 * MB);
  u16* WoT = (u16*)(ws + 30 * MB);  // live until gemm_out
  u16* Q = (u16*)(ws + 32 * MB);    // 8MB [B,H,S,D] (prescaled)
  u16* K = (u16*)(ws + 40 * MB);    // 8MB [B,H,S,D]
  u16* V = (u16*)(ws + 48 * MB);    // 8MB [B,H,D,S]  (transposed)
  u16* Z = (u16*)(ws + 56 * MB);    // 8MB [B,S,H,D]
  // kv-split partials overlay the dead Xq/Xk/Xv/WqT regions (0..26MB):
  u16* PO = (u16*)(ws);                        // 24MB: [3][32][2048][64] bf16
  float* PM = (float*)(ws + 24 * MB);          // 768KB: [3][32][2048] f32
  float* PL = (float*)(ws + 25 * MB);          // 768KB

  prep_kernel<<<dim3(7168), 256, 0, stream>>>(xq, xk, xv, Xq, Xk, Xv,
                                              WQ, WK, WV, WqT, WkT, WvT, WO, WoT);
  gemm_qkv_kernel<<<dim3(32, 8, 3), 256, 0, stream>>>(Xq, Xk, Xv, WqT, WkT, WvT,
                                                      bQ, bK, bV, Q, K, V);
  attn_kernel<<<dim3(8, 32, 3), 256, 0, stream>>>(Q, K, V, PO, PM, PL);
  combine_kernel<<<dim3(1024), 256, 0, stream>>>(PO, PM, PL, Z);
  gemm_out_kernel<<<dim3(32, 8), 256, 0, stream>>>(Z, WoT, bO, out);
}

// Round 7
// 152.172 us; speedup vs baseline: 1.5227x; 1.0107x over previous
//
#include <hip/hip_runtime.h>
#include <cstdint>
#include <cmath>

typedef __attribute__((ext_vector_type(4))) float f32x4;
typedef __attribute__((ext_vector_type(16))) float f32x16;
typedef __attribute__((ext_vector_type(8))) short bf16x8;
using u16 = unsigned short;
using u32 = uint32_t;

// ---------- helpers ----------

static __device__ __forceinline__ u16 f2bf(float f) {
  uint32_t u = __float_as_uint(f);
  u += 0x7fffu + ((u >> 16) & 1u);
  return (u16)(u >> 16);
}

static __device__ __forceinline__ float bf2f(u16 x) {
  return __uint_as_float((u32)x << 16);
}

// round f32 to float8_e4m3fn (RNE), return dequantized f32.
static __device__ __forceinline__ float quant_e4m3(float x) {
  uint32_t u = __float_as_uint(x);
  uint32_t absu = u & 0x7fffffffu;
  if (absu >= 0x3c800000u) {  // |x| >= 2^-6 : e4m3 normal, keep 3 mantissa bits RNE
    uint32_t lsb = (absu >> 20) & 1u;
    uint32_t r = (absu + 0x7ffffu + lsb) & ~0xfffffu;
    return __uint_as_float((u & 0x80000000u) | r);
  }
  return rintf(x * 512.0f) * 0.001953125f;
}

static __device__ __forceinline__ void async16(const void* g, void* l) {
  __builtin_amdgcn_global_load_lds(
      (const __attribute__((address_space(1))) void*)g,
      (__attribute__((address_space(3))) void*)l, 16, 0, 0);
}

static __device__ __forceinline__ u32 cvtpk(float a, float b) {
  u32 r;
  asm("v_cvt_pk_bf16_f32 %0, %1, %2" : "=v"(r) : "v"(a), "v"(b));
  return r;
}

#define MFMA(a, b, c) __builtin_amdgcn_mfma_f32_16x16x32_bf16(a, b, c, 0, 0, 0)
#define MFMA32(a, b, c) __builtin_amdgcn_mfma_f32_32x32x16_bf16(a, b, c, 0, 0, 0)

// log2(e)/sqrt(64): folded into Q at projection time so attn uses exp2 directly.
#define QSCALE 0.18033688011112042f

// ---------- kernel 1: merged prep (quantize inputs + weight transposes) ----------

__global__ __launch_bounds__(256)
void prep_kernel(const float* __restrict__ xq, const float* __restrict__ xk,
                 const float* __restrict__ xv,
                 u16* __restrict__ Xq, u16* __restrict__ Xk, u16* __restrict__ Xv,
                 const float* __restrict__ WQ, const float* __restrict__ WK,
                 const float* __restrict__ WV,
                 u16* __restrict__ WqT, u16* __restrict__ WkT, u16* __restrict__ WvT,
                 const float* __restrict__ WO, u16* __restrict__ WoT) {
  __shared__ u16 T[64][72];
  const int bid = blockIdx.x;
  const int t = threadIdx.x;

  if (bid < 6144) {  // activation quantize: fp32 -> e4m3 -> bf16
    const int which = bid >> 11, idx = bid & 2047;
    const float* x = which == 0 ? xq : (which == 1 ? xk : xv);
    u16* y = which == 0 ? Xq : (which == 1 ? Xk : Xv);
    int i = (idx * 256 + t) * 8;
    f32x4 a = *(const f32x4*)(x + i);
    f32x4 b = *(const f32x4*)(x + i + 4);
    union { bf16x8 v; u16 s[8]; } r;
#pragma unroll
    for (int j = 0; j < 4; ++j) r.s[j] = f2bf(quant_e4m3(a[j]));
#pragma unroll
    for (int j = 0; j < 4; ++j) r.s[4 + j] = f2bf(quant_e4m3(b[j]));
    *(bf16x8*)(y + i) = r.v;
    return;
  }

  if (bid < 6912) {  // W_{Q,K,V} [H,M,D] -> quant -> bf16 Bt[n=h*64+d][k=m]
    const int sub = bid - 6144;
    const int zz = sub >> 8;
    const int rem = sub & 255;
    const int h = rem >> 4;
    const int k0 = (rem & 15) * 64;
    const float* w = zz == 0 ? WQ : (zz == 1 ? WK : WV);
    u16* wt = zz == 0 ? WqT : (zz == 1 ? WkT : WvT);
    int ml = t >> 2, d0 = (t & 3) * 16;
    const float* src = w + ((size_t)h * 1024 + (k0 + ml)) * 64 + d0;
    u16 q16[16];
#pragma unroll
    for (int j = 0; j < 16; j += 4) {
      f32x4 f = *(const f32x4*)(src + j);
#pragma unroll
      for (int c = 0; c < 4; ++c) q16[j + c] = f2bf(quant_e4m3(f[c]));
    }
#pragma unroll
    for (int j = 0; j < 16; ++j) T[ml][d0 + j] = q16[j];
    __syncthreads();
    int d = t >> 2, cb = t & 3;
    union { bf16x8 v; u16 s[8]; } o0, o1;
#pragma unroll
    for (int j = 0; j < 8; ++j) { o0.s[j] = T[cb * 16 + j][d]; o1.s[j] = T[cb * 16 + 8 + j][d]; }
    u16* dst = wt + (size_t)(h * 64 + d) * 1024 + k0 + cb * 16;
    *(bf16x8*)(dst) = o0.v;
    *(bf16x8*)(dst + 8) = o1.v;
    return;
  }

  {  // W_O [H,D,M] -> bf16 Bt[n=m][k=h*64+d]
    const int sub = bid - 6912;
    const int r0 = (sub >> 4) * 64;
    const int c0 = (sub & 15) * 64;
    int rl = t >> 2, cl0 = (t & 3) * 16;
    const float* src = WO + (size_t)(r0 + rl) * 1024 + c0 + cl0;
    u16 q16[16];
#pragma unroll
    for (int j = 0; j < 16; j += 4) {
      f32x4 f = *(const f32x4*)(src + j);
#pragma unroll
      for (int c = 0; c < 4; ++c) q16[j + c] = f2bf(f[c]);
    }
#pragma unroll
    for (int j = 0; j < 16; ++j) T[rl][cl0 + j] = q16[j];
    __syncthreads();
    int ml = t >> 2, cb = t & 3;
    union { bf16x8 v; u16 s[8]; } o0, o1;
#pragma unroll
    for (int j = 0; j < 8; ++j) { o0.s[j] = T[cb * 16 + j][ml]; o1.s[j] = T[cb * 16 + 8 + j][ml]; }
    u16* dst = WoT + (size_t)(c0 + ml) * 1024 + r0 + cb * 16;
    *(bf16x8*)(dst) = o0.v;
    *(bf16x8*)(dst + 8) = o1.v;
  }
}

// ---------- kernel 2: QKV GEMM, BK=32 double-buffered, swizzled LDS ----------
// LDS layout: [128 rows][4 groups of 8]; stored[row][g] = src[row][g ^ ((row>>1)&3)].

__global__ __launch_bounds__(256)
void gemm_qkv_kernel(const u16* __restrict__ A0, const u16* __restrict__ A1, const u16* __restrict__ A2,
                     const u16* __restrict__ B0, const u16* __restrict__ B1, const u16* __restrict__ B2,
                     const float* __restrict__ bias0, const float* __restrict__ bias1,
                     const float* __restrict__ bias2,
                     u16* __restrict__ O0, u16* __restrict__ O1, u16* __restrict__ O2) {
  const int bz = blockIdx.z;
  const u16* Aptr = bz == 0 ? A0 : (bz == 1 ? A1 : A2);
  const u16* Bptr = bz == 0 ? B0 : (bz == 1 ? B1 : B2);
  const float* bias = bz == 0 ? bias0 : (bz == 1 ? bias1 : bias2);
  u16* O = bz == 0 ? O0 : (bz == 1 ? O1 : O2);

  __shared__ u16 As[2][128 * 32];
  __shared__ u16 Bs[2][128 * 32];
  const int m0 = blockIdx.x * 128;
  const int n0 = blockIdx.y * 128;
  const int tid = threadIdx.x;
  const int wave = tid >> 6, lane = tid & 63;
  const int wr = wave >> 1, wc = wave & 1;
  const int srow = lane >> 2;                       // row within 16-row chunk
  const int sgrp = (lane & 3) ^ ((lane >> 3) & 3);  // pre-swizzled source group
  const int l15 = lane & 15, hi = lane >> 4;
  const int rg = hi ^ ((lane >> 1) & 3);            // swizzled read group

#define GSTAGE(KT, BUF)                                                       \
  {                                                                           \
    _Pragma("unroll") for (int j_ = 0; j_ < 2; ++j_) {                        \
      int c_ = wave * 2 + j_;                                                 \
      int row_ = c_ * 16 + srow;                                              \
      async16(Aptr + (size_t)(m0 + row_) * 1024 + (KT) + sgrp * 8,            \
              &As[BUF][c_ * 512]);                                            \
      async16(Bptr + (size_t)(n0 + row_) * 1024 + (KT) + sgrp * 8,            \
              &Bs[BUF][c_ * 512]);                                            \
    }                                                                         \
  }

  f32x4 acc[4][4] = {};

  GSTAGE(0, 0);
  __syncthreads();
  int cur = 0;
  for (int kt = 0; kt < 1024; kt += 32) {
    if (kt + 32 < 1024) GSTAGE(kt + 32, cur ^ 1);
    bf16x8 af[4], bfv[4];
#pragma unroll
    for (int i = 0; i < 4; ++i) {
      af[i] = *(const bf16x8*)(&As[cur][(wr * 64 + i * 16 + l15) * 32 + rg * 8]);
      bfv[i] = *(const bf16x8*)(&Bs[cur][(wc * 64 + i * 16 + l15) * 32 + rg * 8]);
    }
#pragma unroll
    for (int i = 0; i < 4; ++i)
#pragma unroll
      for (int j = 0; j < 4; ++j)
        acc[i][j] = MFMA(af[i], bfv[j], acc[i][j]);
    __syncthreads();
    cur ^= 1;
  }
#undef GSTAGE

  if (bz == 2) {
    // V^T: [B,H,D,S]
#pragma unroll
    for (int fm = 0; fm < 4; ++fm) {
#pragma unroll
      for (int fn = 0; fn < 4; ++fn) {
        int n = n0 + wc * 64 + fn * 16 + (lane & 15);
        int hh = n >> 6, d = n & 63;
        float bv = bias[n];
        int m_base = m0 + wr * 64 + fm * 16 + (lane >> 4) * 4;
        int b = m_base >> 11, s = m_base & 2047;
        union { u16 s4[4]; uint2 u2; } pk;
#pragma unroll
        for (int i = 0; i < 4; ++i) pk.s4[i] = f2bf(acc[fm][fn][i] + bv);
        *(uint2*)(&O[(((size_t)b * 16 + hh) * 64 + d) * 2048 + s]) = pk.u2;
      }
    }
  } else {
    const float oscale = (bz == 0) ? QSCALE : 1.0f;
#pragma unroll
    for (int fm = 0; fm < 4; ++fm) {
#pragma unroll
      for (int fn = 0; fn < 4; ++fn) {
        int n = n0 + wc * 64 + fn * 16 + (lane & 15);
        int hh = n >> 6, d = n & 63;
        float bv = bias[n];
#pragma unroll
        for (int i = 0; i < 4; ++i) {
          int m = m0 + wr * 64 + fm * 16 + (lane >> 4) * 4 + i;
          int b = m >> 11, s = m & 2047;
          O[(((size_t)b * 16 + hh) * 2048 + s) * 64 + d] = f2bf((acc[fm][fn][i] + bv) * oscale);
        }
      }
    }
  }
}

// ---------- kernel 3: causal flash attention, uniform-work blocks ----------
// grid (8, 32, 3): x -> q-tile pair {x, 15-x}, y = b*16+h, z = kv-split (t%3==z).
// 256 thr = 4 waves, 32 q-rows/wave. P-exchange via v_permlane32_swap_b32.

__global__ __launch_bounds__(256)
void attn_kernel(const u16* __restrict__ q, const u16* __restrict__ k,
                 const u16* __restrict__ vt,
                 u16* __restrict__ PO, float* __restrict__ PM, float* __restrict__ PL) {
  const int x = blockIdx.x, bh = blockIdx.y, zs = blockIdx.z;
  const int tid = threadIdx.x;
  const int w = tid >> 6, lane = tid & 63;
  const int l31 = lane & 31, h = lane >> 5;
  const int swz = lane & 7;
  const size_t base = (size_t)bh * (2048 * 64);

  __shared__ u16 Ks[3][64 * 64];
  __shared__ u16 Vs[3][64 * 64];

  // staging: lane writes LDS 16B-group lane&7 (linear); source pre-swizzled by ^ (lane>>3)
  const int r8 = lane >> 3;
  const int cg = (lane & 7) ^ r8;
  const int c0 = 2 * w;

#define STAGE(J, B)                                                              \
  {                                                                              \
    const int kv_ = (zs + 3 * (J)) * 64;                                         \
    _Pragma("unroll")                                                            \
    for (int c_ = 0; c_ < 2; ++c_) {                                             \
      int chunk_ = c0 + c_;                                                      \
      int row_ = chunk_ * 8 + r8;                                                \
      async16(k + base + (size_t)(kv_ + row_) * 64 + cg * 8, &Ks[B][chunk_ * 512]); \
      async16(vt + base + (size_t)row_ * 2048 + kv_ + cg * 8, &Vs[B][chunk_ * 512]); \
    }                                                                            \
  }

  int bcur = 0;
#pragma unroll 1
  for (int seg = 0; seg < 2; ++seg) {
    const int qb = seg ? 15 - x : x;
    const int nj = (2 * qb + 4 - zs) / 3;  // tiles t = zs + 3j in [0, 2qb+2)
    const int wq0 = qb * 128 + w * 32;
    const int q_glob = wq0 + l31;

    // Q fragments: B-operand, lane holds Q[q=l31][d = 16*kk + 8*h + j]
    bf16x8 qf[4];
    {
      const u16* qp = q + base + (size_t)q_glob * 64 + 8 * h;
#pragma unroll
      for (int kk = 0; kk < 4; ++kk) qf[kk] = *(const bf16x8*)(qp + 16 * kk);
    }

    f32x16 oa0 = {}, oa1 = {};   // O^T acc: lane holds q=l31, d rows
    float mreg = -1e30f, lsum = 0.f;

    __builtin_amdgcn_s_barrier();  // guard LDS reuse across segments
    if (nj > 0) {
      STAGE(0, bcur);
      asm volatile("s_waitcnt vmcnt(0)" ::: "memory");
      __builtin_amdgcn_s_barrier();
      if (nj > 1) STAGE(1, (bcur + 1) % 3);

      for (int t = 0; t < nj; ++t) {
        const int kv0 = (zs + 3 * t) * 64;
        if (t + 2 < nj) STAGE(t + 2, (bcur + 2) % 3);

        if (kv0 <= wq0 + 31) {  // skip fully-masked tiles (wave-uniform)
          bf16x8 kf0[4], kf1[4];
#pragma unroll
          for (int kk = 0; kk < 4; ++kk) {
            const int colo = ((2 * kk + h) ^ swz) * 8;
            kf0[kk] = *(const bf16x8*)(&Ks[bcur][l31 * 64 + colo]);
            kf1[kk] = *(const bf16x8*)(&Ks[bcur][(32 + l31) * 64 + colo]);
          }
          f32x16 sa0 = {}, sa1 = {};
          __builtin_amdgcn_s_setprio(1);
#pragma unroll
          for (int kk = 0; kk < 4; ++kk) {
            sa0 = MFMA32(kf0[kk], qf[kk], sa0);
            sa1 = MFMA32(kf1[kk], qf[kk], sa1);
          }
          __builtin_amdgcn_s_setprio(0);

          if (kv0 + 63 > wq0) {  // diagonal tile: apply causal mask
            int kvoff = kv0 + 4 * h - q_glob;
#pragma unroll
            for (int rg = 0; rg < 16; ++rg) {
              const int pat = (rg & 3) + 8 * (rg >> 2);
              if (pat + kvoff > 0) sa0[rg] = -1e30f;
              if (pat + 32 + kvoff > 0) sa1[rg] = -1e30f;
            }
          }

          // tree max over 32 values
          float mx[8];
#pragma unroll
          for (int i = 0; i < 8; ++i)
            mx[i] = fmaxf(fmaxf(sa0[i], sa0[i + 8]), fmaxf(sa1[i], sa1[i + 8]));
          float pmax = fmaxf(fmaxf(fmaxf(mx[0], mx[1]), fmaxf(mx[2], mx[3])),
                             fmaxf(fmaxf(mx[4], mx[5]), fmaxf(mx[6], mx[7])));
          pmax = fmaxf(pmax, __shfl_xor(pmax, 32));

          // defer-max: rescale only when max grew past threshold
          if (!__all(pmax <= mreg + 8.f)) {
            float mnew = fmaxf(mreg, pmax);
            float alpha = __builtin_amdgcn_exp2f(mreg - mnew);
            mreg = mnew;
            lsum *= alpha;
#pragma unroll
            for (int i = 0; i < 16; ++i) { oa0[i] *= alpha; oa1[i] *= alpha; }
          }

          // P = exp2(S - m)
          float p0a[16], p1a[16];
#pragma unroll
          for (int i = 0; i < 16; ++i) {
            p0a[i] = __builtin_amdgcn_exp2f(sa0[i] - mreg);
            p1a[i] = __builtin_amdgcn_exp2f(sa1[i] - mreg);
          }
          u32 P32[2][4][2];
#pragma unroll
          for (int tt = 0; tt < 4; ++tt)
#pragma unroll
            for (int cc = 0; cc < 2; ++cc) {
              P32[0][tt][cc] = cvtpk(p0a[4 * tt + 2 * cc], p0a[4 * tt + 2 * cc + 1]);
              P32[1][tt][cc] = cvtpk(p1a[4 * tt + 2 * cc], p1a[4 * tt + 2 * cc + 1]);
            }
          // tree row-sum
          float r8v[8];
#pragma unroll
          for (int i = 0; i < 8; ++i)
            r8v[i] = (p0a[i] + p0a[i + 8]) + (p1a[i] + p1a[i + 8]);
          float rsum = ((r8v[0] + r8v[1]) + (r8v[2] + r8v[3])) +
                       ((r8v[4] + r8v[5]) + (r8v[6] + r8v[7]));
          rsum += __shfl_xor(rsum, 32);
          lsum += rsum;

          // V fragments
          bf16x8 vf0[4], vf1[4];
#pragma unroll
          for (int kk = 0; kk < 4; ++kk) {
            const int colo = ((2 * kk + h) ^ swz) * 8;
            vf0[kk] = *(const bf16x8*)(&Vs[bcur][l31 * 64 + colo]);
            vf1[kk] = *(const bf16x8*)(&Vs[bcur][(32 + l31) * 64 + colo]);
          }
          // P exchange via permlane32_swap: A'={A.lo,B.lo}, B'={A.hi,B.hi}
          __builtin_amdgcn_s_setprio(1);
#pragma unroll
          for (int kk = 0; kk < 4; ++kk) {
            const int fp = kk >> 1;
            const int ta = 2 * (kk & 1);
            union { u32 u[4]; bf16x8 v; } pb;
#pragma unroll
            for (int cc = 0; cc < 2; ++cc) {
              u32 a = P32[fp][ta][cc], b = P32[fp][ta + 1][cc];
              asm("v_permlane32_swap_b32 %0, %1" : "+v"(a), "+v"(b));
              pb.u[cc] = a;
              pb.u[2 + cc] = b;
            }
            oa0 = MFMA32(vf0[kk], pb.v, oa0);
            oa1 = MFMA32(vf1[kk], pb.v, oa1);
          }
          __builtin_amdgcn_s_setprio(0);
        }

        if (t + 1 < nj) {
          if (t + 2 < nj) {
            asm volatile("s_waitcnt vmcnt(4) lgkmcnt(0)" ::: "memory");
          } else {
            asm volatile("s_waitcnt vmcnt(0) lgkmcnt(0)" ::: "memory");
          }
          __builtin_amdgcn_s_barrier();
        }
        bcur = (bcur + 1) % 3;
      }
    }

    // write normalized partial O (bf16) + m,l (f32) for this segment's q-tile
    const float inv = lsum > 0.f ? 1.f / lsum : 0.f;
    const size_t prow = (size_t)(zs * 32 + bh) * 2048 + q_glob;
    u16* pop = PO + prow * 64;
#pragma unroll
    for (int fd = 0; fd < 2; ++fd)
#pragma unroll
      for (int tt = 0; tt < 4; ++tt) {
        union { u16 s[4]; uint2 u2; } pk;
#pragma unroll
        for (int i = 0; i < 4; ++i) {
          float ov = (fd ? oa1[4 * tt + i] : oa0[4 * tt + i]) * inv;
          pk.s[i] = f2bf(ov);
        }
        *(uint2*)(pop + fd * 32 + tt * 8 + 4 * h) = pk.u2;
      }
    if (h == 0) {
      PM[prow] = mreg;
      PL[prow] = lsum;
    }
  }
#undef STAGE
}

// ---------- kernel 4: combine 3 kv-split partials -> Z [B,S,H,D] bf16 ----------

__global__ __launch_bounds__(256)
void combine_kernel(const u16* __restrict__ PO, const float* __restrict__ PM,
                    const float* __restrict__ PL, u16* __restrict__ z) {
  const int g = blockIdx.x * 256 + threadIdx.x;  // 4 threads per q-row
  const int row = g >> 2, dp = (g & 3) * 16;
  const int bh = row >> 11, qq = row & 2047;
  const int b = bh >> 4, head = bh & 15;
  float m0 = PM[row], m1 = PM[65536 + row], m2 = PM[131072 + row];
  float l0 = PL[row], l1 = PL[65536 + row], l2 = PL[131072 + row];
  float m = fmaxf(m0, fmaxf(m1, m2));
  float a0 = l0 * __builtin_amdgcn_exp2f(m0 - m);
  float a1 = l1 * __builtin_amdgcn_exp2f(m1 - m);
  float a2 = l2 * __builtin_amdgcn_exp2f(m2 - m);
  float inv = 1.f / (a0 + a1 + a2);
  a0 *= inv; a1 *= inv; a2 *= inv;
  const u16* p0 = PO + (size_t)row * 64 + dp;
  const u16* p1 = PO + (size_t)(65536 + row) * 64 + dp;
  const u16* p2 = PO + (size_t)(131072 + row) * 64 + dp;
  union { bf16x8 v; u16 s[8]; } i0a, i0b, i1a, i1b, i2a, i2b, oA, oB;
  i0a.v = *(const bf16x8*)(p0);
  i0b.v = *(const bf16x8*)(p0 + 8);
  i1a.v = *(const bf16x8*)(p1);
  i1b.v = *(const bf16x8*)(p1 + 8);
  i2a.v = *(const bf16x8*)(p2);
  i2b.v = *(const bf16x8*)(p2 + 8);
#pragma unroll
  for (int j = 0; j < 8; ++j) {
    oA.s[j] = f2bf(bf2f(i0a.s[j]) * a0 + bf2f(i1a.s[j]) * a1 + bf2f(i2a.s[j]) * a2);
    oB.s[j] = f2bf(bf2f(i0b.s[j]) * a0 + bf2f(i1b.s[j]) * a1 + bf2f(i2b.s[j]) * a2);
  }
  u16* zp = z + (((size_t)b * 2048 + qq) * 16 + head) * 64 + dp;
  *(bf16x8*)(zp) = oA.v;
  *(bf16x8*)(zp + 8) = oB.v;
}

// ---------- kernel 5: output projection GEMM, BK=32 dbuf, swizzled LDS ----------

__global__ __launch_bounds__(256)
void gemm_out_kernel(const u16* __restrict__ Aptr, const u16* __restrict__ Bptr,
                     const float* __restrict__ bias, float* __restrict__ Out) {
  __shared__ u16 As[2][128 * 32];
  __shared__ u16 Bs[2][128 * 32];
  const int m0 = blockIdx.x * 128;
  const int n0 = blockIdx.y * 128;
  const int tid = threadIdx.x;
  const int wave = tid >> 6, lane = tid & 63;
  const int wr = wave >> 1, wc = wave & 1;
  const int srow = lane >> 2;
  const int sgrp = (lane & 3) ^ ((lane >> 3) & 3);
  const int l15 = lane & 15, hi = lane >> 4;
  const int rg = hi ^ ((lane >> 1) & 3);

#define GSTAGE(KT, BUF)                                                       \
  {                                                                           \
    _Pragma("unroll") for (int j_ = 0; j_ < 2; ++j_) {                        \
      int c_ = wave * 2 + j_;                                                 \
      int row_ = c_ * 16 + srow;                                              \
      async16(Aptr + (size_t)(m0 + row_) * 1024 + (KT) + sgrp * 8,            \
              &As[BUF][c_ * 512]);                                            \
      async16(Bptr + (size_t)(n0 + row_) * 1024 + (KT) + sgrp * 8,            \
              &Bs[BUF][c_ * 512]);                                            \
    }                                                                         \
  }

  f32x4 acc[4][4] = {};

  GSTAGE(0, 0);
  __syncthreads();
  int cur = 0;
  for (int kt = 0; kt < 1024; kt += 32) {
    if (kt + 32 < 1024) GSTAGE(kt + 32, cur ^ 1);
    bf16x8 af[4], bfv[4];
#pragma unroll
    for (int i = 0; i < 4; ++i) {
      af[i] = *(const bf16x8*)(&As[cur][(wr * 64 + i * 16 + l15) * 32 + rg * 8]);
      bfv[i] = *(const bf16x8*)(&Bs[cur][(wc * 64 + i * 16 + l15) * 32 + rg * 8]);
    }
#pragma unroll
    for (int i = 0; i < 4; ++i)
#pragma unroll
      for (int j = 0; j < 4; ++j)
        acc[i][j] = MFMA(af[i], bfv[j], acc[i][j]);
    __syncthreads();
    cur ^= 1;
  }
#undef GSTAGE

#pragma unroll
  for (int fm = 0; fm < 4; ++fm) {
#pragma unroll
    for (int fn = 0; fn < 4; ++fn) {
      int n = n0 + wc * 64 + fn * 16 + (lane & 15);
      float bv = bias[n];
#pragma unroll
      for (int i = 0; i < 4; ++i) {
        int m = m0 + wr * 64 + fm * 16 + (lane >> 4) * 4 + i;
        Out[(size_t)m * 1024 + n] = acc[fm][fn][i] + bv;
      }
    }
  }
}

// ---------- launcher ----------

extern "C" void kernel_launch(void* const* d_in, const int* in_sizes, int n_in,
                              void* d_out, int out_size, void* d_ws, size_t ws_size,
                              hipStream_t stream) {
  const float* xq = (const float*)d_in[0];
  const float* xk = (const float*)d_in[1];
  const float* xv = (const float*)d_in[2];
  const float* WQ = (const float*)d_in[3];
  const float* WK = (const float*)d_in[4];
  const float* WV = (const float*)d_in[5];
  const float* WO = (const float*)d_in[6];
  const float* bQ = (const float*)d_in[7];
  const float* bK = (const float*)d_in[8];
  const float* bV = (const float*)d_in[9];
  const float* bO = (const float*)d_in[10];
  float* out = (float*)d_out;

  char* ws = (char*)d_ws;
  const size_t MB = 1024 * 1024;
  u16* Xq = (u16*)(ws);             // 8MB each (4096x1024 bf16); dead after gemm_qkv
  u16* Xk = (u16*)(ws + 8 * MB);
  u16* Xv = (u16*)(ws + 16 * MB);
  u16* WqT = (u16*)(ws + 24 * MB);  // 2MB each; dead after gemm_qkv
  u16* WkT = (u16*)(ws + 26 * MB);
  u16* WvT = (u16*)(ws + 28 * MB);
  u16* WoT = (u16*)(ws + 30 * MB);  // live until gemm_out
  u16* Q = (u16*)(ws + 32 * MB);    // 8MB [B,H,S,D] (prescaled)
  u16* K = (u16*)(ws + 40 * MB);    // 8MB [B,H,S,D]
  u16* V = (u16*)(ws + 48 * MB);    // 8MB [B,H,D,S]  (transposed)
  u16* Z = (u16*)(ws + 56 * MB);    // 8MB [B,S,H,D]
  // kv-split partials overlay the dead Xq/Xk/Xv/WqT regions (0..26MB):
  u16* PO = (u16*)(ws);                        // 24MB: [3][32][2048][64] bf16
  float* PM = (float*)(ws + 24 * MB);          // 768KB: [3][32][2048] f32
  float* PL = (float*)(ws + 25 * MB);          // 768KB

  prep_kernel<<<dim3(7168), 256, 0, stream>>>(xq, xk, xv, Xq, Xk, Xv,
                                              WQ, WK, WV, WqT, WkT, WvT, WO, WoT);
  gemm_qkv_kernel<<<dim3(32, 8, 3), 256, 0, stream>>>(Xq, Xk, Xv, WqT, WkT, WvT,
                                                      bQ, bK, bV, Q, K, V);
  attn_kernel<<<dim3(8, 32, 3), 256, 0, stream>>>(Q, K, V, PO, PM, PL);
  combine_kernel<<<dim3(1024), 256, 0, stream>>>(PO, PM, PL, Z);
  gemm_out_kernel<<<dim3(32, 8), 256, 0, stream>>>(Z, WoT, bO, out);
}

// Round 8
// 152.061 us; speedup vs baseline: 1.5239x; 1.0007x over previous
//
#include <hip/hip_runtime.h>
#include <cstdint>
#include <cmath>

typedef __attribute__((ext_vector_type(4))) float f32x4;
typedef __attribute__((ext_vector_type(16))) float f32x16;
typedef __attribute__((ext_vector_type(8))) short bf16x8;
using u16 = unsigned short;
using u32 = uint32_t;

// ---------- helpers ----------

static __device__ __forceinline__ u16 f2bf(float f) {
  uint32_t u = __float_as_uint(f);
  u += 0x7fffu + ((u >> 16) & 1u);
  return (u16)(u >> 16);
}

static __device__ __forceinline__ float bf2f(u16 x) {
  return __uint_as_float((u32)x << 16);
}

// round f32 to float8_e4m3fn (RNE), return dequantized f32.
static __device__ __forceinline__ float quant_e4m3(float x) {
  uint32_t u = __float_as_uint(x);
  uint32_t absu = u & 0x7fffffffu;
  if (absu >= 0x3c800000u) {  // |x| >= 2^-6 : e4m3 normal, keep 3 mantissa bits RNE
    uint32_t lsb = (absu >> 20) & 1u;
    uint32_t r = (absu + 0x7ffffu + lsb) & ~0xfffffu;
    return __uint_as_float((u & 0x80000000u) | r);
  }
  return rintf(x * 512.0f) * 0.001953125f;
}

static __device__ __forceinline__ void async16(const void* g, void* l) {
  __builtin_amdgcn_global_load_lds(
      (const __attribute__((address_space(1))) void*)g,
      (__attribute__((address_space(3))) void*)l, 16, 0, 0);
}

static __device__ __forceinline__ u32 cvtpk(float a, float b) {
  u32 r;
  asm("v_cvt_pk_bf16_f32 %0, %1, %2" : "=v"(r) : "v"(a), "v"(b));
  return r;
}

#define MFMA(a, b, c) __builtin_amdgcn_mfma_f32_16x16x32_bf16(a, b, c, 0, 0, 0)
#define MFMA32(a, b, c) __builtin_amdgcn_mfma_f32_32x32x16_bf16(a, b, c, 0, 0, 0)

// log2(e)/sqrt(64): folded into Q at projection time so attn uses exp2 directly.
#define QSCALE 0.18033688011112042f

// ---------- kernel 1: merged prep (quantize inputs + weight transposes) ----------

__global__ __launch_bounds__(256)
void prep_kernel(const float* __restrict__ xq, const float* __restrict__ xk,
                 const float* __restrict__ xv,
                 u16* __restrict__ Xq, u16* __restrict__ Xk, u16* __restrict__ Xv,
                 const float* __restrict__ WQ, const float* __restrict__ WK,
                 const float* __restrict__ WV,
                 u16* __restrict__ WqT, u16* __restrict__ WkT, u16* __restrict__ WvT,
                 const float* __restrict__ WO, u16* __restrict__ WoT) {
  __shared__ u16 T[64][72];
  const int bid = blockIdx.x;
  const int t = threadIdx.x;

  if (bid < 6144) {  // activation quantize: fp32 -> e4m3 -> bf16
    const int which = bid >> 11, idx = bid & 2047;
    const float* x = which == 0 ? xq : (which == 1 ? xk : xv);
    u16* y = which == 0 ? Xq : (which == 1 ? Xk : Xv);
    int i = (idx * 256 + t) * 8;
    f32x4 a = *(const f32x4*)(x + i);
    f32x4 b = *(const f32x4*)(x + i + 4);
    union { bf16x8 v; u16 s[8]; } r;
#pragma unroll
    for (int j = 0; j < 4; ++j) r.s[j] = f2bf(quant_e4m3(a[j]));
#pragma unroll
    for (int j = 0; j < 4; ++j) r.s[4 + j] = f2bf(quant_e4m3(b[j]));
    *(bf16x8*)(y + i) = r.v;
    return;
  }

  if (bid < 6912) {  // W_{Q,K,V} [H,M,D] -> quant -> bf16 Bt[n=h*64+d][k=m]
    const int sub = bid - 6144;
    const int zz = sub >> 8;
    const int rem = sub & 255;
    const int h = rem >> 4;
    const int k0 = (rem & 15) * 64;
    const float* w = zz == 0 ? WQ : (zz == 1 ? WK : WV);
    u16* wt = zz == 0 ? WqT : (zz == 1 ? WkT : WvT);
    int ml = t >> 2, d0 = (t & 3) * 16;
    const float* src = w + ((size_t)h * 1024 + (k0 + ml)) * 64 + d0;
    u16 q16[16];
#pragma unroll
    for (int j = 0; j < 16; j += 4) {
      f32x4 f = *(const f32x4*)(src + j);
#pragma unroll
      for (int c = 0; c < 4; ++c) q16[j + c] = f2bf(quant_e4m3(f[c]));
    }
#pragma unroll
    for (int j = 0; j < 16; ++j) T[ml][d0 + j] = q16[j];
    __syncthreads();
    int d = t >> 2, cb = t & 3;
    union { bf16x8 v; u16 s[8]; } o0, o1;
#pragma unroll
    for (int j = 0; j < 8; ++j) { o0.s[j] = T[cb * 16 + j][d]; o1.s[j] = T[cb * 16 + 8 + j][d]; }
    u16* dst = wt + (size_t)(h * 64 + d) * 1024 + k0 + cb * 16;
    *(bf16x8*)(dst) = o0.v;
    *(bf16x8*)(dst + 8) = o1.v;
    return;
  }

  {  // W_O [H,D,M] -> bf16 Bt[n=m][k=h*64+d]
    const int sub = bid - 6912;
    const int r0 = (sub >> 4) * 64;
    const int c0 = (sub & 15) * 64;
    int rl = t >> 2, cl0 = (t & 3) * 16;
    const float* src = WO + (size_t)(r0 + rl) * 1024 + c0 + cl0;
    u16 q16[16];
#pragma unroll
    for (int j = 0; j < 16; j += 4) {
      f32x4 f = *(const f32x4*)(src + j);
#pragma unroll
      for (int c = 0; c < 4; ++c) q16[j + c] = f2bf(f[c]);
    }
#pragma unroll
    for (int j = 0; j < 16; ++j) T[rl][cl0 + j] = q16[j];
    __syncthreads();
    int ml = t >> 2, cb = t & 3;
    union { bf16x8 v; u16 s[8]; } o0, o1;
#pragma unroll
    for (int j = 0; j < 8; ++j) { o0.s[j] = T[cb * 16 + j][ml]; o1.s[j] = T[cb * 16 + 8 + j][ml]; }
    u16* dst = WoT + (size_t)(c0 + ml) * 1024 + r0 + cb * 16;
    *(bf16x8*)(dst) = o0.v;
    *(bf16x8*)(dst + 8) = o1.v;
  }
}

// ---------- kernel 2: QKV GEMM, BK=32, 3-buffer counted-vmcnt pipeline, swizzled LDS ----------
// LDS layout: [128 rows][4 groups of 8]; stored[row][g] = src[row][g ^ ((row>>1)&3)].

__global__ __launch_bounds__(256)
void gemm_qkv_kernel(const u16* __restrict__ A0, const u16* __restrict__ A1, const u16* __restrict__ A2,
                     const u16* __restrict__ B0, const u16* __restrict__ B1, const u16* __restrict__ B2,
                     const float* __restrict__ bias0, const float* __restrict__ bias1,
                     const float* __restrict__ bias2,
                     u16* __restrict__ O0, u16* __restrict__ O1, u16* __restrict__ O2) {
  const int bz = blockIdx.z;
  const u16* Aptr = bz == 0 ? A0 : (bz == 1 ? A1 : A2);
  const u16* Bptr = bz == 0 ? B0 : (bz == 1 ? B1 : B2);
  const float* bias = bz == 0 ? bias0 : (bz == 1 ? bias1 : bias2);
  u16* O = bz == 0 ? O0 : (bz == 1 ? O1 : O2);

  __shared__ u16 As[3][128 * 32];
  __shared__ u16 Bs[3][128 * 32];
  const int m0 = blockIdx.x * 128;
  const int n0 = blockIdx.y * 128;
  const int tid = threadIdx.x;
  const int wave = tid >> 6, lane = tid & 63;
  const int wr = wave >> 1, wc = wave & 1;
  const int srow = lane >> 2;                       // row within 16-row chunk
  const int sgrp = (lane & 3) ^ ((lane >> 3) & 3);  // pre-swizzled source group
  const int l15 = lane & 15, hi = lane >> 4;
  const int rg = hi ^ ((lane >> 1) & 3);            // swizzled read group

#define GSTAGE(KT, BUF)                                                       \
  {                                                                           \
    _Pragma("unroll") for (int j_ = 0; j_ < 2; ++j_) {                        \
      int c_ = wave * 2 + j_;                                                 \
      int row_ = c_ * 16 + srow;                                              \
      async16(Aptr + (size_t)(m0 + row_) * 1024 + (KT) + sgrp * 8,            \
              &As[BUF][c_ * 512]);                                            \
      async16(Bptr + (size_t)(n0 + row_) * 1024 + (KT) + sgrp * 8,            \
              &Bs[BUF][c_ * 512]);                                            \
    }                                                                         \
  }

  f32x4 acc[4][4] = {};

  // prologue: 2-deep prefetch
  GSTAGE(0, 0);
  GSTAGE(32, 1);
  asm volatile("s_waitcnt vmcnt(4)" ::: "memory");  // tile 0 landed, tile 1 in flight
  __builtin_amdgcn_s_barrier();

  int cur = 0;
  for (int it = 0; it < 32; ++it) {
    if (it + 2 < 32) {
      const int b2 = (cur + 2) % 3;
      GSTAGE((it + 2) * 32, b2);
    }
    bf16x8 af[4], bfv[4];
#pragma unroll
    for (int i = 0; i < 4; ++i) {
      af[i] = *(const bf16x8*)(&As[cur][(wr * 64 + i * 16 + l15) * 32 + rg * 8]);
      bfv[i] = *(const bf16x8*)(&Bs[cur][(wc * 64 + i * 16 + l15) * 32 + rg * 8]);
    }
    __builtin_amdgcn_s_setprio(1);
#pragma unroll
    for (int i = 0; i < 4; ++i)
#pragma unroll
      for (int j = 0; j < 4; ++j)
        acc[i][j] = MFMA(af[i], bfv[j], acc[i][j]);
    __builtin_amdgcn_s_setprio(0);
    if (it + 1 < 32) {
      if (it + 2 < 32) {
        asm volatile("s_waitcnt vmcnt(4) lgkmcnt(0)" ::: "memory");  // t+1 landed, t+2 in flight
      } else {
        asm volatile("s_waitcnt vmcnt(0) lgkmcnt(0)" ::: "memory");
      }
      __builtin_amdgcn_s_barrier();
    }
    cur = (cur + 1) % 3;
  }
#undef GSTAGE

  if (bz == 2) {
    // V^T: [B,H,D,S]
#pragma unroll
    for (int fm = 0; fm < 4; ++fm) {
#pragma unroll
      for (int fn = 0; fn < 4; ++fn) {
        int n = n0 + wc * 64 + fn * 16 + (lane & 15);
        int hh = n >> 6, d = n & 63;
        float bv = bias[n];
        int m_base = m0 + wr * 64 + fm * 16 + (lane >> 4) * 4;
        int b = m_base >> 11, s = m_base & 2047;
        union { u16 s4[4]; uint2 u2; } pk;
#pragma unroll
        for (int i = 0; i < 4; ++i) pk.s4[i] = f2bf(acc[fm][fn][i] + bv);
        *(uint2*)(&O[(((size_t)b * 16 + hh) * 64 + d) * 2048 + s]) = pk.u2;
      }
    }
  } else {
    const float oscale = (bz == 0) ? QSCALE : 1.0f;
#pragma unroll
    for (int fm = 0; fm < 4; ++fm) {
#pragma unroll
      for (int fn = 0; fn < 4; ++fn) {
        int n = n0 + wc * 64 + fn * 16 + (lane & 15);
        int hh = n >> 6, d = n & 63;
        float bv = bias[n];
#pragma unroll
        for (int i = 0; i < 4; ++i) {
          int m = m0 + wr * 64 + fm * 16 + (lane >> 4) * 4 + i;
          int b = m >> 11, s = m & 2047;
          O[(((size_t)b * 16 + hh) * 2048 + s) * 64 + d] = f2bf((acc[fm][fn][i] + bv) * oscale);
        }
      }
    }
  }
}

// ---------- kernel 3: causal flash attention, uniform-work blocks ----------
// grid (8, 32, 3): x -> q-tile pair {x, 15-x}, y = b*16+h, z = kv-split (t%3==z).
// 256 thr = 4 waves, 32 q-rows/wave. P-exchange via v_permlane32_swap_b32.

__global__ __launch_bounds__(256)
void attn_kernel(const u16* __restrict__ q, const u16* __restrict__ k,
                 const u16* __restrict__ vt,
                 u16* __restrict__ PO, float* __restrict__ PM, float* __restrict__ PL) {
  const int x = blockIdx.x, bh = blockIdx.y, zs = blockIdx.z;
  const int tid = threadIdx.x;
  const int w = tid >> 6, lane = tid & 63;
  const int l31 = lane & 31, h = lane >> 5;
  const int swz = lane & 7;
  const size_t base = (size_t)bh * (2048 * 64);

  __shared__ u16 Ks[3][64 * 64];
  __shared__ u16 Vs[3][64 * 64];

  // staging: lane writes LDS 16B-group lane&7 (linear); source pre-swizzled by ^ (lane>>3)
  const int r8 = lane >> 3;
  const int cg = (lane & 7) ^ r8;
  const int c0 = 2 * w;

#define STAGE(J, B)                                                              \
  {                                                                              \
    const int kv_ = (zs + 3 * (J)) * 64;                                         \
    _Pragma("unroll")                                                            \
    for (int c_ = 0; c_ < 2; ++c_) {                                             \
      int chunk_ = c0 + c_;                                                      \
      int row_ = chunk_ * 8 + r8;                                                \
      async16(k + base + (size_t)(kv_ + row_) * 64 + cg * 8, &Ks[B][chunk_ * 512]); \
      async16(vt + base + (size_t)row_ * 2048 + kv_ + cg * 8, &Vs[B][chunk_ * 512]); \
    }                                                                            \
  }

  int bcur = 0;
#pragma unroll 1
  for (int seg = 0; seg < 2; ++seg) {
    const int qb = seg ? 15 - x : x;
    const int nj = (2 * qb + 4 - zs) / 3;  // tiles t = zs + 3j in [0, 2qb+2)
    const int wq0 = qb * 128 + w * 32;
    const int q_glob = wq0 + l31;

    // Q fragments: B-operand, lane holds Q[q=l31][d = 16*kk + 8*h + j]
    bf16x8 qf[4];
    {
      const u16* qp = q + base + (size_t)q_glob * 64 + 8 * h;
#pragma unroll
      for (int kk = 0; kk < 4; ++kk) qf[kk] = *(const bf16x8*)(qp + 16 * kk);
    }

    f32x16 oa0 = {}, oa1 = {};   // O^T acc: lane holds q=l31, d rows
    float mreg = -1e30f, lsum = 0.f;

    __builtin_amdgcn_s_barrier();  // guard LDS reuse across segments
    if (nj > 0) {
      STAGE(0, bcur);
      asm volatile("s_waitcnt vmcnt(0)" ::: "memory");
      __builtin_amdgcn_s_barrier();
      if (nj > 1) STAGE(1, (bcur + 1) % 3);

      for (int t = 0; t < nj; ++t) {
        const int kv0 = (zs + 3 * t) * 64;
        if (t + 2 < nj) STAGE(t + 2, (bcur + 2) % 3);

        if (kv0 <= wq0 + 31) {  // skip fully-masked tiles (wave-uniform)
          bf16x8 kf0[4], kf1[4];
#pragma unroll
          for (int kk = 0; kk < 4; ++kk) {
            const int colo = ((2 * kk + h) ^ swz) * 8;
            kf0[kk] = *(const bf16x8*)(&Ks[bcur][l31 * 64 + colo]);
            kf1[kk] = *(const bf16x8*)(&Ks[bcur][(32 + l31) * 64 + colo]);
          }
          f32x16 sa0 = {}, sa1 = {};
          __builtin_amdgcn_s_setprio(1);
#pragma unroll
          for (int kk = 0; kk < 4; ++kk) {
            sa0 = MFMA32(kf0[kk], qf[kk], sa0);
            sa1 = MFMA32(kf1[kk], qf[kk], sa1);
          }
          __builtin_amdgcn_s_setprio(0);

          if (kv0 + 63 > wq0) {  // diagonal tile: apply causal mask
            int kvoff = kv0 + 4 * h - q_glob;
#pragma unroll
            for (int rg2 = 0; rg2 < 16; ++rg2) {
              const int pat = (rg2 & 3) + 8 * (rg2 >> 2);
              if (pat + kvoff > 0) sa0[rg2] = -1e30f;
              if (pat + 32 + kvoff > 0) sa1[rg2] = -1e30f;
            }
          }

          // tree max over 32 values
          float mx[8];
#pragma unroll
          for (int i = 0; i < 8; ++i)
            mx[i] = fmaxf(fmaxf(sa0[i], sa0[i + 8]), fmaxf(sa1[i], sa1[i + 8]));
          float pmax = fmaxf(fmaxf(fmaxf(mx[0], mx[1]), fmaxf(mx[2], mx[3])),
                             fmaxf(fmaxf(mx[4], mx[5]), fmaxf(mx[6], mx[7])));
          pmax = fmaxf(pmax, __shfl_xor(pmax, 32));

          // defer-max: rescale only when max grew past threshold
          if (!__all(pmax <= mreg + 8.f)) {
            float mnew = fmaxf(mreg, pmax);
            float alpha = __builtin_amdgcn_exp2f(mreg - mnew);
            mreg = mnew;
            lsum *= alpha;
#pragma unroll
            for (int i = 0; i < 16; ++i) { oa0[i] *= alpha; oa1[i] *= alpha; }
          }

          // P = exp2(S - m)
          float p0a[16], p1a[16];
#pragma unroll
          for (int i = 0; i < 16; ++i) {
            p0a[i] = __builtin_amdgcn_exp2f(sa0[i] - mreg);
            p1a[i] = __builtin_amdgcn_exp2f(sa1[i] - mreg);
          }
          u32 P32[2][4][2];
#pragma unroll
          for (int tt = 0; tt < 4; ++tt)
#pragma unroll
            for (int cc = 0; cc < 2; ++cc) {
              P32[0][tt][cc] = cvtpk(p0a[4 * tt + 2 * cc], p0a[4 * tt + 2 * cc + 1]);
              P32[1][tt][cc] = cvtpk(p1a[4 * tt + 2 * cc], p1a[4 * tt + 2 * cc + 1]);
            }
          // tree row-sum
          float r8v[8];
#pragma unroll
          for (int i = 0; i < 8; ++i)
            r8v[i] = (p0a[i] + p0a[i + 8]) + (p1a[i] + p1a[i + 8]);
          float rsum = ((r8v[0] + r8v[1]) + (r8v[2] + r8v[3])) +
                       ((r8v[4] + r8v[5]) + (r8v[6] + r8v[7]));
          rsum += __shfl_xor(rsum, 32);
          lsum += rsum;

          // V fragments
          bf16x8 vf0[4], vf1[4];
#pragma unroll
          for (int kk = 0; kk < 4; ++kk) {
            const int colo = ((2 * kk + h) ^ swz) * 8;
            vf0[kk] = *(const bf16x8*)(&Vs[bcur][l31 * 64 + colo]);
            vf1[kk] = *(const bf16x8*)(&Vs[bcur][(32 + l31) * 64 + colo]);
          }
          // P exchange via permlane32_swap: A'={A.lo,B.lo}, B'={A.hi,B.hi}
          __builtin_amdgcn_s_setprio(1);
#pragma unroll
          for (int kk = 0; kk < 4; ++kk) {
            const int fp = kk >> 1;
            const int ta = 2 * (kk & 1);
            union { u32 u[4]; bf16x8 v; } pb;
#pragma unroll
            for (int cc = 0; cc < 2; ++cc) {
              u32 a = P32[fp][ta][cc], b = P32[fp][ta + 1][cc];
              asm("v_permlane32_swap_b32 %0, %1" : "+v"(a), "+v"(b));
              pb.u[cc] = a;
              pb.u[2 + cc] = b;
            }
            oa0 = MFMA32(vf0[kk], pb.v, oa0);
            oa1 = MFMA32(vf1[kk], pb.v, oa1);
          }
          __builtin_amdgcn_s_setprio(0);
        }

        if (t + 1 < nj) {
          if (t + 2 < nj) {
            asm volatile("s_waitcnt vmcnt(4) lgkmcnt(0)" ::: "memory");
          } else {
            asm volatile("s_waitcnt vmcnt(0) lgkmcnt(0)" ::: "memory");
          }
          __builtin_amdgcn_s_barrier();
        }
        bcur = (bcur + 1) % 3;
      }
    }

    // write normalized partial O (bf16) + m,l (f32) for this segment's q-tile
    const float inv = lsum > 0.f ? 1.f / lsum : 0.f;
    const size_t prow = (size_t)(zs * 32 + bh) * 2048 + q_glob;
    u16* pop = PO + prow * 64;
#pragma unroll
    for (int fd = 0; fd < 2; ++fd)
#pragma unroll
      for (int tt = 0; tt < 4; ++tt) {
        union { u16 s[4]; uint2 u2; } pk;
#pragma unroll
        for (int i = 0; i < 4; ++i) {
          float ov = (fd ? oa1[4 * tt + i] : oa0[4 * tt + i]) * inv;
          pk.s[i] = f2bf(ov);
        }
        *(uint2*)(pop + fd * 32 + tt * 8 + 4 * h) = pk.u2;
      }
    if (h == 0) {
      PM[prow] = mreg;
      PL[prow] = lsum;
    }
  }
#undef STAGE
}

// ---------- kernel 4: combine 3 kv-split partials -> Z [B,S,H,D] bf16 ----------

__global__ __launch_bounds__(256)
void combine_kernel(const u16* __restrict__ PO, const float* __restrict__ PM,
                    const float* __restrict__ PL, u16* __restrict__ z) {
  const int g = blockIdx.x * 256 + threadIdx.x;  // 4 threads per q-row
  const int row = g >> 2, dp = (g & 3) * 16;
  const int bh = row >> 11, qq = row & 2047;
  const int b = bh >> 4, head = bh & 15;
  float m0 = PM[row], m1 = PM[65536 + row], m2 = PM[131072 + row];
  float l0 = PL[row], l1 = PL[65536 + row], l2 = PL[131072 + row];
  float m = fmaxf(m0, fmaxf(m1, m2));
  float a0 = l0 * __builtin_amdgcn_exp2f(m0 - m);
  float a1 = l1 * __builtin_amdgcn_exp2f(m1 - m);
  float a2 = l2 * __builtin_amdgcn_exp2f(m2 - m);
  float inv = 1.f / (a0 + a1 + a2);
  a0 *= inv; a1 *= inv; a2 *= inv;
  const u16* p0 = PO + (size_t)row * 64 + dp;
  const u16* p1 = PO + (size_t)(65536 + row) * 64 + dp;
  const u16* p2 = PO + (size_t)(131072 + row) * 64 + dp;
  union { bf16x8 v; u16 s[8]; } i0a, i0b, i1a, i1b, i2a, i2b, oA, oB;
  i0a.v = *(const bf16x8*)(p0);
  i0b.v = *(const bf16x8*)(p0 + 8);
  i1a.v = *(const bf16x8*)(p1);
  i1b.v = *(const bf16x8*)(p1 + 8);
  i2a.v = *(const bf16x8*)(p2);
  i2b.v = *(const bf16x8*)(p2 + 8);
#pragma unroll
  for (int j = 0; j < 8; ++j) {
    oA.s[j] = f2bf(bf2f(i0a.s[j]) * a0 + bf2f(i1a.s[j]) * a1 + bf2f(i2a.s[j]) * a2);
    oB.s[j] = f2bf(bf2f(i0b.s[j]) * a0 + bf2f(i1b.s[j]) * a1 + bf2f(i2b.s[j]) * a2);
  }
  u16* zp = z + (((size_t)b * 2048 + qq) * 16 + head) * 64 + dp;
  *(bf16x8*)(zp) = oA.v;
  *(bf16x8*)(zp + 8) = oB.v;
}

// ---------- kernel 5: output projection GEMM, BK=32, 3-buffer counted-vmcnt, swizzled ----------

__global__ __launch_bounds__(256)
void gemm_out_kernel(const u16* __restrict__ Aptr, const u16* __restrict__ Bptr,
                     const float* __restrict__ bias, float* __restrict__ Out) {
  __shared__ u16 As[3][128 * 32];
  __shared__ u16 Bs[3][128 * 32];
  const int m0 = blockIdx.x * 128;
  const int n0 = blockIdx.y * 128;
  const int tid = threadIdx.x;
  const int wave = tid >> 6, lane = tid & 63;
  const int wr = wave >> 1, wc = wave & 1;
  const int srow = lane >> 2;
  const int sgrp = (lane & 3) ^ ((lane >> 3) & 3);
  const int l15 = lane & 15, hi = lane >> 4;
  const int rg = hi ^ ((lane >> 1) & 3);

#define GSTAGE(KT, BUF)                                                       \
  {                                                                           \
    _Pragma("unroll") for (int j_ = 0; j_ < 2; ++j_) {                        \
      int c_ = wave * 2 + j_;                                                 \
      int row_ = c_ * 16 + srow;                                              \
      async16(Aptr + (size_t)(m0 + row_) * 1024 + (KT) + sgrp * 8,            \
              &As[BUF][c_ * 512]);                                            \
      async16(Bptr + (size_t)(n0 + row_) * 1024 + (KT) + sgrp * 8,            \
              &Bs[BUF][c_ * 512]);                                            \
    }                                                                         \
  }

  f32x4 acc[4][4] = {};

  GSTAGE(0, 0);
  GSTAGE(32, 1);
  asm volatile("s_waitcnt vmcnt(4)" ::: "memory");
  __builtin_amdgcn_s_barrier();

  int cur = 0;
  for (int it = 0; it < 32; ++it) {
    if (it + 2 < 32) {
      const int b2 = (cur + 2) % 3;
      GSTAGE((it + 2) * 32, b2);
    }
    bf16x8 af[4], bfv[4];
#pragma unroll
    for (int i = 0; i < 4; ++i) {
      af[i] = *(const bf16x8*)(&As[cur][(wr * 64 + i * 16 + l15) * 32 + rg * 8]);
      bfv[i] = *(const bf16x8*)(&Bs[cur][(wc * 64 + i * 16 + l15) * 32 + rg * 8]);
    }
    __builtin_amdgcn_s_setprio(1);
#pragma unroll
    for (int i = 0; i < 4; ++i)
#pragma unroll
      for (int j = 0; j < 4; ++j)
        acc[i][j] = MFMA(af[i], bfv[j], acc[i][j]);
    __builtin_amdgcn_s_setprio(0);
    if (it + 1 < 32) {
      if (it + 2 < 32) {
        asm volatile("s_waitcnt vmcnt(4) lgkmcnt(0)" ::: "memory");
      } else {
        asm volatile("s_waitcnt vmcnt(0) lgkmcnt(0)" ::: "memory");
      }
      __builtin_amdgcn_s_barrier();
    }
    cur = (cur + 1) % 3;
  }
#undef GSTAGE

#pragma unroll
  for (int fm = 0; fm < 4; ++fm) {
#pragma unroll
    for (int fn = 0; fn < 4; ++fn) {
      int n = n0 + wc * 64 + fn * 16 + (lane & 15);
      float bv = bias[n];
#pragma unroll
      for (int i = 0; i < 4; ++i) {
        int m = m0 + wr * 64 + fm * 16 + (lane >> 4) * 4 + i;
        Out[(size_t)m * 1024 + n] = acc[fm][fn][i] + bv;
      }
    }
  }
}

// ---------- launcher ----------

extern "C" void kernel_launch(void* const* d_in, const int* in_sizes, int n_in,
                              void* d_out, int out_size, void* d_ws, size_t ws_size,
                              hipStream_t stream) {
  const float* xq = (const float*)d_in[0];
  const float* xk = (const float*)d_in[1];
  const float* xv = (const float*)d_in[2];
  const float* WQ = (const float*)d_in[3];
  const float* WK = (const float*)d_in[4];
  const float* WV = (const float*)d_in[5];
  const float* WO = (const float*)d_in[6];
  const float* bQ = (const float*)d_in[7];
  const float* bK = (const float*)d_in[8];
  const float* bV = (const float*)d_in[9];
  const float* bO = (const float*)d_in[10];
  float* out = (float*)d_out;

  char* ws = (char*)d_ws;
  const size_t MB = 1024 * 1024;
  u16* Xq = (u16*)(ws);             // 8MB each (4096x1024 bf16); dead after gemm_qkv
  u16* Xk = (u16*)(ws + 8 * MB);
  u16* Xv = (u16*)(ws + 16 * MB);
  u16* WqT = (u16*)(ws + 24 * MB);  // 2MB each; dead after gemm_qkv
  u16* WkT = (u16*)(ws + 26 * MB);
  u16* WvT = (u16*)(ws + 28 * MB);
  u16* WoT = (u16*)(ws + 30 * MB);  // live until gemm_out
  u16* Q = (u16*)(ws + 32 * MB);    // 8MB [B,H,S,D] (prescaled)
  u16* K = (u16*)(ws + 40 * MB);    // 8MB [B,H,S,D]
  u16* V = (u16*)(ws + 48 * MB);    // 8MB [B,H,D,S]  (transposed)
  u16* Z = (u16*)(ws + 56 * MB);    // 8MB [B,S,H,D]
  // kv-split partials overlay the dead Xq/Xk/Xv/WqT regions (0..26MB):
  u16* PO = (u16*)(ws);                        // 24MB: [3][32][2048][64] bf16
  float* PM = (float*)(ws + 24 * MB);          // 768KB: [3][32][2048] f32
  float* PL = (float*)(ws + 25 * MB);          // 768KB

  prep_kernel<<<dim3(7168), 256, 0, stream>>>(xq, xk, xv, Xq, Xk, Xv,
                                              WQ, WK, WV, WqT, WkT, WvT, WO, WoT);
  gemm_qkv_kernel<<<dim3(32, 8, 3), 256, 0, stream>>>(Xq, Xk, Xv, WqT, WkT, WvT,
                                                      bQ, bK, bV, Q, K, V);
  attn_kernel<<<dim3(8, 32, 3), 256, 0, stream>>>(Q, K, V, PO, PM, PL);
  combine_kernel<<<dim3(1024), 256, 0, stream>>>(PO, PM, PL, Z);
  gemm_out_kernel<<<dim3(32, 8), 256, 0, stream>>>(Z, WoT, bO, out);
}